// Round 2
// baseline (2698.006 us; speedup 1.0000x reference)
//
#include <hip/hip_runtime.h>

// DecoderLayer (B=16, N1=512, D=1024, H=16, Dk=64, FF=4096)
// Round 2: crash-fix round.
//  - ws usage cut 342.5 -> 174.25 MiB (suspected ws overflow -> GPU fault):
//    lazy weight transpose (8 MiB shared), shared padded-KV buffer, bf16 branch
//    outputs + pairwise fuse, xbuf aliases hbuf, FFN-mid aliases dead k/v/bp1/bp2.
//  - removed __builtin_amdgcn_fdot2_f32_bf16 (unverified on gfx950) -> plain FMA.
//  - GEMM: bf16 MFMA 16x16x32, 128x128 tile (unchanged from round 1).

typedef __attribute__((ext_vector_type(4))) float          f32x4;
typedef __attribute__((ext_vector_type(8))) short          bf16x8;
typedef __attribute__((ext_vector_type(4))) unsigned short us4;

#define DEV static __device__ __forceinline__

DEV float bf2f(short h) {
  union { unsigned u; float f; } c;
  c.u = ((unsigned)(unsigned short)h) << 16;
  return c.f;
}
DEV unsigned short f2bf(float f) {  // round-to-nearest-even
  union { float f; unsigned u; } c; c.f = f;
  return (unsigned short)((c.u + 0x7fffu + ((c.u >> 16) & 1u)) >> 16);
}

// ---------------- transpose + f32->bf16 convert (weights) ----------------
// src: blockIdx.z-th [R,C] f32 matrix; dst: [C,R] bf16
__global__ __launch_bounds__(256)
void k_transpose_cvt(const float* __restrict__ src, unsigned short* __restrict__ dst,
                     int R, int C) {
  __shared__ float tile[32][33];
  const size_t mo = (size_t)blockIdx.z * R * C;
  src += mo; dst += mo;
  const int c0 = blockIdx.x * 32, r0 = blockIdx.y * 32;
  const int tx = threadIdx.x, ty = threadIdx.y;
#pragma unroll
  for (int i = 0; i < 32; i += 8)
    tile[ty + i][tx] = src[(size_t)(r0 + ty + i) * C + (c0 + tx)];
  __syncthreads();
#pragma unroll
  for (int i = 0; i < 32; i += 8)
    dst[(size_t)(c0 + ty + i) * R + (r0 + tx)] = f2bf(tile[tx][ty + i]);
}

// ---------------- f32 -> bf16 convert with zero row padding ----------------
__global__ __launch_bounds__(256)
void k_cvt_pad(const float* __restrict__ src, unsigned short* __restrict__ dst, int rows) {
  const int r = blockIdx.x;
  const int c = threadIdx.x * 4;
  us4 o;
  if (r < rows) {
    f32x4 v = *(const f32x4*)(src + (size_t)r * 1024 + c);
    o[0] = f2bf(v[0]); o[1] = f2bf(v[1]); o[2] = f2bf(v[2]); o[3] = f2bf(v[3]);
  } else {
    o[0] = 0; o[1] = 0; o[2] = 0; o[3] = 0;
  }
  *(us4*)(dst + (size_t)r * 1024 + c) = o;
}

// ---------------- LayerNorm (D=1024), f32 in -> bf16 out ----------------
__global__ __launch_bounds__(256)
void k_ln(const float* __restrict__ x, const float* __restrict__ g,
          const float* __restrict__ bb, unsigned short* __restrict__ y) {
  __shared__ float red[8];
  const size_t base = (size_t)blockIdx.x * 1024;
  const int t = threadIdx.x;
  f32x4 v = *(const f32x4*)(x + base + t * 4);
  float s  = v[0] + v[1] + v[2] + v[3];
  float s2 = v[0]*v[0] + v[1]*v[1] + v[2]*v[2] + v[3]*v[3];
#pragma unroll
  for (int m = 32; m >= 1; m >>= 1) { s += __shfl_xor(s, m); s2 += __shfl_xor(s2, m); }
  const int w = t >> 6;
  if ((t & 63) == 0) { red[w] = s; red[4 + w] = s2; }
  __syncthreads();
  s  = red[0] + red[1] + red[2] + red[3];
  s2 = red[4] + red[5] + red[6] + red[7];
  const float mean = s * (1.f / 1024.f);
  const float var  = s2 * (1.f / 1024.f) - mean * mean;
  const float rstd = rsqrtf(var + 1e-5f);
  us4 o;
#pragma unroll
  for (int j = 0; j < 4; ++j)
    o[j] = f2bf((v[j] - mean) * rstd * g[t * 4 + j] + bb[t * 4 + j]);
  *(us4*)(y + base + t * 4) = o;
}

// ---------------- GEMM: C[M,N] = A[M,K](bf16) @ Bt[N,K]^T(bf16) + bias ----------------
// 128x128 tile, BK=32, 4 waves, 16x16x32 MFMA. M,N multiples of 128; K multiple of 32.
// MODE 0: bf16 out; 1: bf16 relu out; 2: f32 out = res(f32) + acc + bias
template <int MODE>
__global__ __launch_bounds__(256)
void k_gemm(const unsigned short* __restrict__ A,
            const unsigned short* __restrict__ Bt,
            const float* __restrict__ bias,
            void* __restrict__ Cout,
            const float* __restrict__ res,
            int N, int K) {
  __shared__ unsigned short sA[128 * 32];
  __shared__ unsigned short sB[128 * 32];
  const int t = threadIdx.x;
  const int l = t & 63, w = t >> 6;
  const int wr = w >> 1, wc = w & 1;
  const int bx = blockIdx.x, by = blockIdx.y;

  const int srow = t >> 2;            // staging: thread t moves 16B
  const int scol = (t & 3) << 3;
  const unsigned short* gA = A  + (size_t)(by * 128 + srow) * K + scol;
  const unsigned short* gB = Bt + (size_t)(bx * 128 + srow) * K + scol;
  unsigned short* sAw0 = sA + srow * 32 + scol;
  unsigned short* sAw1 = sA + (srow + 64) * 32 + scol;
  unsigned short* sBw0 = sB + srow * 32 + scol;
  unsigned short* sBw1 = sB + (srow + 64) * 32 + scol;

  const int lr = l & 15;
  const int lk = (l >> 4) << 3;
  const unsigned short* sAr = sA + (wr * 64 + lr) * 32 + lk;
  const unsigned short* sBr = sB + (wc * 64 + lr) * 32 + lk;

  f32x4 acc[4][4];
#pragma unroll
  for (int m = 0; m < 4; ++m)
#pragma unroll
    for (int n = 0; n < 4; ++n) { acc[m][n][0]=0.f; acc[m][n][1]=0.f; acc[m][n][2]=0.f; acc[m][n][3]=0.f; }

  for (int k0 = 0; k0 < K; k0 += 32) {
    const bf16x8 a0 = *(const bf16x8*)(gA + k0);
    const bf16x8 a1 = *(const bf16x8*)(gA + (size_t)64 * K + k0);
    const bf16x8 b0 = *(const bf16x8*)(gB + k0);
    const bf16x8 b1 = *(const bf16x8*)(gB + (size_t)64 * K + k0);
    __syncthreads();
    *(bf16x8*)sAw0 = a0;
    *(bf16x8*)sAw1 = a1;
    *(bf16x8*)sBw0 = b0;
    *(bf16x8*)sBw1 = b1;
    __syncthreads();
    bf16x8 af[4], bfr[4];
#pragma unroll
    for (int m = 0; m < 4; ++m) af[m]  = *(const bf16x8*)(sAr + m * 16 * 32);
#pragma unroll
    for (int n = 0; n < 4; ++n) bfr[n] = *(const bf16x8*)(sBr + n * 16 * 32);
#pragma unroll
    for (int m = 0; m < 4; ++m)
#pragma unroll
      for (int n = 0; n < 4; ++n)
        acc[m][n] = __builtin_amdgcn_mfma_f32_16x16x32_bf16(af[m], bfr[n], acc[m][n], 0, 0, 0);
  }

  const int rq = (l >> 4) << 2;  // C/D: col = lane&15, row = (lane>>4)*4 + reg
#pragma unroll
  for (int n = 0; n < 4; ++n) {
    const int cg = bx * 128 + wc * 64 + n * 16 + lr;
    const float bv = bias[cg];
#pragma unroll
    for (int m = 0; m < 4; ++m) {
#pragma unroll
      for (int r = 0; r < 4; ++r) {
        const int rg = by * 128 + wr * 64 + m * 16 + rq + r;
        const float v = acc[m][n][r] + bv;
        if constexpr (MODE == 0) {
          ((unsigned short*)Cout)[(size_t)rg * N + cg] = f2bf(v);
        } else if constexpr (MODE == 1) {
          ((unsigned short*)Cout)[(size_t)rg * N + cg] = f2bf(v > 0.f ? v : 0.f);
        } else {
          ((float*)Cout)[(size_t)rg * N + cg] = res[(size_t)rg * N + cg] + v;
        }
      }
    }
  }
}

// ---------------- attention ----------------
// grid (Nq/64, H, B); 4 waves, 16 q-rows/wave. K/V chunk (<=176 rows) in LDS,
// online softmax; scores lane-per-key; PV row-batched with bf16 probs in LDS.
template <bool CAUSAL>
__global__ __launch_bounds__(256)
void k_attn(const unsigned short* __restrict__ Q,
            const unsigned short* __restrict__ Kb,
            const unsigned short* __restrict__ Vb,
            unsigned short* __restrict__ O,
            int kvlen) {
  constexpr int CH = 176;
  __shared__ unsigned short sK[CH * 72];
  __shared__ unsigned short sV[CH * 72];
  __shared__ unsigned short sP[4][CH * 8];
  const int b = blockIdx.z, h = blockIdx.y, q0 = blockIdx.x * 64;
  const int t = threadIdx.x, w = t >> 6, l = t & 63;

  float om[16], os[16], oa[16];
#pragma unroll
  for (int i = 0; i < 16; ++i) { om[i] = -1e30f; os[i] = 0.f; oa[i] = 0.f; }

  const int kvmax = CAUSAL ? (kvlen < q0 + 64 ? kvlen : q0 + 64) : kvlen;
  for (int c0 = 0; c0 < kvmax; c0 += CH) {
    const int cn = (kvmax - c0) < CH ? (kvmax - c0) : CH;
    __syncthreads();
    for (int e = t * 8; e < cn * 64; e += 2048) {
      const int r = e >> 6, cc = e & 63;
      const size_t g = ((size_t)(b * kvlen + c0 + r) << 10) + h * 64 + cc;
      *(bf16x8*)(sK + r * 72 + cc) = *(const bf16x8*)(Kb + g);
      *(bf16x8*)(sV + r * 72 + cc) = *(const bf16x8*)(Vb + g);
    }
    __syncthreads();

#pragma unroll
    for (int half = 0; half < 2; ++half) {
#pragma unroll
      for (int i8 = 0; i8 < 8; ++i8) {
        const int i = half * 8 + i8;
        const int qrow = q0 + w * 16 + i;
        const unsigned short* qg = Q + ((size_t)(b * 512 + qrow) << 10) + h * 64;
        bf16x8 qv[8];
#pragma unroll
        for (int d8 = 0; d8 < 8; ++d8) qv[d8] = *(const bf16x8*)(qg + d8 * 8);

        float p[4];
        float cm = -1e30f;
#pragma unroll
        for (int tt = 0; tt < 4; ++tt) {
          const int j = tt * 64 + l;
          float s = -1e30f;
          if (j < cn && (!CAUSAL || (c0 + j) <= qrow)) {
            float a = 0.f;
#pragma unroll
            for (int d8 = 0; d8 < 8; ++d8) {
              const bf16x8 kk = *(const bf16x8*)(sK + j * 72 + d8 * 8);
#pragma unroll
              for (int e2 = 0; e2 < 8; ++e2) a += bf2f(kk[e2]) * bf2f(qv[d8][e2]);
            }
            s = a * 0.125f;
          }
          p[tt] = s;
          cm = fmaxf(cm, s);
        }
#pragma unroll
        for (int m2 = 32; m2 >= 1; m2 >>= 1) cm = fmaxf(cm, __shfl_xor(cm, m2));
        const float mn = fmaxf(om[i], cm);
        const float scale = (om[i] > -1e29f) ? __expf(om[i] - mn) : 0.f;
        float ps = 0.f;
#pragma unroll
        for (int tt = 0; tt < 4; ++tt) {
          const float pv = (p[tt] > -1e29f) ? __expf(p[tt] - mn) : 0.f;
          p[tt] = pv; ps += pv;
        }
#pragma unroll
        for (int m2 = 32; m2 >= 1; m2 >>= 1) ps += __shfl_xor(ps, m2);
        os[i] = os[i] * scale + ps;
        oa[i] *= scale;
        om[i] = mn;
#pragma unroll
        for (int tt = 0; tt < 4; ++tt) {
          const int j = tt * 64 + l;
          if (j < cn) sP[w][j * 8 + i8] = f2bf(p[tt]);
        }
      }
      float a8[8];
#pragma unroll
      for (int i8 = 0; i8 < 8; ++i8) a8[i8] = 0.f;
      for (int j = 0; j < cn; ++j) {
        const float v = bf2f((short)sV[j * 72 + l]);
        const bf16x8 pr = *(const bf16x8*)(&sP[w][j * 8]);
#pragma unroll
        for (int i8 = 0; i8 < 8; ++i8) a8[i8] += bf2f(pr[i8]) * v;
      }
#pragma unroll
      for (int i8 = 0; i8 < 8; ++i8) oa[half * 8 + i8] += a8[i8];
    }
  }
#pragma unroll
  for (int i = 0; i < 16; ++i) {
    const int qrow = q0 + w * 16 + i;
    O[((size_t)(b * 512 + qrow) << 10) + h * 64 + l] = f2bf(oa[i] / os[i]);
  }
}

// ---------------- pairwise fuse gate ----------------
// pair1: acc = 0.5*softmax2(p1.c, p2.c)@[p1,p2]           (bf16 out)
// pair2: c  += bf2f(acc) + 0.5*softmax2(p1.c, p2.c)@[p1,p2] (f32 in-place)
template <int PHASE>
__global__ __launch_bounds__(256)
void k_pair(float* __restrict__ c, const unsigned short* __restrict__ p1,
            const unsigned short* __restrict__ p2, unsigned short* __restrict__ acc) {
  __shared__ float red[8];
  const size_t base = (size_t)blockIdx.x * 1024;
  const int t = threadIdx.x;
  const f32x4 cv = *(const f32x4*)(c + base + t * 4);
  const us4 u1 = *(const us4*)(p1 + base + t * 4);
  const us4 u2 = *(const us4*)(p2 + base + t * 4);
  float f1v[4], f2v[4];
  float d1 = 0.f, d2 = 0.f;
#pragma unroll
  for (int j = 0; j < 4; ++j) {
    f1v[j] = bf2f((short)u1[j]); f2v[j] = bf2f((short)u2[j]);
    d1 += cv[j] * f1v[j]; d2 += cv[j] * f2v[j];
  }
#pragma unroll
  for (int m = 32; m >= 1; m >>= 1) { d1 += __shfl_xor(d1, m); d2 += __shfl_xor(d2, m); }
  const int w = t >> 6;
  if ((t & 63) == 0) { red[w] = d1; red[4 + w] = d2; }
  __syncthreads();
  d1 = red[0] + red[1] + red[2] + red[3];
  d2 = red[4] + red[5] + red[6] + red[7];
  const float mx = fmaxf(d1, d2);
  const float e1 = __expf(d1 - mx), e2 = __expf(d2 - mx);
  const float w1 = e1 / (e1 + e2), w2 = e2 / (e1 + e2);
  if constexpr (PHASE == 1) {
    us4 o;
#pragma unroll
    for (int j = 0; j < 4; ++j) o[j] = f2bf(0.5f * (w1 * f1v[j] + w2 * f2v[j]));
    *(us4*)(acc + base + t * 4) = o;
  } else {
    const us4 ua = *(const us4*)(acc + base + t * 4);
    f32x4 o;
#pragma unroll
    for (int j = 0; j < 4; ++j)
      o[j] = cv[j] + bf2f((short)ua[j]) + 0.5f * (w1 * f1v[j] + w2 * f2v[j]);
    *(f32x4*)(c + base + t * 4) = o;
  }
}

// ---------------- host ----------------
extern "C" void kernel_launch(void* const* d_in, const int* in_sizes, int n_in,
                              void* d_out, int out_size, void* d_ws, size_t ws_size,
                              hipStream_t stream) {
  (void)in_sizes; (void)n_in; (void)out_size; (void)ws_size;
  const float* captions      = (const float*)d_in[0];
  const float* cpt_words     = (const float*)d_in[1];
  const float* senti_words   = (const float*)d_in[2];
  const float* region_feats  = (const float*)d_in[3];
  const float* spatial_feats = (const float*)d_in[4];
  const float* att_W  = (const float*)d_in[5];
  const float* att_b  = (const float*)d_in[6];
  const float* ffn_W1 = (const float*)d_in[7];
  const float* ffn_b1 = (const float*)d_in[8];
  const float* ffn_W2 = (const float*)d_in[9];
  const float* ffn_b2 = (const float*)d_in[10];
  const float* ln_g   = (const float*)d_in[11];
  const float* ln_b   = (const float*)d_in[12];
  // d_in[13] seq_masks: tril by construction -> causal handled analytically.

  // ---- ws layout: 174.25 MiB total ----
  char* ws = (char*)d_ws;
  size_t off = 0;
  auto alloc = [&](size_t bytes) {
    char* p = ws + off;
    off += (bytes + 255) & ~(size_t)255;
    return p;
  };
  const size_t ACT2 = (size_t)8192 * 1024 * 2;   // 16 MiB bf16 activation
  unsigned short* hbuf = (unsigned short*)alloc(ACT2);  // LN out; also attn out (xbuf)
  unsigned short* qbuf = (unsigned short*)alloc(ACT2);
  unsigned short* kbuf = (unsigned short*)alloc(ACT2);  // f1 spans kbuf..bp2 (64 MiB)
  unsigned short* vbuf = (unsigned short*)alloc(ACT2);
  unsigned short* bp1  = (unsigned short*)alloc(ACT2);  // branch output A of pair
  unsigned short* bp2  = (unsigned short*)alloc(ACT2);  // branch output B of pair
  float*          c1   = (float*)alloc((size_t)8192 * 1024 * 4);  // residual stream
  unsigned short* accb = (unsigned short*)alloc(ACT2);  // 0.5*sem contribution
  unsigned short* wAttB= (unsigned short*)alloc((size_t)4 * 1024 * 1024 * 2);  // 8 MiB
  unsigned short* wF1t = (unsigned short*)alloc((size_t)4096 * 1024 * 2);
  unsigned short* wF2t = (unsigned short*)alloc((size_t)1024 * 4096 * 2);
  unsigned short* padw = (unsigned short*)alloc((size_t)3200 * 1024 * 2);  // shared K/V src
  unsigned short* xbuf = hbuf;   // attn output aliases LN buffer (dead by then)
  unsigned short* f1   = kbuf;   // FFN mid [8192,4096] bf16 = kbuf+vbuf+bp1+bp2

  const dim3 tb32(32, 8);
  k_transpose_cvt<<<dim3(128, 32, 1), tb32, 0, stream>>>(ffn_W1, wF1t, 1024, 4096);
  k_transpose_cvt<<<dim3(32, 128, 1), tb32, 0, stream>>>(ffn_W2, wF2t, 4096, 1024);

  const size_t MS = (size_t)1024 * 1024;
  auto Wi = [&](int j) { return wAttB + (size_t)j * MS; };
  auto Bv = [&](int i, int j) { return att_b + (size_t)(i * 4 + j) * 1024; };
  const dim3 gBig(8, 64);
  const dim3 gAttn(8, 16, 16);

  // ---- self attention (causal) ----
  k_transpose_cvt<<<dim3(32, 32, 4), tb32, 0, stream>>>(att_W, wAttB, 1024, 1024);
  k_ln<<<8192, 256, 0, stream>>>(captions, ln_g, ln_b, hbuf);
  k_gemm<0><<<gBig, 256, 0, stream>>>(hbuf, Wi(0), Bv(0,0), qbuf, nullptr, 1024, 1024);
  k_gemm<0><<<gBig, 256, 0, stream>>>(hbuf, Wi(1), Bv(0,1), kbuf, nullptr, 1024, 1024);
  k_gemm<0><<<gBig, 256, 0, stream>>>(hbuf, Wi(2), Bv(0,2), vbuf, nullptr, 1024, 1024);
  k_attn<true><<<gAttn, 256, 0, stream>>>(qbuf, kbuf, vbuf, xbuf, 512);
  k_gemm<2><<<gBig, 256, 0, stream>>>(xbuf, Wi(3), Bv(0,3), c1, captions, 1024, 1024);

  // ---- branch helper pattern (sequential, buffers reused) ----
  // cpt (att 1) -> bp1
  k_transpose_cvt<<<dim3(32, 32, 4), tb32, 0, stream>>>(att_W + 4 * MS, wAttB, 1024, 1024);
  k_cvt_pad<<<512, 256, 0, stream>>>(cpt_words, padw, 400);
  k_ln<<<8192, 256, 0, stream>>>(c1, ln_g + 1024, ln_b + 1024, hbuf);
  k_gemm<0><<<gBig, 256, 0, stream>>>(hbuf, Wi(0), Bv(1,0), qbuf, nullptr, 1024, 1024);
  k_gemm<0><<<dim3(8,4), 256, 0, stream>>>(padw, Wi(1), Bv(1,1), kbuf, nullptr, 1024, 1024);
  k_gemm<0><<<dim3(8,4), 256, 0, stream>>>(padw, Wi(2), Bv(1,2), vbuf, nullptr, 1024, 1024);
  k_attn<false><<<gAttn, 256, 0, stream>>>(qbuf, kbuf, vbuf, xbuf, 25);
  k_gemm<0><<<gBig, 256, 0, stream>>>(xbuf, Wi(3), Bv(1,3), bp1, nullptr, 1024, 1024);

  // sen (att 2) -> bp2
  k_transpose_cvt<<<dim3(32, 32, 4), tb32, 0, stream>>>(att_W + 8 * MS, wAttB, 1024, 1024);
  k_cvt_pad<<<512, 256, 0, stream>>>(senti_words, padw, 400);
  k_ln<<<8192, 256, 0, stream>>>(c1, ln_g + 2048, ln_b + 2048, hbuf);
  k_gemm<0><<<gBig, 256, 0, stream>>>(hbuf, Wi(0), Bv(2,0), qbuf, nullptr, 1024, 1024);
  k_gemm<0><<<dim3(8,4), 256, 0, stream>>>(padw, Wi(1), Bv(2,1), kbuf, nullptr, 1024, 1024);
  k_gemm<0><<<dim3(8,4), 256, 0, stream>>>(padw, Wi(2), Bv(2,2), vbuf, nullptr, 1024, 1024);
  k_attn<false><<<gAttn, 256, 0, stream>>>(qbuf, kbuf, vbuf, xbuf, 25);
  k_gemm<0><<<gBig, 256, 0, stream>>>(xbuf, Wi(3), Bv(2,3), bp2, nullptr, 1024, 1024);

  k_pair<1><<<8192, 256, 0, stream>>>(c1, bp1, bp2, accb);

  // region (att 3) -> bp1
  k_transpose_cvt<<<dim3(32, 32, 4), tb32, 0, stream>>>(att_W + 12 * MS, wAttB, 1024, 1024);
  k_cvt_pad<<<3200, 256, 0, stream>>>(region_feats, padw, 3136);
  k_ln<<<8192, 256, 0, stream>>>(c1, ln_g + 3072, ln_b + 3072, hbuf);
  k_gemm<0><<<gBig, 256, 0, stream>>>(hbuf, Wi(0), Bv(3,0), qbuf, nullptr, 1024, 1024);
  k_gemm<0><<<dim3(8,25), 256, 0, stream>>>(padw, Wi(1), Bv(3,1), kbuf, nullptr, 1024, 1024);
  k_gemm<0><<<dim3(8,25), 256, 0, stream>>>(padw, Wi(2), Bv(3,2), vbuf, nullptr, 1024, 1024);
  k_attn<false><<<gAttn, 256, 0, stream>>>(qbuf, kbuf, vbuf, xbuf, 196);
  k_gemm<0><<<gBig, 256, 0, stream>>>(xbuf, Wi(3), Bv(3,3), bp1, nullptr, 1024, 1024);

  // spatial (att 4) -> bp2
  k_transpose_cvt<<<dim3(32, 32, 4), tb32, 0, stream>>>(att_W + 16 * MS, wAttB, 1024, 1024);
  k_cvt_pad<<<3200, 256, 0, stream>>>(spatial_feats, padw, 3136);
  k_ln<<<8192, 256, 0, stream>>>(c1, ln_g + 4096, ln_b + 4096, hbuf);
  k_gemm<0><<<gBig, 256, 0, stream>>>(hbuf, Wi(0), Bv(4,0), qbuf, nullptr, 1024, 1024);
  k_gemm<0><<<dim3(8,25), 256, 0, stream>>>(padw, Wi(1), Bv(4,1), kbuf, nullptr, 1024, 1024);
  k_gemm<0><<<dim3(8,25), 256, 0, stream>>>(padw, Wi(2), Bv(4,2), vbuf, nullptr, 1024, 1024);
  k_attn<false><<<gAttn, 256, 0, stream>>>(qbuf, kbuf, vbuf, xbuf, 196);
  k_gemm<0><<<gBig, 256, 0, stream>>>(xbuf, Wi(3), Bv(4,3), bp2, nullptr, 1024, 1024);

  k_pair<2><<<8192, 256, 0, stream>>>(c1, bp1, bp2, accb);  // c1 = fuse (in-place)

  // ---- FFN ----
  k_ln<<<8192, 256, 0, stream>>>(c1, ln_g + 5120, ln_b + 5120, hbuf);
  k_gemm<1><<<dim3(32, 64), 256, 0, stream>>>(hbuf, wF1t, ffn_b1, f1, nullptr, 4096, 1024);
  k_gemm<2><<<gBig, 256, 0, stream>>>(f1, wF2t, ffn_b2, (float*)d_out, c1, 1024, 4096);
}

// Round 3
// 1131.817 us; speedup vs baseline: 2.3838x; 2.3838x over previous
//
#include <hip/hip_runtime.h>

// DecoderLayer (B=16, N1=512, D=1024, H=16, Dk=64, FF=4096)
// Round 3: MFMA flash attention (replaces scalar-VALU k_attn, which was
// 2.1ms of 2.7ms). GEMM path unchanged from round 2 (passing, absmax 0.031).
//  - attention: per block 4 waves x 16 q-rows, KV chunks of 64.
//    QK^T and PV via mfma_f32_16x16x32_bf16; K in LDS [kv][64] XOR-swizzled
//    (T2: elem ^= (row&7)<<3); V staged transposed sVt[d][kv] (same swizzle,
//    rotated scalar writes -> ~2-way); softmax in-register (shfl within
//    16-lane groups); P through per-wave swizzled LDS tile.
//  - causal handled analytically (seq_masks is tril); kv masked by kvlen.

typedef __attribute__((ext_vector_type(4))) float          f32x4;
typedef __attribute__((ext_vector_type(8))) short          bf16x8;
typedef __attribute__((ext_vector_type(4))) unsigned short us4;

#define DEV static __device__ __forceinline__

DEV float bf2f(short h) {
  union { unsigned u; float f; } c;
  c.u = ((unsigned)(unsigned short)h) << 16;
  return c.f;
}
DEV unsigned short f2bf(float f) {  // round-to-nearest-even
  union { float f; unsigned u; } c; c.f = f;
  return (unsigned short)((c.u + 0x7fffu + ((c.u >> 16) & 1u)) >> 16);
}

// ---------------- transpose + f32->bf16 convert (weights) ----------------
__global__ __launch_bounds__(256)
void k_transpose_cvt(const float* __restrict__ src, unsigned short* __restrict__ dst,
                     int R, int C) {
  __shared__ float tile[32][33];
  const size_t mo = (size_t)blockIdx.z * R * C;
  src += mo; dst += mo;
  const int c0 = blockIdx.x * 32, r0 = blockIdx.y * 32;
  const int tx = threadIdx.x, ty = threadIdx.y;
#pragma unroll
  for (int i = 0; i < 32; i += 8)
    tile[ty + i][tx] = src[(size_t)(r0 + ty + i) * C + (c0 + tx)];
  __syncthreads();
#pragma unroll
  for (int i = 0; i < 32; i += 8)
    dst[(size_t)(c0 + ty + i) * R + (r0 + tx)] = f2bf(tile[tx][ty + i]);
}

// ---------------- f32 -> bf16 convert with zero row padding ----------------
__global__ __launch_bounds__(256)
void k_cvt_pad(const float* __restrict__ src, unsigned short* __restrict__ dst, int rows) {
  const int r = blockIdx.x;
  const int c = threadIdx.x * 4;
  us4 o;
  if (r < rows) {
    f32x4 v = *(const f32x4*)(src + (size_t)r * 1024 + c);
    o[0] = f2bf(v[0]); o[1] = f2bf(v[1]); o[2] = f2bf(v[2]); o[3] = f2bf(v[3]);
  } else {
    o[0] = 0; o[1] = 0; o[2] = 0; o[3] = 0;
  }
  *(us4*)(dst + (size_t)r * 1024 + c) = o;
}

// ---------------- LayerNorm (D=1024), f32 in -> bf16 out ----------------
__global__ __launch_bounds__(256)
void k_ln(const float* __restrict__ x, const float* __restrict__ g,
          const float* __restrict__ bb, unsigned short* __restrict__ y) {
  __shared__ float red[8];
  const size_t base = (size_t)blockIdx.x * 1024;
  const int t = threadIdx.x;
  f32x4 v = *(const f32x4*)(x + base + t * 4);
  float s  = v[0] + v[1] + v[2] + v[3];
  float s2 = v[0]*v[0] + v[1]*v[1] + v[2]*v[2] + v[3]*v[3];
#pragma unroll
  for (int m = 32; m >= 1; m >>= 1) { s += __shfl_xor(s, m); s2 += __shfl_xor(s2, m); }
  const int w = t >> 6;
  if ((t & 63) == 0) { red[w] = s; red[4 + w] = s2; }
  __syncthreads();
  s  = red[0] + red[1] + red[2] + red[3];
  s2 = red[4] + red[5] + red[6] + red[7];
  const float mean = s * (1.f / 1024.f);
  const float var  = s2 * (1.f / 1024.f) - mean * mean;
  const float rstd = rsqrtf(var + 1e-5f);
  us4 o;
#pragma unroll
  for (int j = 0; j < 4; ++j)
    o[j] = f2bf((v[j] - mean) * rstd * g[t * 4 + j] + bb[t * 4 + j]);
  *(us4*)(y + base + t * 4) = o;
}

// ---------------- GEMM: C[M,N] = A[M,K](bf16) @ Bt[N,K]^T(bf16) + bias ----------------
// MODE 0: bf16 out; 1: bf16 relu out; 2: f32 out = res(f32) + acc + bias
template <int MODE>
__global__ __launch_bounds__(256)
void k_gemm(const unsigned short* __restrict__ A,
            const unsigned short* __restrict__ Bt,
            const float* __restrict__ bias,
            void* __restrict__ Cout,
            const float* __restrict__ res,
            int N, int K) {
  __shared__ unsigned short sA[128 * 32];
  __shared__ unsigned short sB[128 * 32];
  const int t = threadIdx.x;
  const int l = t & 63, w = t >> 6;
  const int wr = w >> 1, wc = w & 1;
  const int bx = blockIdx.x, by = blockIdx.y;

  const int srow = t >> 2;
  const int scol = (t & 3) << 3;
  const unsigned short* gA = A  + (size_t)(by * 128 + srow) * K + scol;
  const unsigned short* gB = Bt + (size_t)(bx * 128 + srow) * K + scol;
  unsigned short* sAw0 = sA + srow * 32 + scol;
  unsigned short* sAw1 = sA + (srow + 64) * 32 + scol;
  unsigned short* sBw0 = sB + srow * 32 + scol;
  unsigned short* sBw1 = sB + (srow + 64) * 32 + scol;

  const int lr = l & 15;
  const int lk = (l >> 4) << 3;
  const unsigned short* sAr = sA + (wr * 64 + lr) * 32 + lk;
  const unsigned short* sBr = sB + (wc * 64 + lr) * 32 + lk;

  f32x4 acc[4][4];
#pragma unroll
  for (int m = 0; m < 4; ++m)
#pragma unroll
    for (int n = 0; n < 4; ++n) { acc[m][n][0]=0.f; acc[m][n][1]=0.f; acc[m][n][2]=0.f; acc[m][n][3]=0.f; }

  for (int k0 = 0; k0 < K; k0 += 32) {
    const bf16x8 a0 = *(const bf16x8*)(gA + k0);
    const bf16x8 a1 = *(const bf16x8*)(gA + (size_t)64 * K + k0);
    const bf16x8 b0 = *(const bf16x8*)(gB + k0);
    const bf16x8 b1 = *(const bf16x8*)(gB + (size_t)64 * K + k0);
    __syncthreads();
    *(bf16x8*)sAw0 = a0;
    *(bf16x8*)sAw1 = a1;
    *(bf16x8*)sBw0 = b0;
    *(bf16x8*)sBw1 = b1;
    __syncthreads();
    bf16x8 af[4], bfr[4];
#pragma unroll
    for (int m = 0; m < 4; ++m) af[m]  = *(const bf16x8*)(sAr + m * 16 * 32);
#pragma unroll
    for (int n = 0; n < 4; ++n) bfr[n] = *(const bf16x8*)(sBr + n * 16 * 32);
#pragma unroll
    for (int m = 0; m < 4; ++m)
#pragma unroll
      for (int n = 0; n < 4; ++n)
        acc[m][n] = __builtin_amdgcn_mfma_f32_16x16x32_bf16(af[m], bfr[n], acc[m][n], 0, 0, 0);
  }

  const int rq = (l >> 4) << 2;  // C/D: col = lane&15, row = (lane>>4)*4 + reg
#pragma unroll
  for (int n = 0; n < 4; ++n) {
    const int cg = bx * 128 + wc * 64 + n * 16 + lr;
    const float bv = bias[cg];
#pragma unroll
    for (int m = 0; m < 4; ++m) {
#pragma unroll
      for (int r = 0; r < 4; ++r) {
        const int rg = by * 128 + wr * 64 + m * 16 + rq + r;
        const float v = acc[m][n][r] + bv;
        if constexpr (MODE == 0) {
          ((unsigned short*)Cout)[(size_t)rg * N + cg] = f2bf(v);
        } else if constexpr (MODE == 1) {
          ((unsigned short*)Cout)[(size_t)rg * N + cg] = f2bf(v > 0.f ? v : 0.f);
        } else {
          ((float*)Cout)[(size_t)rg * N + cg] = res[(size_t)rg * N + cg] + v;
        }
      }
    }
  }
}

// ---------------- MFMA flash attention ----------------
// grid (Nq/64, H, B), 256 threads (4 waves x 16 q-rows). KV chunks of 64.
// S = Q.K^T via mfma (A=Q regs, B=K from swizzled LDS); online softmax in-reg;
// P -> bf16 via per-wave swizzled LDS tile; O += P.V via mfma (B=V^T LDS).
template <bool CAUSAL>
__global__ __launch_bounds__(256)
void k_attn_mfma(const unsigned short* __restrict__ Q,
                 const unsigned short* __restrict__ Kb,
                 const unsigned short* __restrict__ Vb,
                 unsigned short* __restrict__ O,
                 int kvlen) {
  __shared__ __align__(16) unsigned short sK [64 * 64];
  __shared__ __align__(16) unsigned short sVt[64 * 64];
  __shared__ __align__(16) unsigned short sP [4][16 * 64];
  const int b = blockIdx.z, h = blockIdx.y, q0 = blockIdx.x * 64;
  const int t = threadIdx.x, w = t >> 6, l = t & 63;
  const int cc = l & 15, g = l >> 4;     // frag col / k-group
  const int gk = g << 3;                  // k-offset within 32 (g*8)

  // Q A-fragments, hoisted: row = cc (within wave tile), d = ks*32 + gk + j
  const unsigned short* qg =
      Q + ((size_t)(b * 512 + q0 + w * 16 + cc) << 10) + h * 64 + gk;
  bf16x8 qf[2];
  qf[0] = *(const bf16x8*)(qg);
  qf[1] = *(const bf16x8*)(qg + 32);

  f32x4 accO[4];
#pragma unroll
  for (int n = 0; n < 4; ++n) { accO[n][0]=0.f; accO[n][1]=0.f; accO[n][2]=0.f; accO[n][3]=0.f; }
  float om[4], ls[4];
#pragma unroll
  for (int r = 0; r < 4; ++r) { om[r] = -1e30f; ls[r] = 0.f; }

  // staging map: thread t -> row sr (0..63), col block sc (0/16/32/48)
  const int sr = t >> 2;
  const int sc = (t & 3) << 4;
  const int kx = (sr & 7) << 3;                 // K-row swizzle term
  const size_t stg0 = ((size_t)(b * kvlen + sr) << 10) + h * 64 + sc;

  const int kvmax = CAUSAL ? (q0 + 64) : kvlen;
  for (int c0 = 0; c0 < kvmax; c0 += 64) {
    __syncthreads();
    const size_t gr = stg0 + ((size_t)c0 << 10);
    const bf16x8 k0 = *(const bf16x8*)(Kb + gr);
    const bf16x8 k1 = *(const bf16x8*)(Kb + gr + 8);
    const bf16x8 v0 = *(const bf16x8*)(Vb + gr);
    const bf16x8 v1 = *(const bf16x8*)(Vb + gr + 8);
    // K row-major, swizzled: elem col ^= (row&7)<<3
    *(bf16x8*)(sK + sr * 64 + (sc ^ kx))       = k0;
    *(bf16x8*)(sK + sr * 64 + ((sc + 8) ^ kx)) = k1;
    // V transposed: sVt[d][kv], swizzled; rotated scalar writes (2-way banks)
#pragma unroll
    for (int i = 0; i < 8; ++i) {
      const int j  = (i + 2 * (t & 3)) & 7;
      const int xj = sr ^ (j << 3);             // (d&7)==j for both d0 and d1
      sVt[(sc + j)     * 64 + xj] = (unsigned short)v0[j];
      sVt[(sc + 8 + j) * 64 + xj] = (unsigned short)v1[j];
    }
    __syncthreads();

    // ---- S = Q.K^T (16q x 64kv): B-frag col=kv=n*16+cc, k=d ----
    f32x4 S[4];
#pragma unroll
    for (int n = 0; n < 4; ++n) { S[n][0]=0.f; S[n][1]=0.f; S[n][2]=0.f; S[n][3]=0.f; }
#pragma unroll
    for (int n = 0; n < 4; ++n) {
      const int kvr = (n * 16 + cc) * 64;
      const int sxk = (cc & 7) << 3;
#pragma unroll
      for (int ks = 0; ks < 2; ++ks) {
        const bf16x8 kf = *(const bf16x8*)(sK + kvr + ((ks * 32 + gk) ^ sxk));
        S[n] = __builtin_amdgcn_mfma_f32_16x16x32_bf16(qf[ks], kf, S[n], 0, 0, 0);
      }
    }

    // ---- mask + scale + row-max (rows = g*4+r, cols = n*16+cc) ----
    float cm[4];
#pragma unroll
    for (int r = 0; r < 4; ++r) cm[r] = -1e30f;
#pragma unroll
    for (int n = 0; n < 4; ++n) {
      const int kvg = c0 + n * 16 + cc;
#pragma unroll
      for (int r = 0; r < 4; ++r) {
        const int qrow = q0 + w * 16 + g * 4 + r;
        const bool valid = (kvg < kvlen) && (!CAUSAL || kvg <= qrow);
        const float sv = valid ? S[n][r] * 0.125f : -1e30f;
        S[n][r] = sv;
        cm[r] = fmaxf(cm[r], sv);
      }
    }
#pragma unroll
    for (int m2 = 1; m2 <= 8; m2 <<= 1)
#pragma unroll
      for (int r = 0; r < 4; ++r) cm[r] = fmaxf(cm[r], __shfl_xor(cm[r], m2));

    float sc4[4], ps[4];
#pragma unroll
    for (int r = 0; r < 4; ++r) {
      const float mn = fmaxf(om[r], cm[r]);
      sc4[r] = __expf(om[r] - mn);
      om[r] = mn;
      ps[r] = 0.f;
    }
    // ---- P = exp(S-m) -> bf16 to sP (row q=g*4+r, swizzled) ----
#pragma unroll
    for (int n = 0; n < 4; ++n) {
#pragma unroll
      for (int r = 0; r < 4; ++r) {
        const float pv = __expf(S[n][r] - om[r]);
        ps[r] += pv;
        const int q = g * 4 + r;
        sP[w][q * 64 + ((n * 16 + cc) ^ ((q & 7) << 3))] = f2bf(pv);
      }
    }
#pragma unroll
    for (int m2 = 1; m2 <= 8; m2 <<= 1)
#pragma unroll
      for (int r = 0; r < 4; ++r) ps[r] += __shfl_xor(ps[r], m2);
#pragma unroll
    for (int r = 0; r < 4; ++r) ls[r] = ls[r] * sc4[r] + ps[r];
#pragma unroll
    for (int n = 0; n < 4; ++n)
#pragma unroll
      for (int r = 0; r < 4; ++r) accO[n][r] *= sc4[r];

    // ---- O += P.V : A-frag P(row=cc), B-frag V^T(col=d=n*16+cc) ----
    const int pxk = (cc & 7) << 3;
#pragma unroll
    for (int ks = 0; ks < 2; ++ks) {
      const bf16x8 pf = *(const bf16x8*)(&sP[w][cc * 64 + ((ks * 32 + gk) ^ pxk)]);
#pragma unroll
      for (int n = 0; n < 4; ++n) {
        const int d = n * 16 + cc;
        const bf16x8 vf = *(const bf16x8*)(sVt + d * 64 + ((ks * 32 + gk) ^ ((d & 7) << 3)));
        accO[n] = __builtin_amdgcn_mfma_f32_16x16x32_bf16(pf, vf, accO[n], 0, 0, 0);
      }
    }
  }

  // ---- write O (rows g*4+r, cols n*16+cc) ----
#pragma unroll
  for (int r = 0; r < 4; ++r) {
    const float inv = 1.f / ls[r];
    const size_t ob = ((size_t)(b * 512 + q0 + w * 16 + g * 4 + r) << 10) + h * 64;
#pragma unroll
    for (int n = 0; n < 4; ++n)
      O[ob + n * 16 + cc] = f2bf(accO[n][r] * inv);
  }
}

// ---------------- pairwise fuse gate ----------------
template <int PHASE>
__global__ __launch_bounds__(256)
void k_pair(float* __restrict__ c, const unsigned short* __restrict__ p1,
            const unsigned short* __restrict__ p2, unsigned short* __restrict__ acc) {
  __shared__ float red[8];
  const size_t base = (size_t)blockIdx.x * 1024;
  const int t = threadIdx.x;
  const f32x4 cv = *(const f32x4*)(c + base + t * 4);
  const us4 u1 = *(const us4*)(p1 + base + t * 4);
  const us4 u2 = *(const us4*)(p2 + base + t * 4);
  float f1v[4], f2v[4];
  float d1 = 0.f, d2 = 0.f;
#pragma unroll
  for (int j = 0; j < 4; ++j) {
    f1v[j] = bf2f((short)u1[j]); f2v[j] = bf2f((short)u2[j]);
    d1 += cv[j] * f1v[j]; d2 += cv[j] * f2v[j];
  }
#pragma unroll
  for (int m = 32; m >= 1; m >>= 1) { d1 += __shfl_xor(d1, m); d2 += __shfl_xor(d2, m); }
  const int w = t >> 6;
  if ((t & 63) == 0) { red[w] = d1; red[4 + w] = d2; }
  __syncthreads();
  d1 = red[0] + red[1] + red[2] + red[3];
  d2 = red[4] + red[5] + red[6] + red[7];
  const float mx = fmaxf(d1, d2);
  const float e1 = __expf(d1 - mx), e2 = __expf(d2 - mx);
  const float w1 = e1 / (e1 + e2), w2 = e2 / (e1 + e2);
  if constexpr (PHASE == 1) {
    us4 o;
#pragma unroll
    for (int j = 0; j < 4; ++j) o[j] = f2bf(0.5f * (w1 * f1v[j] + w2 * f2v[j]));
    *(us4*)(acc + base + t * 4) = o;
  } else {
    const us4 ua = *(const us4*)(acc + base + t * 4);
    f32x4 o;
#pragma unroll
    for (int j = 0; j < 4; ++j)
      o[j] = cv[j] + bf2f((short)ua[j]) + 0.5f * (w1 * f1v[j] + w2 * f2v[j]);
    *(f32x4*)(c + base + t * 4) = o;
  }
}

// ---------------- host ----------------
extern "C" void kernel_launch(void* const* d_in, const int* in_sizes, int n_in,
                              void* d_out, int out_size, void* d_ws, size_t ws_size,
                              hipStream_t stream) {
  (void)in_sizes; (void)n_in; (void)out_size; (void)ws_size;
  const float* captions      = (const float*)d_in[0];
  const float* cpt_words     = (const float*)d_in[1];
  const float* senti_words   = (const float*)d_in[2];
  const float* region_feats  = (const float*)d_in[3];
  const float* spatial_feats = (const float*)d_in[4];
  const float* att_W  = (const float*)d_in[5];
  const float* att_b  = (const float*)d_in[6];
  const float* ffn_W1 = (const float*)d_in[7];
  const float* ffn_b1 = (const float*)d_in[8];
  const float* ffn_W2 = (const float*)d_in[9];
  const float* ffn_b2 = (const float*)d_in[10];
  const float* ln_g   = (const float*)d_in[11];
  const float* ln_b   = (const float*)d_in[12];
  // d_in[13] seq_masks: tril by construction -> causal handled analytically.

  char* ws = (char*)d_ws;
  size_t off = 0;
  auto alloc = [&](size_t bytes) {
    char* p = ws + off;
    off += (bytes + 255) & ~(size_t)255;
    return p;
  };
  const size_t ACT2 = (size_t)8192 * 1024 * 2;
  unsigned short* hbuf = (unsigned short*)alloc(ACT2);
  unsigned short* qbuf = (unsigned short*)alloc(ACT2);
  unsigned short* kbuf = (unsigned short*)alloc(ACT2);
  unsigned short* vbuf = (unsigned short*)alloc(ACT2);
  unsigned short* bp1  = (unsigned short*)alloc(ACT2);
  unsigned short* bp2  = (unsigned short*)alloc(ACT2);
  float*          c1   = (float*)alloc((size_t)8192 * 1024 * 4);
  unsigned short* accb = (unsigned short*)alloc(ACT2);
  unsigned short* wAttB= (unsigned short*)alloc((size_t)4 * 1024 * 1024 * 2);
  unsigned short* wF1t = (unsigned short*)alloc((size_t)4096 * 1024 * 2);
  unsigned short* wF2t = (unsigned short*)alloc((size_t)1024 * 4096 * 2);
  unsigned short* padw = (unsigned short*)alloc((size_t)3200 * 1024 * 2);
  unsigned short* xbuf = hbuf;   // attn out aliases LN buffer (dead by then)
  unsigned short* f1   = kbuf;   // FFN mid [8192,4096] bf16 = kbuf+vbuf+bp1+bp2

  const dim3 tb32(32, 8);
  k_transpose_cvt<<<dim3(128, 32, 1), tb32, 0, stream>>>(ffn_W1, wF1t, 1024, 4096);
  k_transpose_cvt<<<dim3(32, 128, 1), tb32, 0, stream>>>(ffn_W2, wF2t, 4096, 1024);

  const size_t MS = (size_t)1024 * 1024;
  auto Wi = [&](int j) { return wAttB + (size_t)j * MS; };
  auto Bv = [&](int i, int j) { return att_b + (size_t)(i * 4 + j) * 1024; };
  const dim3 gBig(8, 64);
  const dim3 gAttn(8, 16, 16);

  // ---- self attention (causal) ----
  k_transpose_cvt<<<dim3(32, 32, 4), tb32, 0, stream>>>(att_W, wAttB, 1024, 1024);
  k_ln<<<8192, 256, 0, stream>>>(captions, ln_g, ln_b, hbuf);
  k_gemm<0><<<gBig, 256, 0, stream>>>(hbuf, Wi(0), Bv(0,0), qbuf, nullptr, 1024, 1024);
  k_gemm<0><<<gBig, 256, 0, stream>>>(hbuf, Wi(1), Bv(0,1), kbuf, nullptr, 1024, 1024);
  k_gemm<0><<<gBig, 256, 0, stream>>>(hbuf, Wi(2), Bv(0,2), vbuf, nullptr, 1024, 1024);
  k_attn_mfma<true><<<gAttn, 256, 0, stream>>>(qbuf, kbuf, vbuf, xbuf, 512);
  k_gemm<2><<<gBig, 256, 0, stream>>>(xbuf, Wi(3), Bv(0,3), c1, captions, 1024, 1024);

  // ---- cpt (att 1) -> bp1 ----
  k_transpose_cvt<<<dim3(32, 32, 4), tb32, 0, stream>>>(att_W + 4 * MS, wAttB, 1024, 1024);
  k_cvt_pad<<<512, 256, 0, stream>>>(cpt_words, padw, 400);
  k_ln<<<8192, 256, 0, stream>>>(c1, ln_g + 1024, ln_b + 1024, hbuf);
  k_gemm<0><<<gBig, 256, 0, stream>>>(hbuf, Wi(0), Bv(1,0), qbuf, nullptr, 1024, 1024);
  k_gemm<0><<<dim3(8,4), 256, 0, stream>>>(padw, Wi(1), Bv(1,1), kbuf, nullptr, 1024, 1024);
  k_gemm<0><<<dim3(8,4), 256, 0, stream>>>(padw, Wi(2), Bv(1,2), vbuf, nullptr, 1024, 1024);
  k_attn_mfma<false><<<gAttn, 256, 0, stream>>>(qbuf, kbuf, vbuf, xbuf, 25);
  k_gemm<0><<<gBig, 256, 0, stream>>>(xbuf, Wi(3), Bv(1,3), bp1, nullptr, 1024, 1024);

  // ---- sen (att 2) -> bp2 ----
  k_transpose_cvt<<<dim3(32, 32, 4), tb32, 0, stream>>>(att_W + 8 * MS, wAttB, 1024, 1024);
  k_cvt_pad<<<512, 256, 0, stream>>>(senti_words, padw, 400);
  k_ln<<<8192, 256, 0, stream>>>(c1, ln_g + 2048, ln_b + 2048, hbuf);
  k_gemm<0><<<gBig, 256, 0, stream>>>(hbuf, Wi(0), Bv(2,0), qbuf, nullptr, 1024, 1024);
  k_gemm<0><<<dim3(8,4), 256, 0, stream>>>(padw, Wi(1), Bv(2,1), kbuf, nullptr, 1024, 1024);
  k_gemm<0><<<dim3(8,4), 256, 0, stream>>>(padw, Wi(2), Bv(2,2), vbuf, nullptr, 1024, 1024);
  k_attn_mfma<false><<<gAttn, 256, 0, stream>>>(qbuf, kbuf, vbuf, xbuf, 25);
  k_gemm<0><<<gBig, 256, 0, stream>>>(xbuf, Wi(3), Bv(2,3), bp2, nullptr, 1024, 1024);

  k_pair<1><<<8192, 256, 0, stream>>>(c1, bp1, bp2, accb);

  // ---- region (att 3) -> bp1 ----
  k_transpose_cvt<<<dim3(32, 32, 4), tb32, 0, stream>>>(att_W + 12 * MS, wAttB, 1024, 1024);
  k_cvt_pad<<<3200, 256, 0, stream>>>(region_feats, padw, 3136);
  k_ln<<<8192, 256, 0, stream>>>(c1, ln_g + 3072, ln_b + 3072, hbuf);
  k_gemm<0><<<gBig, 256, 0, stream>>>(hbuf, Wi(0), Bv(3,0), qbuf, nullptr, 1024, 1024);
  k_gemm<0><<<dim3(8,25), 256, 0, stream>>>(padw, Wi(1), Bv(3,1), kbuf, nullptr, 1024, 1024);
  k_gemm<0><<<dim3(8,25), 256, 0, stream>>>(padw, Wi(2), Bv(3,2), vbuf, nullptr, 1024, 1024);
  k_attn_mfma<false><<<gAttn, 256, 0, stream>>>(qbuf, kbuf, vbuf, xbuf, 196);
  k_gemm<0><<<gBig, 256, 0, stream>>>(xbuf, Wi(3), Bv(3,3), bp1, nullptr, 1024, 1024);

  // ---- spatial (att 4) -> bp2 ----
  k_transpose_cvt<<<dim3(32, 32, 4), tb32, 0, stream>>>(att_W + 16 * MS, wAttB, 1024, 1024);
  k_cvt_pad<<<3200, 256, 0, stream>>>(spatial_feats, padw, 3136);
  k_ln<<<8192, 256, 0, stream>>>(c1, ln_g + 4096, ln_b + 4096, hbuf);
  k_gemm<0><<<gBig, 256, 0, stream>>>(hbuf, Wi(0), Bv(4,0), qbuf, nullptr, 1024, 1024);
  k_gemm<0><<<dim3(8,25), 256, 0, stream>>>(padw, Wi(1), Bv(4,1), kbuf, nullptr, 1024, 1024);
  k_gemm<0><<<dim3(8,25), 256, 0, stream>>>(padw, Wi(2), Bv(4,2), vbuf, nullptr, 1024, 1024);
  k_attn_mfma<false><<<gAttn, 256, 0, stream>>>(qbuf, kbuf, vbuf, xbuf, 196);
  k_gemm<0><<<gBig, 256, 0, stream>>>(xbuf, Wi(3), Bv(4,3), bp2, nullptr, 1024, 1024);

  k_pair<2><<<8192, 256, 0, stream>>>(c1, bp1, bp2, accb);  // c1 = fuse (in-place)

  // ---- FFN ----
  k_ln<<<8192, 256, 0, stream>>>(c1, ln_g + 5120, ln_b + 5120, hbuf);
  k_gemm<1><<<dim3(32, 64), 256, 0, stream>>>(hbuf, wF1t, ffn_b1, f1, nullptr, 4096, 1024);
  k_gemm<2><<<gBig, 256, 0, stream>>>(f1, wF2t, ffn_b2, (float*)d_out, c1, 1024, 4096);
}

// Round 4
// 1096.715 us; speedup vs baseline: 2.4601x; 1.0320x over previous
//
#include <hip/hip_runtime.h>

// DecoderLayer (B=16, N1=512, D=1024, H=16, Dk=64, FF=4096)
// Round 4: GEMM upgrade (attention/LN/fuse unchanged from round 3, passing).
//  - k_gemm: 1D grid + bijective XCD swizzle (T1) so each XCD's L2 keeps its
//    8 A-panels + W panel (kills the 290MB/dispatch A re-fetch seen in rocprof);
//    global_load_lds width=16 staging (m97 structure: linear LDS dest =
//    wave-uniform base + lane*16B, per-lane global src) replaces reg staging.
//  - bank conflicts in [128][32] LDS retained (m97-level; 256^2 8-phase is the
//    next rung if GEMM still dominates).

typedef __attribute__((ext_vector_type(4))) float          f32x4;
typedef __attribute__((ext_vector_type(8))) short          bf16x8;
typedef __attribute__((ext_vector_type(4))) unsigned short us4;

#define DEV static __device__ __forceinline__

DEV float bf2f(short h) {
  union { unsigned u; float f; } c;
  c.u = ((unsigned)(unsigned short)h) << 16;
  return c.f;
}
DEV unsigned short f2bf(float f) {  // round-to-nearest-even
  union { float f; unsigned u; } c; c.f = f;
  return (unsigned short)((c.u + 0x7fffu + ((c.u >> 16) & 1u)) >> 16);
}

// async global->LDS, 16B per lane; LDS dest is wave-uniform base + lane*16B
DEV void gll16(const unsigned short* g, unsigned short* l) {
  __builtin_amdgcn_global_load_lds((const __attribute__((address_space(1))) void*)g,
                                   (__attribute__((address_space(3))) void*)l,
                                   16, 0, 0);
}

// ---------------- transpose + f32->bf16 convert (weights) ----------------
__global__ __launch_bounds__(256)
void k_transpose_cvt(const float* __restrict__ src, unsigned short* __restrict__ dst,
                     int R, int C) {
  __shared__ float tile[32][33];
  const size_t mo = (size_t)blockIdx.z * R * C;
  src += mo; dst += mo;
  const int c0 = blockIdx.x * 32, r0 = blockIdx.y * 32;
  const int tx = threadIdx.x, ty = threadIdx.y;
#pragma unroll
  for (int i = 0; i < 32; i += 8)
    tile[ty + i][tx] = src[(size_t)(r0 + ty + i) * C + (c0 + tx)];
  __syncthreads();
#pragma unroll
  for (int i = 0; i < 32; i += 8)
    dst[(size_t)(c0 + ty + i) * R + (r0 + tx)] = f2bf(tile[tx][ty + i]);
}

// ---------------- f32 -> bf16 convert with zero row padding ----------------
__global__ __launch_bounds__(256)
void k_cvt_pad(const float* __restrict__ src, unsigned short* __restrict__ dst, int rows) {
  const int r = blockIdx.x;
  const int c = threadIdx.x * 4;
  us4 o;
  if (r < rows) {
    f32x4 v = *(const f32x4*)(src + (size_t)r * 1024 + c);
    o[0] = f2bf(v[0]); o[1] = f2bf(v[1]); o[2] = f2bf(v[2]); o[3] = f2bf(v[3]);
  } else {
    o[0] = 0; o[1] = 0; o[2] = 0; o[3] = 0;
  }
  *(us4*)(dst + (size_t)r * 1024 + c) = o;
}

// ---------------- LayerNorm (D=1024), f32 in -> bf16 out ----------------
__global__ __launch_bounds__(256)
void k_ln(const float* __restrict__ x, const float* __restrict__ g,
          const float* __restrict__ bb, unsigned short* __restrict__ y) {
  __shared__ float red[8];
  const size_t base = (size_t)blockIdx.x * 1024;
  const int t = threadIdx.x;
  f32x4 v = *(const f32x4*)(x + base + t * 4);
  float s  = v[0] + v[1] + v[2] + v[3];
  float s2 = v[0]*v[0] + v[1]*v[1] + v[2]*v[2] + v[3]*v[3];
#pragma unroll
  for (int m = 32; m >= 1; m >>= 1) { s += __shfl_xor(s, m); s2 += __shfl_xor(s2, m); }
  const int w = t >> 6;
  if ((t & 63) == 0) { red[w] = s; red[4 + w] = s2; }
  __syncthreads();
  s  = red[0] + red[1] + red[2] + red[3];
  s2 = red[4] + red[5] + red[6] + red[7];
  const float mean = s * (1.f / 1024.f);
  const float var  = s2 * (1.f / 1024.f) - mean * mean;
  const float rstd = rsqrtf(var + 1e-5f);
  us4 o;
#pragma unroll
  for (int j = 0; j < 4; ++j)
    o[j] = f2bf((v[j] - mean) * rstd * g[t * 4 + j] + bb[t * 4 + j]);
  *(us4*)(y + base + t * 4) = o;
}

// ---------------- GEMM: C[M,N] = A[M,K](bf16) @ Bt[N,K]^T(bf16) + bias ----------------
// 1D grid (nwg = nbx*nby, nwg%8==0), bijective XCD swizzle, bx-fastest.
// 128x128 tile, BK=32, 4 waves, global_load_lds staging.
// MODE 0: bf16 out; 1: bf16 relu out; 2: f32 out = res(f32) + acc + bias
template <int MODE>
__global__ __launch_bounds__(256)
void k_gemm(const unsigned short* __restrict__ A,
            const unsigned short* __restrict__ Bt,
            const float* __restrict__ bias,
            void* __restrict__ Cout,
            const float* __restrict__ res,
            int N, int K, int nbx) {
  __shared__ unsigned short sA[128 * 32];
  __shared__ unsigned short sB[128 * 32];
  const int t = threadIdx.x;
  const int l = t & 63, w = t >> 6;
  const int wr = w >> 1, wc = w & 1;

  // XCD swizzle: hardware block hb -> logical tile; XCD p = hb%8 gets a
  // contiguous logical chunk (bx-fastest => 8 consecutive A-panels/XCD).
  const int nwg = gridDim.x;
  const int q8  = nwg >> 3;
  const int swz = (blockIdx.x & 7) * q8 + (blockIdx.x >> 3);
  const int bx = swz % nbx, by = swz / nbx;

  // staging: wave w covers tile rows [w*32, w*32+32); two 16-row issues each
  // for A and B. LDS dest wave-uniform; HW adds lane*16B (= row l/4, col (l%4)*8).
  const int glr = l >> 2;             // +row within 16-row group
  const int glc = (l & 3) << 3;       // elem col
  const unsigned short* gA = A  + (size_t)(by * 128 + w * 32 + glr) * K + glc;
  const unsigned short* gB = Bt + (size_t)(bx * 128 + w * 32 + glr) * K + glc;
  unsigned short* sA0 = sA + (w * 32) * 32;
  unsigned short* sA1 = sA + (w * 32 + 16) * 32;
  unsigned short* sB0 = sB + (w * 32) * 32;
  unsigned short* sB1 = sB + (w * 32 + 16) * 32;
  const size_t r16 = (size_t)16 * K;

  const int lr = l & 15;
  const int lk = (l >> 4) << 3;
  const unsigned short* sAr = sA + (wr * 64 + lr) * 32 + lk;
  const unsigned short* sBr = sB + (wc * 64 + lr) * 32 + lk;

  f32x4 acc[4][4];
#pragma unroll
  for (int m = 0; m < 4; ++m)
#pragma unroll
    for (int n = 0; n < 4; ++n) { acc[m][n][0]=0.f; acc[m][n][1]=0.f; acc[m][n][2]=0.f; acc[m][n][3]=0.f; }

  for (int k0 = 0; k0 < K; k0 += 32) {
    __syncthreads();                      // readers of prev tile done
    gll16(gA + k0,       sA0);
    gll16(gA + r16 + k0, sA1);
    gll16(gB + k0,       sB0);
    gll16(gB + r16 + k0, sB1);
    __syncthreads();                      // compiler drains vmcnt(0) here
    bf16x8 af[4], bfr[4];
#pragma unroll
    for (int m = 0; m < 4; ++m) af[m]  = *(const bf16x8*)(sAr + m * 16 * 32);
#pragma unroll
    for (int n = 0; n < 4; ++n) bfr[n] = *(const bf16x8*)(sBr + n * 16 * 32);
#pragma unroll
    for (int m = 0; m < 4; ++m)
#pragma unroll
      for (int n = 0; n < 4; ++n)
        acc[m][n] = __builtin_amdgcn_mfma_f32_16x16x32_bf16(af[m], bfr[n], acc[m][n], 0, 0, 0);
  }

  const int rq = (l >> 4) << 2;  // C/D: col = lane&15, row = (lane>>4)*4 + reg
#pragma unroll
  for (int n = 0; n < 4; ++n) {
    const int cg = bx * 128 + wc * 64 + n * 16 + lr;
    const float bv = bias[cg];
#pragma unroll
    for (int m = 0; m < 4; ++m) {
#pragma unroll
      for (int r = 0; r < 4; ++r) {
        const int rg = by * 128 + wr * 64 + m * 16 + rq + r;
        const float v = acc[m][n][r] + bv;
        if constexpr (MODE == 0) {
          ((unsigned short*)Cout)[(size_t)rg * N + cg] = f2bf(v);
        } else if constexpr (MODE == 1) {
          ((unsigned short*)Cout)[(size_t)rg * N + cg] = f2bf(v > 0.f ? v : 0.f);
        } else {
          ((float*)Cout)[(size_t)rg * N + cg] = res[(size_t)rg * N + cg] + v;
        }
      }
    }
  }
}

// ---------------- MFMA flash attention (unchanged from round 3) ----------------
template <bool CAUSAL>
__global__ __launch_bounds__(256)
void k_attn_mfma(const unsigned short* __restrict__ Q,
                 const unsigned short* __restrict__ Kb,
                 const unsigned short* __restrict__ Vb,
                 unsigned short* __restrict__ O,
                 int kvlen) {
  __shared__ __align__(16) unsigned short sK [64 * 64];
  __shared__ __align__(16) unsigned short sVt[64 * 64];
  __shared__ __align__(16) unsigned short sP [4][16 * 64];
  const int b = blockIdx.z, h = blockIdx.y, q0 = blockIdx.x * 64;
  const int t = threadIdx.x, w = t >> 6, l = t & 63;
  const int cc = l & 15, g = l >> 4;
  const int gk = g << 3;

  const unsigned short* qg =
      Q + ((size_t)(b * 512 + q0 + w * 16 + cc) << 10) + h * 64 + gk;
  bf16x8 qf[2];
  qf[0] = *(const bf16x8*)(qg);
  qf[1] = *(const bf16x8*)(qg + 32);

  f32x4 accO[4];
#pragma unroll
  for (int n = 0; n < 4; ++n) { accO[n][0]=0.f; accO[n][1]=0.f; accO[n][2]=0.f; accO[n][3]=0.f; }
  float om[4], ls[4];
#pragma unroll
  for (int r = 0; r < 4; ++r) { om[r] = -1e30f; ls[r] = 0.f; }

  const int sr = t >> 2;
  const int sc = (t & 3) << 4;
  const int kx = (sr & 7) << 3;
  const size_t stg0 = ((size_t)(b * kvlen + sr) << 10) + h * 64 + sc;

  const int kvmax = CAUSAL ? (q0 + 64) : kvlen;
  for (int c0 = 0; c0 < kvmax; c0 += 64) {
    __syncthreads();
    const size_t gr = stg0 + ((size_t)c0 << 10);
    const bf16x8 k0 = *(const bf16x8*)(Kb + gr);
    const bf16x8 k1 = *(const bf16x8*)(Kb + gr + 8);
    const bf16x8 v0 = *(const bf16x8*)(Vb + gr);
    const bf16x8 v1 = *(const bf16x8*)(Vb + gr + 8);
    *(bf16x8*)(sK + sr * 64 + (sc ^ kx))       = k0;
    *(bf16x8*)(sK + sr * 64 + ((sc + 8) ^ kx)) = k1;
#pragma unroll
    for (int i = 0; i < 8; ++i) {
      const int j  = (i + 2 * (t & 3)) & 7;
      const int xj = sr ^ (j << 3);
      sVt[(sc + j)     * 64 + xj] = (unsigned short)v0[j];
      sVt[(sc + 8 + j) * 64 + xj] = (unsigned short)v1[j];
    }
    __syncthreads();

    f32x4 S[4];
#pragma unroll
    for (int n = 0; n < 4; ++n) { S[n][0]=0.f; S[n][1]=0.f; S[n][2]=0.f; S[n][3]=0.f; }
#pragma unroll
    for (int n = 0; n < 4; ++n) {
      const int kvr = (n * 16 + cc) * 64;
      const int sxk = (cc & 7) << 3;
#pragma unroll
      for (int ks = 0; ks < 2; ++ks) {
        const bf16x8 kf = *(const bf16x8*)(sK + kvr + ((ks * 32 + gk) ^ sxk));
        S[n] = __builtin_amdgcn_mfma_f32_16x16x32_bf16(qf[ks], kf, S[n], 0, 0, 0);
      }
    }

    float cm[4];
#pragma unroll
    for (int r = 0; r < 4; ++r) cm[r] = -1e30f;
#pragma unroll
    for (int n = 0; n < 4; ++n) {
      const int kvg = c0 + n * 16 + cc;
#pragma unroll
      for (int r = 0; r < 4; ++r) {
        const int qrow = q0 + w * 16 + g * 4 + r;
        const bool valid = (kvg < kvlen) && (!CAUSAL || kvg <= qrow);
        const float sv = valid ? S[n][r] * 0.125f : -1e30f;
        S[n][r] = sv;
        cm[r] = fmaxf(cm[r], sv);
      }
    }
#pragma unroll
    for (int m2 = 1; m2 <= 8; m2 <<= 1)
#pragma unroll
      for (int r = 0; r < 4; ++r) cm[r] = fmaxf(cm[r], __shfl_xor(cm[r], m2));

    float sc4[4], ps[4];
#pragma unroll
    for (int r = 0; r < 4; ++r) {
      const float mn = fmaxf(om[r], cm[r]);
      sc4[r] = __expf(om[r] - mn);
      om[r] = mn;
      ps[r] = 0.f;
    }
#pragma unroll
    for (int n = 0; n < 4; ++n) {
#pragma unroll
      for (int r = 0; r < 4; ++r) {
        const float pv = __expf(S[n][r] - om[r]);
        ps[r] += pv;
        const int q = g * 4 + r;
        sP[w][q * 64 + ((n * 16 + cc) ^ ((q & 7) << 3))] = f2bf(pv);
      }
    }
#pragma unroll
    for (int m2 = 1; m2 <= 8; m2 <<= 1)
#pragma unroll
      for (int r = 0; r < 4; ++r) ps[r] += __shfl_xor(ps[r], m2);
#pragma unroll
    for (int r = 0; r < 4; ++r) ls[r] = ls[r] * sc4[r] + ps[r];
#pragma unroll
    for (int n = 0; n < 4; ++n)
#pragma unroll
      for (int r = 0; r < 4; ++r) accO[n][r] *= sc4[r];

    const int pxk = (cc & 7) << 3;
#pragma unroll
    for (int ks = 0; ks < 2; ++ks) {
      const bf16x8 pf = *(const bf16x8*)(&sP[w][cc * 64 + ((ks * 32 + gk) ^ pxk)]);
#pragma unroll
      for (int n = 0; n < 4; ++n) {
        const int d = n * 16 + cc;
        const bf16x8 vf = *(const bf16x8*)(sVt + d * 64 + ((ks * 32 + gk) ^ ((d & 7) << 3)));
        accO[n] = __builtin_amdgcn_mfma_f32_16x16x32_bf16(pf, vf, accO[n], 0, 0, 0);
      }
    }
  }

#pragma unroll
  for (int r = 0; r < 4; ++r) {
    const float inv = 1.f / ls[r];
    const size_t ob = ((size_t)(b * 512 + q0 + w * 16 + g * 4 + r) << 10) + h * 64;
#pragma unroll
    for (int n = 0; n < 4; ++n)
      O[ob + n * 16 + cc] = f2bf(accO[n][r] * inv);
  }
}

// ---------------- pairwise fuse gate ----------------
template <int PHASE>
__global__ __launch_bounds__(256)
void k_pair(float* __restrict__ c, const unsigned short* __restrict__ p1,
            const unsigned short* __restrict__ p2, unsigned short* __restrict__ acc) {
  __shared__ float red[8];
  const size_t base = (size_t)blockIdx.x * 1024;
  const int t = threadIdx.x;
  const f32x4 cv = *(const f32x4*)(c + base + t * 4);
  const us4 u1 = *(const us4*)(p1 + base + t * 4);
  const us4 u2 = *(const us4*)(p2 + base + t * 4);
  float f1v[4], f2v[4];
  float d1 = 0.f, d2 = 0.f;
#pragma unroll
  for (int j = 0; j < 4; ++j) {
    f1v[j] = bf2f((short)u1[j]); f2v[j] = bf2f((short)u2[j]);
    d1 += cv[j] * f1v[j]; d2 += cv[j] * f2v[j];
  }
#pragma unroll
  for (int m = 32; m >= 1; m >>= 1) { d1 += __shfl_xor(d1, m); d2 += __shfl_xor(d2, m); }
  const int w = t >> 6;
  if ((t & 63) == 0) { red[w] = d1; red[4 + w] = d2; }
  __syncthreads();
  d1 = red[0] + red[1] + red[2] + red[3];
  d2 = red[4] + red[5] + red[6] + red[7];
  const float mx = fmaxf(d1, d2);
  const float e1 = __expf(d1 - mx), e2 = __expf(d2 - mx);
  const float w1 = e1 / (e1 + e2), w2 = e2 / (e1 + e2);
  if constexpr (PHASE == 1) {
    us4 o;
#pragma unroll
    for (int j = 0; j < 4; ++j) o[j] = f2bf(0.5f * (w1 * f1v[j] + w2 * f2v[j]));
    *(us4*)(acc + base + t * 4) = o;
  } else {
    const us4 ua = *(const us4*)(acc + base + t * 4);
    f32x4 o;
#pragma unroll
    for (int j = 0; j < 4; ++j)
      o[j] = cv[j] + bf2f((short)ua[j]) + 0.5f * (w1 * f1v[j] + w2 * f2v[j]);
    *(f32x4*)(c + base + t * 4) = o;
  }
}

// ---------------- host ----------------
extern "C" void kernel_launch(void* const* d_in, const int* in_sizes, int n_in,
                              void* d_out, int out_size, void* d_ws, size_t ws_size,
                              hipStream_t stream) {
  (void)in_sizes; (void)n_in; (void)out_size; (void)ws_size;
  const float* captions      = (const float*)d_in[0];
  const float* cpt_words     = (const float*)d_in[1];
  const float* senti_words   = (const float*)d_in[2];
  const float* region_feats  = (const float*)d_in[3];
  const float* spatial_feats = (const float*)d_in[4];
  const float* att_W  = (const float*)d_in[5];
  const float* att_b  = (const float*)d_in[6];
  const float* ffn_W1 = (const float*)d_in[7];
  const float* ffn_b1 = (const float*)d_in[8];
  const float* ffn_W2 = (const float*)d_in[9];
  const float* ffn_b2 = (const float*)d_in[10];
  const float* ln_g   = (const float*)d_in[11];
  const float* ln_b   = (const float*)d_in[12];
  // d_in[13] seq_masks: tril by construction -> causal handled analytically.

  char* ws = (char*)d_ws;
  size_t off = 0;
  auto alloc = [&](size_t bytes) {
    char* p = ws + off;
    off += (bytes + 255) & ~(size_t)255;
    return p;
  };
  const size_t ACT2 = (size_t)8192 * 1024 * 2;
  unsigned short* hbuf = (unsigned short*)alloc(ACT2);
  unsigned short* qbuf = (unsigned short*)alloc(ACT2);
  unsigned short* kbuf = (unsigned short*)alloc(ACT2);
  unsigned short* vbuf = (unsigned short*)alloc(ACT2);
  unsigned short* bp1  = (unsigned short*)alloc(ACT2);
  unsigned short* bp2  = (unsigned short*)alloc(ACT2);
  float*          c1   = (float*)alloc((size_t)8192 * 1024 * 4);
  unsigned short* accb = (unsigned short*)alloc(ACT2);
  unsigned short* wAttB= (unsigned short*)alloc((size_t)4 * 1024 * 1024 * 2);
  unsigned short* wF1t = (unsigned short*)alloc((size_t)4096 * 1024 * 2);
  unsigned short* wF2t = (unsigned short*)alloc((size_t)1024 * 4096 * 2);
  unsigned short* padw = (unsigned short*)alloc((size_t)3200 * 1024 * 2);
  unsigned short* xbuf = hbuf;   // attn out aliases LN buffer (dead by then)
  unsigned short* f1   = kbuf;   // FFN mid [8192,4096] bf16 = kbuf+vbuf+bp1+bp2

  const dim3 tb32(32, 8);
  k_transpose_cvt<<<dim3(128, 32, 1), tb32, 0, stream>>>(ffn_W1, wF1t, 1024, 4096);
  k_transpose_cvt<<<dim3(32, 128, 1), tb32, 0, stream>>>(ffn_W2, wF2t, 4096, 1024);

  const size_t MS = (size_t)1024 * 1024;
  auto Wi = [&](int j) { return wAttB + (size_t)j * MS; };
  auto Bv = [&](int i, int j) { return att_b + (size_t)(i * 4 + j) * 1024; };
  const dim3 gAttn(8, 16, 16);
  // 1D grids: big square = 512 (nbx 8), cpt/sen KV = 32, reg/spa KV = 200,
  // FFN1 = 2048 (nbx 32), FFN2 = 512. All %8 == 0 (bijective XCD swizzle).

  // ---- self attention (causal) ----
  k_transpose_cvt<<<dim3(32, 32, 4), tb32, 0, stream>>>(att_W, wAttB, 1024, 1024);
  k_ln<<<8192, 256, 0, stream>>>(captions, ln_g, ln_b, hbuf);
  k_gemm<0><<<512, 256, 0, stream>>>(hbuf, Wi(0), Bv(0,0), qbuf, nullptr, 1024, 1024, 8);
  k_gemm<0><<<512, 256, 0, stream>>>(hbuf, Wi(1), Bv(0,1), kbuf, nullptr, 1024, 1024, 8);
  k_gemm<0><<<512, 256, 0, stream>>>(hbuf, Wi(2), Bv(0,2), vbuf, nullptr, 1024, 1024, 8);
  k_attn_mfma<true><<<gAttn, 256, 0, stream>>>(qbuf, kbuf, vbuf, xbuf, 512);
  k_gemm<2><<<512, 256, 0, stream>>>(xbuf, Wi(3), Bv(0,3), c1, captions, 1024, 1024, 8);

  // ---- cpt (att 1) -> bp1 ----
  k_transpose_cvt<<<dim3(32, 32, 4), tb32, 0, stream>>>(att_W + 4 * MS, wAttB, 1024, 1024);
  k_cvt_pad<<<512, 256, 0, stream>>>(cpt_words, padw, 400);
  k_ln<<<8192, 256, 0, stream>>>(c1, ln_g + 1024, ln_b + 1024, hbuf);
  k_gemm<0><<<512, 256, 0, stream>>>(hbuf, Wi(0), Bv(1,0), qbuf, nullptr, 1024, 1024, 8);
  k_gemm<0><<<32,  256, 0, stream>>>(padw, Wi(1), Bv(1,1), kbuf, nullptr, 1024, 1024, 8);
  k_gemm<0><<<32,  256, 0, stream>>>(padw, Wi(2), Bv(1,2), vbuf, nullptr, 1024, 1024, 8);
  k_attn_mfma<false><<<gAttn, 256, 0, stream>>>(qbuf, kbuf, vbuf, xbuf, 25);
  k_gemm<0><<<512, 256, 0, stream>>>(xbuf, Wi(3), Bv(1,3), bp1, nullptr, 1024, 1024, 8);

  // ---- sen (att 2) -> bp2 ----
  k_transpose_cvt<<<dim3(32, 32, 4), tb32, 0, stream>>>(att_W + 8 * MS, wAttB, 1024, 1024);
  k_cvt_pad<<<512, 256, 0, stream>>>(senti_words, padw, 400);
  k_ln<<<8192, 256, 0, stream>>>(c1, ln_g + 2048, ln_b + 2048, hbuf);
  k_gemm<0><<<512, 256, 0, stream>>>(hbuf, Wi(0), Bv(2,0), qbuf, nullptr, 1024, 1024, 8);
  k_gemm<0><<<32,  256, 0, stream>>>(padw, Wi(1), Bv(2,1), kbuf, nullptr, 1024, 1024, 8);
  k_gemm<0><<<32,  256, 0, stream>>>(padw, Wi(2), Bv(2,2), vbuf, nullptr, 1024, 1024, 8);
  k_attn_mfma<false><<<gAttn, 256, 0, stream>>>(qbuf, kbuf, vbuf, xbuf, 25);
  k_gemm<0><<<512, 256, 0, stream>>>(xbuf, Wi(3), Bv(2,3), bp2, nullptr, 1024, 1024, 8);

  k_pair<1><<<8192, 256, 0, stream>>>(c1, bp1, bp2, accb);

  // ---- region (att 3) -> bp1 ----
  k_transpose_cvt<<<dim3(32, 32, 4), tb32, 0, stream>>>(att_W + 12 * MS, wAttB, 1024, 1024);
  k_cvt_pad<<<3200, 256, 0, stream>>>(region_feats, padw, 3136);
  k_ln<<<8192, 256, 0, stream>>>(c1, ln_g + 3072, ln_b + 3072, hbuf);
  k_gemm<0><<<512, 256, 0, stream>>>(hbuf, Wi(0), Bv(3,0), qbuf, nullptr, 1024, 1024, 8);
  k_gemm<0><<<200, 256, 0, stream>>>(padw, Wi(1), Bv(3,1), kbuf, nullptr, 1024, 1024, 8);
  k_gemm<0><<<200, 256, 0, stream>>>(padw, Wi(2), Bv(3,2), vbuf, nullptr, 1024, 1024, 8);
  k_attn_mfma<false><<<gAttn, 256, 0, stream>>>(qbuf, kbuf, vbuf, xbuf, 196);
  k_gemm<0><<<512, 256, 0, stream>>>(xbuf, Wi(3), Bv(3,3), bp1, nullptr, 1024, 1024, 8);

  // ---- spatial (att 4) -> bp2 ----
  k_transpose_cvt<<<dim3(32, 32, 4), tb32, 0, stream>>>(att_W + 16 * MS, wAttB, 1024, 1024);
  k_cvt_pad<<<3200, 256, 0, stream>>>(spatial_feats, padw, 3136);
  k_ln<<<8192, 256, 0, stream>>>(c1, ln_g + 4096, ln_b + 4096, hbuf);
  k_gemm<0><<<512, 256, 0, stream>>>(hbuf, Wi(0), Bv(4,0), qbuf, nullptr, 1024, 1024, 8);
  k_gemm<0><<<200, 256, 0, stream>>>(padw, Wi(1), Bv(4,1), kbuf, nullptr, 1024, 1024, 8);
  k_gemm<0><<<200, 256, 0, stream>>>(padw, Wi(2), Bv(4,2), vbuf, nullptr, 1024, 1024, 8);
  k_attn_mfma<false><<<gAttn, 256, 0, stream>>>(qbuf, kbuf, vbuf, xbuf, 196);
  k_gemm<0><<<512, 256, 0, stream>>>(xbuf, Wi(4 - 1), Bv(4,3), bp2, nullptr, 1024, 1024, 8);

  k_pair<2><<<8192, 256, 0, stream>>>(c1, bp1, bp2, accb);  // c1 = fuse (in-place)

  // ---- FFN ----
  k_ln<<<8192, 256, 0, stream>>>(c1, ln_g + 5120, ln_b + 5120, hbuf);
  k_gemm<1><<<2048, 256, 0, stream>>>(hbuf, wF1t, ffn_b1, f1, nullptr, 4096, 1024, 32);
  k_gemm<2><<<512,  256, 0, stream>>>(f1, wF2t, ffn_b2, (float*)d_out, c1, 1024, 4096, 8);
}

// Round 5
// 973.754 us; speedup vs baseline: 2.7707x; 1.1263x over previous
//
#include <hip/hip_runtime.h>

// DecoderLayer (B=16, N1=512, D=1024, H=16, Dk=64, FF=4096)
// Round 5: latency-structure round (round-4 counters: GEMMs latency-bound,
// MfmaUtil 22%, HBM 12.5% after XCD swizzle fixed traffic).
//  - k_gemm: T3-min 2-phase double-buffered K-loop (STAGE(next) issued before
//    compute(cur); ONE __syncthreads() per K-step whose implicit vmcnt(0)
//    drain covers the staged loads). 32KB LDS. T2/T5 omitted (null at 2ph).
//  - self QKV fused into one N=3072 GEMM (1536 blocks, 6/CU); branch K/V
//    fused into N=2048 GEMMs. Attention takes q/kv stride args.
//  - ws 170.75 MiB: accb shares storage with wF1t/wF2t (FFN transposes moved
//    after k_pair<2>).

typedef __attribute__((ext_vector_type(4))) float          f32x4;
typedef __attribute__((ext_vector_type(8))) short          bf16x8;
typedef __attribute__((ext_vector_type(4))) unsigned short us4;

#define DEV static __device__ __forceinline__

DEV float bf2f(short h) {
  union { unsigned u; float f; } c;
  c.u = ((unsigned)(unsigned short)h) << 16;
  return c.f;
}
DEV unsigned short f2bf(float f) {  // round-to-nearest-even
  union { float f; unsigned u; } c; c.f = f;
  return (unsigned short)((c.u + 0x7fffu + ((c.u >> 16) & 1u)) >> 16);
}

// async global->LDS, 16B per lane; LDS dest is wave-uniform base + lane*16B
DEV void gll16(const unsigned short* g, unsigned short* l) {
  __builtin_amdgcn_global_load_lds((const __attribute__((address_space(1))) void*)g,
                                   (__attribute__((address_space(3))) void*)l,
                                   16, 0, 0);
}

// ---------------- transpose + f32->bf16 convert (weights) ----------------
__global__ __launch_bounds__(256)
void k_transpose_cvt(const float* __restrict__ src, unsigned short* __restrict__ dst,
                     int R, int C) {
  __shared__ float tile[32][33];
  const size_t mo = (size_t)blockIdx.z * R * C;
  src += mo; dst += mo;
  const int c0 = blockIdx.x * 32, r0 = blockIdx.y * 32;
  const int tx = threadIdx.x, ty = threadIdx.y;
#pragma unroll
  for (int i = 0; i < 32; i += 8)
    tile[ty + i][tx] = src[(size_t)(r0 + ty + i) * C + (c0 + tx)];
  __syncthreads();
#pragma unroll
  for (int i = 0; i < 32; i += 8)
    dst[(size_t)(c0 + ty + i) * R + (r0 + tx)] = f2bf(tile[tx][ty + i]);
}

// ---------------- f32 -> bf16 convert with zero row padding ----------------
__global__ __launch_bounds__(256)
void k_cvt_pad(const float* __restrict__ src, unsigned short* __restrict__ dst, int rows) {
  const int r = blockIdx.x;
  const int c = threadIdx.x * 4;
  us4 o;
  if (r < rows) {
    f32x4 v = *(const f32x4*)(src + (size_t)r * 1024 + c);
    o[0] = f2bf(v[0]); o[1] = f2bf(v[1]); o[2] = f2bf(v[2]); o[3] = f2bf(v[3]);
  } else {
    o[0] = 0; o[1] = 0; o[2] = 0; o[3] = 0;
  }
  *(us4*)(dst + (size_t)r * 1024 + c) = o;
}

// ---------------- LayerNorm (D=1024), f32 in -> bf16 out ----------------
__global__ __launch_bounds__(256)
void k_ln(const float* __restrict__ x, const float* __restrict__ g,
          const float* __restrict__ bb, unsigned short* __restrict__ y) {
  __shared__ float red[8];
  const size_t base = (size_t)blockIdx.x * 1024;
  const int t = threadIdx.x;
  f32x4 v = *(const f32x4*)(x + base + t * 4);
  float s  = v[0] + v[1] + v[2] + v[3];
  float s2 = v[0]*v[0] + v[1]*v[1] + v[2]*v[2] + v[3]*v[3];
#pragma unroll
  for (int m = 32; m >= 1; m >>= 1) { s += __shfl_xor(s, m); s2 += __shfl_xor(s2, m); }
  const int w = t >> 6;
  if ((t & 63) == 0) { red[w] = s; red[4 + w] = s2; }
  __syncthreads();
  s  = red[0] + red[1] + red[2] + red[3];
  s2 = red[4] + red[5] + red[6] + red[7];
  const float mean = s * (1.f / 1024.f);
  const float var  = s2 * (1.f / 1024.f) - mean * mean;
  const float rstd = rsqrtf(var + 1e-5f);
  us4 o;
#pragma unroll
  for (int j = 0; j < 4; ++j)
    o[j] = f2bf((v[j] - mean) * rstd * g[t * 4 + j] + bb[t * 4 + j]);
  *(us4*)(y + base + t * 4) = o;
}

// ---------------- GEMM: C[M,N] = A[M,K](bf16) @ Bt[N,K]^T(bf16) + bias ----------------
// 1D grid (nwg%8==0), bijective XCD swizzle, bx-fastest. 128x128 tile, BK=32,
// 4 waves, 2-phase double-buffered global_load_lds staging (T3-min: stage next
// before compute cur; one __syncthreads per K-step drains vmcnt+lgkmcnt).
// MODE 0: bf16 out; 1: bf16 relu out; 2: f32 out = res(f32) + acc + bias
template <int MODE>
__global__ __launch_bounds__(256)
void k_gemm(const unsigned short* __restrict__ A,
            const unsigned short* __restrict__ Bt,
            const float* __restrict__ bias,
            void* __restrict__ Cout,
            const float* __restrict__ res,
            int N, int K, int nbx) {
  __shared__ unsigned short sA[2][128 * 32];
  __shared__ unsigned short sB[2][128 * 32];
  const int t = threadIdx.x;
  const int l = t & 63, w = t >> 6;
  const int wr = w >> 1, wc = w & 1;

  const int nwg = gridDim.x;
  const int q8  = nwg >> 3;
  const int swz = (blockIdx.x & 7) * q8 + (blockIdx.x >> 3);
  const int bx = swz % nbx, by = swz / nbx;

  // staging: wave w covers tile rows [w*32, w*32+32); 2 issues each for A,B.
  const int glr = l >> 2;
  const int glc = (l & 3) << 3;
  const unsigned short* gA = A  + (size_t)(by * 128 + w * 32 + glr) * K + glc;
  const unsigned short* gB = Bt + (size_t)(bx * 128 + w * 32 + glr) * K + glc;
  const size_t r16 = (size_t)16 * K;
  const int wofs = w * 32 * 32;          // wave LDS base (elements)

  const int lr = l & 15;
  const int lk = (l >> 4) << 3;

  f32x4 acc[4][4];
#pragma unroll
  for (int m = 0; m < 4; ++m)
#pragma unroll
    for (int n = 0; n < 4; ++n) { acc[m][n][0]=0.f; acc[m][n][1]=0.f; acc[m][n][2]=0.f; acc[m][n][3]=0.f; }

  auto stage = [&](int buf, int k0) {
    gll16(gA + k0,       sA[buf] + wofs);
    gll16(gA + r16 + k0, sA[buf] + wofs + 512);
    gll16(gB + k0,       sB[buf] + wofs);
    gll16(gB + r16 + k0, sB[buf] + wofs + 512);
  };
  auto compute = [&](int buf) {
    const unsigned short* sAr = sA[buf] + (wr * 64 + lr) * 32 + lk;
    const unsigned short* sBr = sB[buf] + (wc * 64 + lr) * 32 + lk;
    bf16x8 af[4], bfr[4];
#pragma unroll
    for (int m = 0; m < 4; ++m) af[m]  = *(const bf16x8*)(sAr + m * 16 * 32);
#pragma unroll
    for (int n = 0; n < 4; ++n) bfr[n] = *(const bf16x8*)(sBr + n * 16 * 32);
#pragma unroll
    for (int m = 0; m < 4; ++m)
#pragma unroll
      for (int n = 0; n < 4; ++n)
        acc[m][n] = __builtin_amdgcn_mfma_f32_16x16x32_bf16(af[m], bfr[n], acc[m][n], 0, 0, 0);
  };

  stage(0, 0);
  __syncthreads();                       // drains vmcnt(0): tile 0 ready
  int cur = 0;
  for (int k0 = 32; k0 < K; k0 += 32) {
    stage(cur ^ 1, k0);                  // next tile in flight during compute
    compute(cur);
    __syncthreads();                     // drains vmcnt(0)+lgkmcnt(0)
    cur ^= 1;
  }
  compute(cur);

  const int rq = (l >> 4) << 2;  // C/D: col = lane&15, row = (lane>>4)*4 + reg
#pragma unroll
  for (int n = 0; n < 4; ++n) {
    const int cg = bx * 128 + wc * 64 + n * 16 + lr;
    const float bv = bias[cg];
#pragma unroll
    for (int m = 0; m < 4; ++m) {
#pragma unroll
      for (int r = 0; r < 4; ++r) {
        const int rg = by * 128 + wr * 64 + m * 16 + rq + r;
        const float v = acc[m][n][r] + bv;
        if constexpr (MODE == 0) {
          ((unsigned short*)Cout)[(size_t)rg * N + cg] = f2bf(v);
        } else if constexpr (MODE == 1) {
          ((unsigned short*)Cout)[(size_t)rg * N + cg] = f2bf(v > 0.f ? v : 0.f);
        } else {
          ((float*)Cout)[(size_t)rg * N + cg] = res[(size_t)rg * N + cg] + v;
        }
      }
    }
  }
}

// ---------------- MFMA flash attention (round-3 math + row strides) ----------------
template <bool CAUSAL>
__global__ __launch_bounds__(256)
void k_attn_mfma(const unsigned short* __restrict__ Q,
                 const unsigned short* __restrict__ Kb,
                 const unsigned short* __restrict__ Vb,
                 unsigned short* __restrict__ O,
                 int kvlen, int qs, int ks) {
  __shared__ __align__(16) unsigned short sK [64 * 64];
  __shared__ __align__(16) unsigned short sVt[64 * 64];
  __shared__ __align__(16) unsigned short sP [4][16 * 64];
  const int b = blockIdx.z, h = blockIdx.y, q0 = blockIdx.x * 64;
  const int t = threadIdx.x, w = t >> 6, l = t & 63;
  const int cc = l & 15, g = l >> 4;
  const int gk = g << 3;

  const unsigned short* qg =
      Q + (size_t)(b * 512 + q0 + w * 16 + cc) * qs + h * 64 + gk;
  bf16x8 qf[2];
  qf[0] = *(const bf16x8*)(qg);
  qf[1] = *(const bf16x8*)(qg + 32);

  f32x4 accO[4];
#pragma unroll
  for (int n = 0; n < 4; ++n) { accO[n][0]=0.f; accO[n][1]=0.f; accO[n][2]=0.f; accO[n][3]=0.f; }
  float om[4], ls[4];
#pragma unroll
  for (int r = 0; r < 4; ++r) { om[r] = -1e30f; ls[r] = 0.f; }

  const int sr = t >> 2;
  const int sc = (t & 3) << 4;
  const int kx = (sr & 7) << 3;
  const size_t stg0 = (size_t)(b * kvlen + sr) * ks + h * 64 + sc;

  const int kvmax = CAUSAL ? (q0 + 64) : kvlen;
  for (int c0 = 0; c0 < kvmax; c0 += 64) {
    __syncthreads();
    const size_t gr = stg0 + (size_t)c0 * ks;
    const bf16x8 k0 = *(const bf16x8*)(Kb + gr);
    const bf16x8 k1 = *(const bf16x8*)(Kb + gr + 8);
    const bf16x8 v0 = *(const bf16x8*)(Vb + gr);
    const bf16x8 v1 = *(const bf16x8*)(Vb + gr + 8);
    *(bf16x8*)(sK + sr * 64 + (sc ^ kx))       = k0;
    *(bf16x8*)(sK + sr * 64 + ((sc + 8) ^ kx)) = k1;
#pragma unroll
    for (int i = 0; i < 8; ++i) {
      const int j  = (i + 2 * (t & 3)) & 7;
      const int xj = sr ^ (j << 3);
      sVt[(sc + j)     * 64 + xj] = (unsigned short)v0[j];
      sVt[(sc + 8 + j) * 64 + xj] = (unsigned short)v1[j];
    }
    __syncthreads();

    f32x4 S[4];
#pragma unroll
    for (int n = 0; n < 4; ++n) { S[n][0]=0.f; S[n][1]=0.f; S[n][2]=0.f; S[n][3]=0.f; }
#pragma unroll
    for (int n = 0; n < 4; ++n) {
      const int kvr = (n * 16 + cc) * 64;
      const int sxk = (cc & 7) << 3;
#pragma unroll
      for (int ks2 = 0; ks2 < 2; ++ks2) {
        const bf16x8 kf = *(const bf16x8*)(sK + kvr + ((ks2 * 32 + gk) ^ sxk));
        S[n] = __builtin_amdgcn_mfma_f32_16x16x32_bf16(qf[ks2], kf, S[n], 0, 0, 0);
      }
    }

    float cm[4];
#pragma unroll
    for (int r = 0; r < 4; ++r) cm[r] = -1e30f;
#pragma unroll
    for (int n = 0; n < 4; ++n) {
      const int kvg = c0 + n * 16 + cc;
#pragma unroll
      for (int r = 0; r < 4; ++r) {
        const int qrow = q0 + w * 16 + g * 4 + r;
        const bool valid = (kvg < kvlen) && (!CAUSAL || kvg <= qrow);
        const float sv = valid ? S[n][r] * 0.125f : -1e30f;
        S[n][r] = sv;
        cm[r] = fmaxf(cm[r], sv);
      }
    }
#pragma unroll
    for (int m2 = 1; m2 <= 8; m2 <<= 1)
#pragma unroll
      for (int r = 0; r < 4; ++r) cm[r] = fmaxf(cm[r], __shfl_xor(cm[r], m2));

    float sc4[4], ps[4];
#pragma unroll
    for (int r = 0; r < 4; ++r) {
      const float mn = fmaxf(om[r], cm[r]);
      sc4[r] = __expf(om[r] - mn);
      om[r] = mn;
      ps[r] = 0.f;
    }
#pragma unroll
    for (int n = 0; n < 4; ++n) {
#pragma unroll
      for (int r = 0; r < 4; ++r) {
        const float pv = __expf(S[n][r] - om[r]);
        ps[r] += pv;
        const int q = g * 4 + r;
        sP[w][q * 64 + ((n * 16 + cc) ^ ((q & 7) << 3))] = f2bf(pv);
      }
    }
#pragma unroll
    for (int m2 = 1; m2 <= 8; m2 <<= 1)
#pragma unroll
      for (int r = 0; r < 4; ++r) ps[r] += __shfl_xor(ps[r], m2);
#pragma unroll
    for (int r = 0; r < 4; ++r) ls[r] = ls[r] * sc4[r] + ps[r];
#pragma unroll
    for (int n = 0; n < 4; ++n)
#pragma unroll
      for (int r = 0; r < 4; ++r) accO[n][r] *= sc4[r];

    const int pxk = (cc & 7) << 3;
#pragma unroll
    for (int ks2 = 0; ks2 < 2; ++ks2) {
      const bf16x8 pf = *(const bf16x8*)(&sP[w][cc * 64 + ((ks2 * 32 + gk) ^ pxk)]);
#pragma unroll
      for (int n = 0; n < 4; ++n) {
        const int d = n * 16 + cc;
        const bf16x8 vf = *(const bf16x8*)(sVt + d * 64 + ((ks2 * 32 + gk) ^ ((d & 7) << 3)));
        accO[n] = __builtin_amdgcn_mfma_f32_16x16x32_bf16(pf, vf, accO[n], 0, 0, 0);
      }
    }
  }

#pragma unroll
  for (int r = 0; r < 4; ++r) {
    const float inv = 1.f / ls[r];
    const size_t ob = ((size_t)(b * 512 + q0 + w * 16 + g * 4 + r) << 10) + h * 64;
#pragma unroll
    for (int n = 0; n < 4; ++n)
      O[ob + n * 16 + cc] = f2bf(accO[n][r] * inv);
  }
}

// ---------------- pairwise fuse gate ----------------
template <int PHASE>
__global__ __launch_bounds__(256)
void k_pair(float* __restrict__ c, const unsigned short* __restrict__ p1,
            const unsigned short* __restrict__ p2, unsigned short* __restrict__ acc) {
  __shared__ float red[8];
  const size_t base = (size_t)blockIdx.x * 1024;
  const int t = threadIdx.x;
  const f32x4 cv = *(const f32x4*)(c + base + t * 4);
  const us4 u1 = *(const us4*)(p1 + base + t * 4);
  const us4 u2 = *(const us4*)(p2 + base + t * 4);
  float f1v[4], f2v[4];
  float d1 = 0.f, d2 = 0.f;
#pragma unroll
  for (int j = 0; j < 4; ++j) {
    f1v[j] = bf2f((short)u1[j]); f2v[j] = bf2f((short)u2[j]);
    d1 += cv[j] * f1v[j]; d2 += cv[j] * f2v[j];
  }
#pragma unroll
  for (int m = 32; m >= 1; m >>= 1) { d1 += __shfl_xor(d1, m); d2 += __shfl_xor(d2, m); }
  const int w = t >> 6;
  if ((t & 63) == 0) { red[w] = d1; red[4 + w] = d2; }
  __syncthreads();
  d1 = red[0] + red[1] + red[2] + red[3];
  d2 = red[4] + red[5] + red[6] + red[7];
  const float mx = fmaxf(d1, d2);
  const float e1 = __expf(d1 - mx), e2 = __expf(d2 - mx);
  const float w1 = e1 / (e1 + e2), w2 = e2 / (e1 + e2);
  if constexpr (PHASE == 1) {
    us4 o;
#pragma unroll
    for (int j = 0; j < 4; ++j) o[j] = f2bf(0.5f * (w1 * f1v[j] + w2 * f2v[j]));
    *(us4*)(acc + base + t * 4) = o;
  } else {
    const us4 ua = *(const us4*)(acc + base + t * 4);
    f32x4 o;
#pragma unroll
    for (int j = 0; j < 4; ++j)
      o[j] = cv[j] + bf2f((short)ua[j]) + 0.5f * (w1 * f1v[j] + w2 * f2v[j]);
    *(f32x4*)(c + base + t * 4) = o;
  }
}

// ---------------- host ----------------
extern "C" void kernel_launch(void* const* d_in, const int* in_sizes, int n_in,
                              void* d_out, int out_size, void* d_ws, size_t ws_size,
                              hipStream_t stream) {
  (void)in_sizes; (void)n_in; (void)out_size; (void)ws_size;
  const float* captions      = (const float*)d_in[0];
  const float* cpt_words     = (const float*)d_in[1];
  const float* senti_words   = (const float*)d_in[2];
  const float* region_feats  = (const float*)d_in[3];
  const float* spatial_feats = (const float*)d_in[4];
  const float* att_W  = (const float*)d_in[5];
  const float* att_b  = (const float*)d_in[6];
  const float* ffn_W1 = (const float*)d_in[7];
  const float* ffn_b1 = (const float*)d_in[8];
  const float* ffn_W2 = (const float*)d_in[9];
  const float* ffn_b2 = (const float*)d_in[10];
  const float* ln_g   = (const float*)d_in[11];
  const float* ln_b   = (const float*)d_in[12];
  // d_in[13] seq_masks: tril by construction -> causal handled analytically.

  // ---- ws layout: 170.75 MiB ----
  char* ws = (char*)d_ws;
  size_t off = 0;
  auto alloc = [&](size_t bytes) {
    char* p = ws + off;
    off += (bytes + 255) & ~(size_t)255;
    return p;
  };
  const size_t ACT2 = (size_t)8192 * 1024 * 2;                    // 16 MiB
  unsigned short* hbuf = (unsigned short*)alloc(ACT2);            // LN out / attn out
  unsigned short* qkv  = (unsigned short*)alloc((size_t)8192 * 3072 * 2);  // 48 MiB
  unsigned short* bp1  = (unsigned short*)alloc(ACT2);
  unsigned short* bp2  = (unsigned short*)alloc(ACT2);
  float*          c1   = (float*)alloc((size_t)8192 * 1024 * 4);  // 32 MiB
  unsigned short* uni  = (unsigned short*)alloc(ACT2);            // accb | wF1t+wF2t
  unsigned short* wAttB= (unsigned short*)alloc((size_t)4 * 1024 * 1024 * 2);
  unsigned short* padw = (unsigned short*)alloc((size_t)3200 * 1024 * 2);
  unsigned short* kvb  = (unsigned short*)alloc((size_t)3200 * 2048 * 2);  // 12.5 MiB
  unsigned short* xbuf = hbuf;        // attn out aliases LN buffer
  unsigned short* qbuf = qkv;         // branch Q (16 MiB) in dead qkv region
  unsigned short* f1   = qkv;         // FFN mid [8192,4096] = qkv(48)+bp1(16)
  unsigned short* accb = uni;
  unsigned short* wF1t = uni;                                     // after accb dead
  unsigned short* wF2t = uni + (size_t)4096 * 1024;

  const dim3 tb32(32, 8);
  const size_t MS = (size_t)1024 * 1024;
  auto Wi = [&](int j) { return wAttB + (size_t)j * MS; };
  auto Bv = [&](int i, int j) { return att_b + (size_t)(i * 4 + j) * 1024; };
  const dim3 gAttn(8, 16, 16);

  // ---- self attention (causal): fused QKV (N=3072, 1536 blocks) ----
  k_transpose_cvt<<<dim3(32, 32, 4), tb32, 0, stream>>>(att_W, wAttB, 1024, 1024);
  k_ln<<<8192, 256, 0, stream>>>(captions, ln_g, ln_b, hbuf);
  k_gemm<0><<<1536, 256, 0, stream>>>(hbuf, Wi(0), Bv(0,0), qkv, nullptr, 3072, 1024, 24);
  k_attn_mfma<true><<<gAttn, 256, 0, stream>>>(qkv, qkv + 1024, qkv + 2048, xbuf,
                                               512, 3072, 3072);
  k_gemm<2><<<512, 256, 0, stream>>>(xbuf, Wi(3), Bv(0,3), c1, captions, 1024, 1024, 8);

  // ---- cpt (att 1) -> bp1 ----
  k_transpose_cvt<<<dim3(32, 32, 4), tb32, 0, stream>>>(att_W + 4 * MS, wAttB, 1024, 1024);
  k_cvt_pad<<<512, 256, 0, stream>>>(cpt_words, padw, 400);
  k_ln<<<8192, 256, 0, stream>>>(c1, ln_g + 1024, ln_b + 1024, hbuf);
  k_gemm<0><<<512, 256, 0, stream>>>(hbuf, Wi(0), Bv(1,0), qbuf, nullptr, 1024, 1024, 8);
  k_gemm<0><<<64,  256, 0, stream>>>(padw, Wi(1), Bv(1,1), kvb, nullptr, 2048, 1024, 16);
  k_attn_mfma<false><<<gAttn, 256, 0, stream>>>(qbuf, kvb, kvb + 1024, xbuf, 25, 1024, 2048);
  k_gemm<0><<<512, 256, 0, stream>>>(xbuf, Wi(3), Bv(1,3), bp1, nullptr, 1024, 1024, 8);

  // ---- sen (att 2) -> bp2 ----
  k_transpose_cvt<<<dim3(32, 32, 4), tb32, 0, stream>>>(att_W + 8 * MS, wAttB, 1024, 1024);
  k_cvt_pad<<<512, 256, 0, stream>>>(senti_words, padw, 400);
  k_ln<<<8192, 256, 0, stream>>>(c1, ln_g + 2048, ln_b + 2048, hbuf);
  k_gemm<0><<<512, 256, 0, stream>>>(hbuf, Wi(0), Bv(2,0), qbuf, nullptr, 1024, 1024, 8);
  k_gemm<0><<<64,  256, 0, stream>>>(padw, Wi(1), Bv(2,1), kvb, nullptr, 2048, 1024, 16);
  k_attn_mfma<false><<<gAttn, 256, 0, stream>>>(qbuf, kvb, kvb + 1024, xbuf, 25, 1024, 2048);
  k_gemm<0><<<512, 256, 0, stream>>>(xbuf, Wi(3), Bv(2,3), bp2, nullptr, 1024, 1024, 8);

  k_pair<1><<<8192, 256, 0, stream>>>(c1, bp1, bp2, accb);

  // ---- region (att 3) -> bp1 ----
  k_transpose_cvt<<<dim3(32, 32, 4), tb32, 0, stream>>>(att_W + 12 * MS, wAttB, 1024, 1024);
  k_cvt_pad<<<3200, 256, 0, stream>>>(region_feats, padw, 3136);
  k_ln<<<8192, 256, 0, stream>>>(c1, ln_g + 3072, ln_b + 3072, hbuf);
  k_gemm<0><<<512, 256, 0, stream>>>(hbuf, Wi(0), Bv(3,0), qbuf, nullptr, 1024, 1024, 8);
  k_gemm<0><<<400, 256, 0, stream>>>(padw, Wi(1), Bv(3,1), kvb, nullptr, 2048, 1024, 16);
  k_attn_mfma<false><<<gAttn, 256, 0, stream>>>(qbuf, kvb, kvb + 1024, xbuf, 196, 1024, 2048);
  k_gemm<0><<<512, 256, 0, stream>>>(xbuf, Wi(3), Bv(3,3), bp1, nullptr, 1024, 1024, 8);

  // ---- spatial (att 4) -> bp2 ----
  k_transpose_cvt<<<dim3(32, 32, 4), tb32, 0, stream>>>(att_W + 16 * MS, wAttB, 1024, 1024);
  k_cvt_pad<<<3200, 256, 0, stream>>>(spatial_feats, padw, 3136);
  k_ln<<<8192, 256, 0, stream>>>(c1, ln_g + 4096, ln_b + 4096, hbuf);
  k_gemm<0><<<512, 256, 0, stream>>>(hbuf, Wi(0), Bv(4,0), qbuf, nullptr, 1024, 1024, 8);
  k_gemm<0><<<400, 256, 0, stream>>>(padw, Wi(1), Bv(4,1), kvb, nullptr, 2048, 1024, 16);
  k_attn_mfma<false><<<gAttn, 256, 0, stream>>>(qbuf, kvb, kvb + 1024, xbuf, 196, 1024, 2048);
  k_gemm<0><<<512, 256, 0, stream>>>(xbuf, Wi(3), Bv(4,3), bp2, nullptr, 1024, 1024, 8);

  k_pair<2><<<8192, 256, 0, stream>>>(c1, bp1, bp2, accb);  // c1 = fuse (in-place)

  // ---- FFN (weight transposes here: accb dead, uni re-used) ----
  k_transpose_cvt<<<dim3(128, 32, 1), tb32, 0, stream>>>(ffn_W1, wF1t, 1024, 4096);
  k_transpose_cvt<<<dim3(32, 128, 1), tb32, 0, stream>>>(ffn_W2, wF2t, 4096, 1024);
  k_ln<<<8192, 256, 0, stream>>>(c1, ln_g + 5120, ln_b + 5120, hbuf);
  k_gemm<1><<<2048, 256, 0, stream>>>(hbuf, wF1t, ffn_b1, f1, nullptr, 4096, 1024, 32);
  k_gemm<2><<<512,  256, 0, stream>>>(f1, wF2t, ffn_b2, (float*)d_out, c1, 1024, 4096, 8);
}

// Round 7
// 969.567 us; speedup vs baseline: 2.7827x; 1.0043x over previous
//
#include <hip/hip_runtime.h>

// DecoderLayer (B=16, N1=512, D=1024, H=16, Dk=64, FF=4096)
// Round 7: fix round-6 KV sizing bug (KV is batch-interleaved flat: must
// compute ALL B*kvlen rows -> Rp=512 cpt/sen, 3200 reg/spa; round 6's 128/256
// left batches>=6 reading unwritten K/V). Keeps round-6 structure: LN folding
// (exact here), paired Q GEMM (N=2048), grouped out-pair GEMM, rotation ws.
// Per-pair KV runs per-branch into shared kvb so ws ~163 MiB (<174 known-good).

typedef __attribute__((ext_vector_type(4))) float          f32x4;
typedef __attribute__((ext_vector_type(8))) short          bf16x8;
typedef __attribute__((ext_vector_type(4))) unsigned short us4;

#define DEV static __device__ __forceinline__

DEV float bf2f(short h) {
  union { unsigned u; float f; } c;
  c.u = ((unsigned)(unsigned short)h) << 16;
  return c.f;
}
DEV unsigned short f2bf(float f) {  // round-to-nearest-even
  union { float f; unsigned u; } c; c.f = f;
  return (unsigned short)((c.u + 0x7fffu + ((c.u >> 16) & 1u)) >> 16);
}

// async global->LDS, 16B per lane; LDS dest is wave-uniform base + lane*16B
DEV void gll16(const unsigned short* g, unsigned short* l) {
  __builtin_amdgcn_global_load_lds((const __attribute__((address_space(1))) void*)g,
                                   (__attribute__((address_space(3))) void*)l,
                                   16, 0, 0);
}

// ---------------- transpose + f32->bf16 convert (+optional row scale) ----------------
// z-th matrix: src += (z>>1)*sHi + (z&1)*sLo; dst += z*R*C.
// dst[c][r] = src[r][c] * (g ? g[z*gStride + r] : 1)
__global__ __launch_bounds__(256)
void k_transpose_cvt(const float* __restrict__ src, unsigned short* __restrict__ dst,
                     long long sHi, long long sLo,
                     const float* __restrict__ g, int gStride, int R, int C) {
  __shared__ float tile[32][33];
  const int z = blockIdx.z;
  src += (long long)(z >> 1) * sHi + (long long)(z & 1) * sLo;
  dst += (size_t)z * R * C;
  const int c0 = blockIdx.x * 32, r0 = blockIdx.y * 32;
  const int tx = threadIdx.x, ty = threadIdx.y;
#pragma unroll
  for (int i = 0; i < 32; i += 8)
    tile[ty + i][tx] = src[(size_t)(r0 + ty + i) * C + (c0 + tx)];
  __syncthreads();
  const float gv = g ? g[(size_t)z * gStride + r0 + tx] : 1.f;
#pragma unroll
  for (int i = 0; i < 32; i += 8)
    dst[(size_t)(c0 + ty + i) * R + (r0 + tx)] = f2bf(tile[tx][ty + i] * gv);
}

// ---------------- folded bias: out[n] = b_i . Wq_i[:,c] + bq_i[c] ----------------
// n in [0,2048): i=n>>10 (branch), c=n&1023. Strides: b 1024, W 4MS, bq 4096.
__global__ __launch_bounds__(256)
void k_foldbias(const float* __restrict__ b, const float* __restrict__ W,
                const float* __restrict__ bq, float* __restrict__ out) {
  __shared__ float red[4];
  const int n = blockIdx.x, i = n >> 10, c = n & 1023, t = threadIdx.x;
  const float* Wi = W + (size_t)i * 4 * 1048576 + c;
  const float* bi = b + i * 1024;
  float s = 0.f;
  for (int k = t; k < 1024; k += 256) s += bi[k] * Wi[(size_t)k * 1024];
#pragma unroll
  for (int m = 32; m >= 1; m >>= 1) s += __shfl_xor(s, m);
  if ((t & 63) == 0) red[t >> 6] = s;
  __syncthreads();
  if (t == 0) out[n] = red[0] + red[1] + red[2] + red[3] + bq[(size_t)i * 4096 + c];
}

// ---------------- f32 -> bf16 convert with zero row padding ----------------
__global__ __launch_bounds__(256)
void k_cvt_pad(const float* __restrict__ src, unsigned short* __restrict__ dst, int rows) {
  const int r = blockIdx.x;
  const int c = threadIdx.x * 4;
  us4 o;
  if (r < rows) {
    f32x4 v = *(const f32x4*)(src + (size_t)r * 1024 + c);
    o[0] = f2bf(v[0]); o[1] = f2bf(v[1]); o[2] = f2bf(v[2]); o[3] = f2bf(v[3]);
  } else {
    o[0] = 0; o[1] = 0; o[2] = 0; o[3] = 0;
  }
  *(us4*)(dst + (size_t)r * 1024 + c) = o;
}

// ---------------- LayerNorm (D=1024), f32 in -> bf16 out ----------------
template <bool AFFINE>
__global__ __launch_bounds__(256)
void k_ln(const float* __restrict__ x, const float* __restrict__ g,
          const float* __restrict__ bb, unsigned short* __restrict__ y) {
  __shared__ float red[8];
  const size_t base = (size_t)blockIdx.x * 1024;
  const int t = threadIdx.x;
  f32x4 v = *(const f32x4*)(x + base + t * 4);
  float s  = v[0] + v[1] + v[2] + v[3];
  float s2 = v[0]*v[0] + v[1]*v[1] + v[2]*v[2] + v[3]*v[3];
#pragma unroll
  for (int m = 32; m >= 1; m >>= 1) { s += __shfl_xor(s, m); s2 += __shfl_xor(s2, m); }
  const int w = t >> 6;
  if ((t & 63) == 0) { red[w] = s; red[4 + w] = s2; }
  __syncthreads();
  s  = red[0] + red[1] + red[2] + red[3];
  s2 = red[4] + red[5] + red[6] + red[7];
  const float mean = s * (1.f / 1024.f);
  const float var  = s2 * (1.f / 1024.f) - mean * mean;
  const float rstd = rsqrtf(var + 1e-5f);
  us4 o;
#pragma unroll
  for (int j = 0; j < 4; ++j) {
    const float zv = (v[j] - mean) * rstd;
    o[j] = f2bf(AFFINE ? zv * g[t * 4 + j] + bb[t * 4 + j] : zv);
  }
  *(us4*)(y + base + t * 4) = o;
}

// ---------------- GEMM core: C[M,N] = A[M,K](bf16) @ Bt[N,K]^T(bf16) + bias ----------------
// 128x128 tile, BK=32, 4 waves, 2-phase dbuf global_load_lds staging.
// MODE 0: bf16 out; 1: bf16 relu out; 2: f32 out = res(f32) + acc + bias
template <int MODE>
DEV void gemm_core(const unsigned short* __restrict__ A,
                   const unsigned short* __restrict__ Bt,
                   const float* __restrict__ bias,
                   void* __restrict__ Cout,
                   const float* __restrict__ res,
                   int N, int K, int bx, int by,
                   unsigned short* sA, unsigned short* sB) {
  const int t = threadIdx.x;
  const int l = t & 63, w = t >> 6;
  const int wr = w >> 1, wc = w & 1;

  const int glr = l >> 2;
  const int glc = (l & 3) << 3;
  const unsigned short* gA = A  + (size_t)(by * 128 + w * 32 + glr) * K + glc;
  const unsigned short* gB = Bt + (size_t)(bx * 128 + w * 32 + glr) * K + glc;
  const size_t r16 = (size_t)16 * K;
  const int wofs = w * 32 * 32;

  const int lr = l & 15;
  const int lk = (l >> 4) << 3;

  f32x4 acc[4][4];
#pragma unroll
  for (int m = 0; m < 4; ++m)
#pragma unroll
    for (int n = 0; n < 4; ++n) { acc[m][n][0]=0.f; acc[m][n][1]=0.f; acc[m][n][2]=0.f; acc[m][n][3]=0.f; }

  auto stage = [&](int buf, int k0) {
    gll16(gA + k0,       sA + buf * 4096 + wofs);
    gll16(gA + r16 + k0, sA + buf * 4096 + wofs + 512);
    gll16(gB + k0,       sB + buf * 4096 + wofs);
    gll16(gB + r16 + k0, sB + buf * 4096 + wofs + 512);
  };
  auto compute = [&](int buf) {
    const unsigned short* sAr = sA + buf * 4096 + (wr * 64 + lr) * 32 + lk;
    const unsigned short* sBr = sB + buf * 4096 + (wc * 64 + lr) * 32 + lk;
    bf16x8 af[4], bfr[4];
#pragma unroll
    for (int m = 0; m < 4; ++m) af[m]  = *(const bf16x8*)(sAr + m * 16 * 32);
#pragma unroll
    for (int n = 0; n < 4; ++n) bfr[n] = *(const bf16x8*)(sBr + n * 16 * 32);
#pragma unroll
    for (int m = 0; m < 4; ++m)
#pragma unroll
      for (int n = 0; n < 4; ++n)
        acc[m][n] = __builtin_amdgcn_mfma_f32_16x16x32_bf16(af[m], bfr[n], acc[m][n], 0, 0, 0);
  };

  stage(0, 0);
  __syncthreads();
  int cur = 0;
  for (int k0 = 32; k0 < K; k0 += 32) {
    stage(cur ^ 1, k0);
    compute(cur);
    __syncthreads();
    cur ^= 1;
  }
  compute(cur);

  const int rq = (l >> 4) << 2;  // C/D: col = lane&15, row = (lane>>4)*4 + reg
#pragma unroll
  for (int n = 0; n < 4; ++n) {
    const int cg = bx * 128 + wc * 64 + n * 16 + lr;
    const float bv = bias[cg];
#pragma unroll
    for (int m = 0; m < 4; ++m) {
#pragma unroll
      for (int r = 0; r < 4; ++r) {
        const int rg = by * 128 + wr * 64 + m * 16 + rq + r;
        const float v = acc[m][n][r] + bv;
        if constexpr (MODE == 0) {
          ((unsigned short*)Cout)[(size_t)rg * N + cg] = f2bf(v);
        } else if constexpr (MODE == 1) {
          ((unsigned short*)Cout)[(size_t)rg * N + cg] = f2bf(v > 0.f ? v : 0.f);
        } else {
          ((float*)Cout)[(size_t)rg * N + cg] = res[(size_t)rg * N + cg] + v;
        }
      }
    }
  }
}

template <int MODE>
__global__ __launch_bounds__(256)
void k_gemm(const unsigned short* __restrict__ A,
            const unsigned short* __restrict__ Bt,
            const float* __restrict__ bias,
            void* __restrict__ Cout,
            const float* __restrict__ res,
            int N, int K, int nbx) {
  __shared__ unsigned short sA[2][128 * 32];
  __shared__ unsigned short sB[2][128 * 32];
  const int nwg = gridDim.x;
  const int q8  = nwg >> 3;
  const int swz = (blockIdx.x & 7) * q8 + (blockIdx.x >> 3);
  gemm_core<MODE>(A, Bt, bias, Cout, res, N, K, swz % nbx, swz / nbx,
                  &sA[0][0], &sB[0][0]);
}

// 2-group GEMM (bf16 out): blocks [0,nblk0) -> set0, rest -> set1.
__global__ __launch_bounds__(256)
void k_gemm2(const unsigned short* __restrict__ A0, const unsigned short* __restrict__ B0,
             const float* __restrict__ b0, unsigned short* __restrict__ C0,
             const unsigned short* __restrict__ A1, const unsigned short* __restrict__ B1,
             const float* __restrict__ b1, unsigned short* __restrict__ C1,
             int N, int K, int nbx, int nblk0) {
  __shared__ unsigned short sA[2][128 * 32];
  __shared__ unsigned short sB[2][128 * 32];
  const int nwg = gridDim.x;
  const int q8  = nwg >> 3;
  int swz = (blockIdx.x & 7) * q8 + (blockIdx.x >> 3);
  const unsigned short* A; const unsigned short* Bt; const float* bias; unsigned short* C;
  if (swz < nblk0) { A = A0; Bt = B0; bias = b0; C = C0; }
  else { swz -= nblk0; A = A1; Bt = B1; bias = b1; C = C1; }
  gemm_core<0>(A, Bt, bias, C, nullptr, N, K, swz % nbx, swz / nbx,
               &sA[0][0], &sB[0][0]);
}

// ---------------- MFMA flash attention ----------------
template <bool CAUSAL>
__global__ __launch_bounds__(256)
void k_attn_mfma(const unsigned short* __restrict__ Q,
                 const unsigned short* __restrict__ Kb,
                 const unsigned short* __restrict__ Vb,
                 unsigned short* __restrict__ O,
                 int kvlen, int qs, int ks) {
  __shared__ __align__(16) unsigned short sK [64 * 64];
  __shared__ __align__(16) unsigned short sVt[64 * 64];
  __shared__ __align__(16) unsigned short sP [4][16 * 64];
  const int b = blockIdx.z, h = blockIdx.y, q0 = blockIdx.x * 64;
  const int t = threadIdx.x, w = t >> 6, l = t & 63;
  const int cc = l & 15, g = l >> 4;
  const int gk = g << 3;

  const unsigned short* qg =
      Q + (size_t)(b * 512 + q0 + w * 16 + cc) * qs + h * 64 + gk;
  bf16x8 qf[2];
  qf[0] = *(const bf16x8*)(qg);
  qf[1] = *(const bf16x8*)(qg + 32);

  f32x4 accO[4];
#pragma unroll
  for (int n = 0; n < 4; ++n) { accO[n][0]=0.f; accO[n][1]=0.f; accO[n][2]=0.f; accO[n][3]=0.f; }
  float om[4], ls[4];
#pragma unroll
  for (int r = 0; r < 4; ++r) { om[r] = -1e30f; ls[r] = 0.f; }

  const int sr = t >> 2;
  const int sc = (t & 3) << 4;
  const int kx = (sr & 7) << 3;
  const size_t stg0 = (size_t)(b * kvlen + sr) * ks + h * 64 + sc;

  const int kvmax = CAUSAL ? (q0 + 64) : kvlen;
  for (int c0 = 0; c0 < kvmax; c0 += 64) {
    __syncthreads();
    const size_t gr = stg0 + (size_t)c0 * ks;
    const bf16x8 k0 = *(const bf16x8*)(Kb + gr);
    const bf16x8 k1 = *(const bf16x8*)(Kb + gr + 8);
    const bf16x8 v0 = *(const bf16x8*)(Vb + gr);
    const bf16x8 v1 = *(const bf16x8*)(Vb + gr + 8);
    *(bf16x8*)(sK + sr * 64 + (sc ^ kx))       = k0;
    *(bf16x8*)(sK + sr * 64 + ((sc + 8) ^ kx)) = k1;
#pragma unroll
    for (int i = 0; i < 8; ++i) {
      const int j  = (i + 2 * (t & 3)) & 7;
      const int xj = sr ^ (j << 3);
      sVt[(sc + j)     * 64 + xj] = (unsigned short)v0[j];
      sVt[(sc + 8 + j) * 64 + xj] = (unsigned short)v1[j];
    }
    __syncthreads();

    f32x4 S[4];
#pragma unroll
    for (int n = 0; n < 4; ++n) { S[n][0]=0.f; S[n][1]=0.f; S[n][2]=0.f; S[n][3]=0.f; }
#pragma unroll
    for (int n = 0; n < 4; ++n) {
      const int kvr = (n * 16 + cc) * 64;
      const int sxk = (cc & 7) << 3;
#pragma unroll
      for (int ks2 = 0; ks2 < 2; ++ks2) {
        const bf16x8 kf = *(const bf16x8*)(sK + kvr + ((ks2 * 32 + gk) ^ sxk));
        S[n] = __builtin_amdgcn_mfma_f32_16x16x32_bf16(qf[ks2], kf, S[n], 0, 0, 0);
      }
    }

    float cm[4];
#pragma unroll
    for (int r = 0; r < 4; ++r) cm[r] = -1e30f;
#pragma unroll
    for (int n = 0; n < 4; ++n) {
      const int kvg = c0 + n * 16 + cc;
#pragma unroll
      for (int r = 0; r < 4; ++r) {
        const int qrow = q0 + w * 16 + g * 4 + r;
        const bool valid = (kvg < kvlen) && (!CAUSAL || kvg <= qrow);
        const float sv = valid ? S[n][r] * 0.125f : -1e30f;
        S[n][r] = sv;
        cm[r] = fmaxf(cm[r], sv);
      }
    }
#pragma unroll
    for (int m2 = 1; m2 <= 8; m2 <<= 1)
#pragma unroll
      for (int r = 0; r < 4; ++r) cm[r] = fmaxf(cm[r], __shfl_xor(cm[r], m2));

    float sc4[4], ps[4];
#pragma unroll
    for (int r = 0; r < 4; ++r) {
      const float mn = fmaxf(om[r], cm[r]);
      sc4[r] = __expf(om[r] - mn);
      om[r] = mn;
      ps[r] = 0.f;
    }
#pragma unroll
    for (int n = 0; n < 4; ++n) {
#pragma unroll
      for (int r = 0; r < 4; ++r) {
        const float pv = __expf(S[n][r] - om[r]);
        ps[r] += pv;
        const int q = g * 4 + r;
        sP[w][q * 64 + ((n * 16 + cc) ^ ((q & 7) << 3))] = f2bf(pv);
      }
    }
#pragma unroll
    for (int m2 = 1; m2 <= 8; m2 <<= 1)
#pragma unroll
      for (int r = 0; r < 4; ++r) ps[r] += __shfl_xor(ps[r], m2);
#pragma unroll
    for (int r = 0; r < 4; ++r) ls[r] = ls[r] * sc4[r] + ps[r];
#pragma unroll
    for (int n = 0; n < 4; ++n)
#pragma unroll
      for (int r = 0; r < 4; ++r) accO[n][r] *= sc4[r];

    const int pxk = (cc & 7) << 3;
#pragma unroll
    for (int ks2 = 0; ks2 < 2; ++ks2) {
      const bf16x8 pf = *(const bf16x8*)(&sP[w][cc * 64 + ((ks2 * 32 + gk) ^ pxk)]);
#pragma unroll
      for (int n = 0; n < 4; ++n) {
        const int d = n * 16 + cc;
        const bf16x8 vf = *(const bf16x8*)(sVt + d * 64 + ((ks2 * 32 + gk) ^ ((d & 7) << 3)));
        accO[n] = __builtin_amdgcn_mfma_f32_16x16x32_bf16(pf, vf, accO[n], 0, 0, 0);
      }
    }
  }

#pragma unroll
  for (int r = 0; r < 4; ++r) {
    const float inv = 1.f / ls[r];
    const size_t ob = ((size_t)(b * 512 + q0 + w * 16 + g * 4 + r) << 10) + h * 64;
#pragma unroll
    for (int n = 0; n < 4; ++n)
      O[ob + n * 16 + cc] = f2bf(accO[n][r] * inv);
  }
}

// ---------------- pairwise fuse gate ----------------
template <int PHASE>
__global__ __launch_bounds__(256)
void k_pair(float* __restrict__ c, const unsigned short* __restrict__ p1,
            const unsigned short* __restrict__ p2, unsigned short* __restrict__ acc) {
  __shared__ float red[8];
  const size_t base = (size_t)blockIdx.x * 1024;
  const int t = threadIdx.x;
  const f32x4 cv = *(const f32x4*)(c + base + t * 4);
  const us4 u1 = *(const us4*)(p1 + base + t * 4);
  const us4 u2 = *(const us4*)(p2 + base + t * 4);
  float f1v[4], f2v[4];
  float d1 = 0.f, d2 = 0.f;
#pragma unroll
  for (int j = 0; j < 4; ++j) {
    f1v[j] = bf2f((short)u1[j]); f2v[j] = bf2f((short)u2[j]);
    d1 += cv[j] * f1v[j]; d2 += cv[j] * f2v[j];
  }
#pragma unroll
  for (int m = 32; m >= 1; m >>= 1) { d1 += __shfl_xor(d1, m); d2 += __shfl_xor(d2, m); }
  const int w = t >> 6;
  if ((t & 63) == 0) { red[w] = d1; red[4 + w] = d2; }
  __syncthreads();
  d1 = red[0] + red[1] + red[2] + red[3];
  d2 = red[4] + red[5] + red[6] + red[7];
  const float mx = fmaxf(d1, d2);
  const float e1 = __expf(d1 - mx), e2 = __expf(d2 - mx);
  const float w1 = e1 / (e1 + e2), w2 = e2 / (e1 + e2);
  if constexpr (PHASE == 1) {
    us4 o;
#pragma unroll
    for (int j = 0; j < 4; ++j) o[j] = f2bf(0.5f * (w1 * f1v[j] + w2 * f2v[j]));
    *(us4*)(acc + base + t * 4) = o;
  } else {
    const us4 ua = *(const us4*)(acc + base + t * 4);
    f32x4 o;
#pragma unroll
    for (int j = 0; j < 4; ++j)
      o[j] = cv[j] + bf2f((short)ua[j]) + 0.5f * (w1 * f1v[j] + w2 * f2v[j]);
    *(f32x4*)(c + base + t * 4) = o;
  }
}

// ---------------- host ----------------
extern "C" void kernel_launch(void* const* d_in, const int* in_sizes, int n_in,
                              void* d_out, int out_size, void* d_ws, size_t ws_size,
                              hipStream_t stream) {
  (void)in_sizes; (void)n_in; (void)out_size; (void)ws_size;
  const float* captions      = (const float*)d_in[0];
  const float* cpt_words     = (const float*)d_in[1];
  const float* senti_words   = (const float*)d_in[2];
  const float* region_feats  = (const float*)d_in[3];
  const float* spatial_feats = (const float*)d_in[4];
  const float* att_W  = (const float*)d_in[5];
  const float* att_b  = (const float*)d_in[6];
  const float* ffn_W1 = (const float*)d_in[7];
  const float* ffn_b1 = (const float*)d_in[8];
  const float* ffn_W2 = (const float*)d_in[9];
  const float* ffn_b2 = (const float*)d_in[10];
  const float* ln_g   = (const float*)d_in[11];
  const float* ln_b   = (const float*)d_in[12];
  // d_in[13] seq_masks: tril by construction -> causal handled analytically.

  // ---- ws layout: ~163 MiB ----
  char* ws = (char*)d_ws;
  size_t off = 0;
  auto alloc = [&](size_t bytes) {
    char* p = ws + off;
    off += (bytes + 255) & ~(size_t)255;
    return p;
  };
  const size_t M8 = (size_t)8 * 1024 * 1024;           // 8M elems (16 MiB bf16)
  unsigned short* hbuf = (unsigned short*)alloc(M8 * 2);          // 16 MiB: ln out / z
  unsigned short* qx   = (unsigned short*)alloc(M8 * 2 * 4);      // 64 MiB rotation
  float*          c1   = (float*)alloc((size_t)8192 * 1024 * 4);  // 32 MiB residual
  unsigned short* uni  = (unsigned short*)alloc(M8 * 2);          // 16 MiB accb|wF1t+wF2t
  unsigned short* wbuf = (unsigned short*)alloc(M8 * 2);          // 16 MiB phase weights
  unsigned short* padb = (unsigned short*)alloc((size_t)3200 * 1024 * 2);  // 6.25 MiB
  unsigned short* kvb  = (unsigned short*)alloc((size_t)3200 * 2048 * 2);  // 12.5 MiB
  float*          qbs  = (float*)alloc(2048 * 4);                 // folded Q bias

  const long long MSL = 1048576;
  const size_t    MSE = 1048576;
  unsigned short* accb = uni;
  unsigned short* wF1t = uni;
  unsigned short* wF2t = uni + (size_t)4096 * 1024;

  const dim3 tb32(32, 8);
  const dim3 gAttn(8, 16, 16);

  // ================= self attention (causal) =================
  k_transpose_cvt<<<dim3(32, 32, 4), tb32, 0, stream>>>(att_W, wbuf, 2 * MSL, MSL,
                                                        nullptr, 0, 1024, 1024);
  k_ln<true><<<8192, 256, 0, stream>>>(captions, ln_g, ln_b, hbuf);
  k_gemm<0><<<1536, 256, 0, stream>>>(hbuf, wbuf, att_b, qx, nullptr, 3072, 1024, 24);
  k_attn_mfma<true><<<gAttn, 256, 0, stream>>>(qx, qx + 1024, qx + 2048,
                                               qx + 3 * M8, 512, 3072, 3072);
  k_gemm<2><<<512, 256, 0, stream>>>(qx + 3 * M8, wbuf + 3 * MSE, att_b + 3 * 1024,
                                     c1, captions, 1024, 1024, 8);

  // ================= branches (paired), folded LN =================
  k_ln<false><<<8192, 256, 0, stream>>>(c1, nullptr, nullptr, hbuf);

  // Rp = total padded KV rows (B*kvlen rounded up; staging reads b*kvlen+c0+63)
  auto branch_pair = [&](int bi0, int Rp, int valid,
                         const float* wrd0, const float* wrd1, int phase) {
    // weights: Q'x2 -> wbuf[0,2MS); Wk|Wv x2 -> [2MS,6MS); Wo x2 -> [6MS,8MS)
    k_transpose_cvt<<<dim3(32, 32, 2), tb32, 0, stream>>>(
        att_W + (size_t)bi0 * 4 * MSE, wbuf, 0, 4 * MSL,
        ln_g + (size_t)bi0 * 1024, 1024, 1024, 1024);
    k_transpose_cvt<<<dim3(32, 32, 4), tb32, 0, stream>>>(
        att_W + ((size_t)bi0 * 4 + 1) * MSE, wbuf + 2 * MSE, 4 * MSL, MSL,
        nullptr, 0, 1024, 1024);
    k_transpose_cvt<<<dim3(32, 32, 2), tb32, 0, stream>>>(
        att_W + ((size_t)bi0 * 4 + 3) * MSE, wbuf + 6 * MSE, 0, 4 * MSL,
        nullptr, 0, 1024, 1024);
    k_foldbias<<<2048, 256, 0, stream>>>(ln_b + (size_t)bi0 * 1024,
                                         att_W + (size_t)bi0 * 4 * MSE,
                                         att_b + (size_t)bi0 * 4 * 1024, qbs);
    // Q pair: z @ [Wq'a;Wq'b] (N=2048) -> qx[0,16M)
    k_gemm<0><<<1024, 256, 0, stream>>>(hbuf, wbuf, qbs, qx, nullptr, 2048, 1024, 16);

    const int kvblk = (Rp / 128) * 16;
    const int nrows = valid * 16;   // valid rows in flat layout (B=16)
    // branch a: KV -> kvb, attn -> xb0 = qx[16M,24M)
    k_cvt_pad<<<Rp, 256, 0, stream>>>(wrd0, padb, nrows);
    k_gemm<0><<<kvblk, 256, 0, stream>>>(padb, wbuf + 2 * MSE,
                                         att_b + ((size_t)bi0 * 4 + 1) * 1024,
                                         kvb, nullptr, 2048, 1024, 16);
    k_attn_mfma<false><<<gAttn, 256, 0, stream>>>(
        qx, kvb, kvb + 1024, qx + 2 * M8, valid, 2048, 2048);
    // branch b: KV -> kvb (reuse), attn -> xb1 = qx[24M,32M)
    k_cvt_pad<<<Rp, 256, 0, stream>>>(wrd1, padb, nrows);
    k_gemm<0><<<kvblk, 256, 0, stream>>>(padb, wbuf + 4 * MSE,
                                         att_b + ((size_t)(bi0 + 1) * 4 + 1) * 1024,
                                         kvb, nullptr, 2048, 1024, 16);
    k_attn_mfma<false><<<gAttn, 256, 0, stream>>>(
        qx + 1024, kvb, kvb + 1024, qx + 3 * M8, valid, 2048, 2048);
    // out pair grouped -> bp0 = qx[0,8M), bp1 = qx[8M,16M)
    k_gemm2<<<1024, 256, 0, stream>>>(
        qx + 2 * M8, wbuf + 6 * MSE, att_b + ((size_t)bi0 * 4 + 3) * 1024, qx,
        qx + 3 * M8, wbuf + 7 * MSE, att_b + ((size_t)(bi0 + 1) * 4 + 3) * 1024,
        qx + M8, 1024, 1024, 8, 512);
    if (phase == 1) k_pair<1><<<8192, 256, 0, stream>>>(c1, qx, qx + M8, accb);
    else            k_pair<2><<<8192, 256, 0, stream>>>(c1, qx, qx + M8, accb);
  };

  branch_pair(1, 512,  25,  cpt_words,    senti_words,   1);  // semantic
  branch_pair(3, 3200, 196, region_feats, spatial_feats, 2);  // visual -> c1 = fuse

  // ================= FFN =================
  k_transpose_cvt<<<dim3(128, 32, 1), tb32, 0, stream>>>(ffn_W1, wF1t, 0, 0,
                                                         nullptr, 0, 1024, 4096);
  k_transpose_cvt<<<dim3(32, 128, 1), tb32, 0, stream>>>(ffn_W2, wF2t, 0, 0,
                                                         nullptr, 0, 4096, 1024);
  k_ln<true><<<8192, 256, 0, stream>>>(c1, ln_g + 5 * 1024, ln_b + 5 * 1024, hbuf);
  k_gemm<1><<<2048, 256, 0, stream>>>(hbuf, wF1t, ffn_b1, qx, nullptr, 4096, 1024, 32);
  k_gemm<2><<<512, 256, 0, stream>>>(qx, wF2t, ffn_b2, (float*)d_out, c1, 1024, 4096, 8);
}

// Round 8
// 931.458 us; speedup vs baseline: 2.8965x; 1.0409x over previous
//
#include <hip/hip_runtime.h>

// DecoderLayer (B=16, N1=512, D=1024, H=16, Dk=64, FF=4096)
// Round 8 (from R7 @ 970us, FFN2 top dispatch 111us, MfmaUtil 25%, 2 blk/CU):
//  - gemm_core templated on BK. BK=64 for the grid-capped 512-block GEMMs
//    (FFN2 K=4096, self-out K=1024): LDS 64KB caps 2/CU = grid cap anyway,
//    barriers halve, MFMA-per-barrier doubles.
//  - k_gemm3: Q-pair + KV_a + KV_b merged into one dispatch per branch pair
//    (uniform N=2048/K=1024; semantic 1152 blk, visual 1824 blk) when ws_size
//    allows the ~181.5MB merged layout; else exact R7 sequential fallback
//    (runtime branch on ws_size -> deterministic).
//  - everything else unchanged from R7 (passing, absmax 0.03125).

typedef __attribute__((ext_vector_type(4))) float          f32x4;
typedef __attribute__((ext_vector_type(8))) short          bf16x8;
typedef __attribute__((ext_vector_type(4))) unsigned short us4;

#define DEV static __device__ __forceinline__

DEV float bf2f(short h) {
  union { unsigned u; float f; } c;
  c.u = ((unsigned)(unsigned short)h) << 16;
  return c.f;
}
DEV unsigned short f2bf(float f) {  // round-to-nearest-even
  union { float f; unsigned u; } c; c.f = f;
  return (unsigned short)((c.u + 0x7fffu + ((c.u >> 16) & 1u)) >> 16);
}

// async global->LDS, 16B per lane; LDS dest is wave-uniform base + lane*16B
DEV void gll16(const unsigned short* g, unsigned short* l) {
  __builtin_amdgcn_global_load_lds((const __attribute__((address_space(1))) void*)g,
                                   (__attribute__((address_space(3))) void*)l,
                                   16, 0, 0);
}

// ---------------- transpose + f32->bf16 convert (+optional row scale) ----------------
__global__ __launch_bounds__(256)
void k_transpose_cvt(const float* __restrict__ src, unsigned short* __restrict__ dst,
                     long long sHi, long long sLo,
                     const float* __restrict__ g, int gStride, int R, int C) {
  __shared__ float tile[32][33];
  const int z = blockIdx.z;
  src += (long long)(z >> 1) * sHi + (long long)(z & 1) * sLo;
  dst += (size_t)z * R * C;
  const int c0 = blockIdx.x * 32, r0 = blockIdx.y * 32;
  const int tx = threadIdx.x, ty = threadIdx.y;
#pragma unroll
  for (int i = 0; i < 32; i += 8)
    tile[ty + i][tx] = src[(size_t)(r0 + ty + i) * C + (c0 + tx)];
  __syncthreads();
  const float gv = g ? g[(size_t)z * gStride + r0 + tx] : 1.f;
#pragma unroll
  for (int i = 0; i < 32; i += 8)
    dst[(size_t)(c0 + ty + i) * R + (r0 + tx)] = f2bf(tile[tx][ty + i] * gv);
}

// ---------------- folded bias: out[n] = b_i . Wq_i[:,c] + bq_i[c] ----------------
__global__ __launch_bounds__(256)
void k_foldbias(const float* __restrict__ b, const float* __restrict__ W,
                const float* __restrict__ bq, float* __restrict__ out) {
  __shared__ float red[4];
  const int n = blockIdx.x, i = n >> 10, c = n & 1023, t = threadIdx.x;
  const float* Wi = W + (size_t)i * 4 * 1048576 + c;
  const float* bi = b + i * 1024;
  float s = 0.f;
  for (int k = t; k < 1024; k += 256) s += bi[k] * Wi[(size_t)k * 1024];
#pragma unroll
  for (int m = 32; m >= 1; m >>= 1) s += __shfl_xor(s, m);
  if ((t & 63) == 0) red[t >> 6] = s;
  __syncthreads();
  if (t == 0) out[n] = red[0] + red[1] + red[2] + red[3] + bq[(size_t)i * 4096 + c];
}

// ---------------- f32 -> bf16 convert with zero row padding ----------------
__global__ __launch_bounds__(256)
void k_cvt_pad(const float* __restrict__ src, unsigned short* __restrict__ dst, int rows) {
  const int r = blockIdx.x;
  const int c = threadIdx.x * 4;
  us4 o;
  if (r < rows) {
    f32x4 v = *(const f32x4*)(src + (size_t)r * 1024 + c);
    o[0] = f2bf(v[0]); o[1] = f2bf(v[1]); o[2] = f2bf(v[2]); o[3] = f2bf(v[3]);
  } else {
    o[0] = 0; o[1] = 0; o[2] = 0; o[3] = 0;
  }
  *(us4*)(dst + (size_t)r * 1024 + c) = o;
}

// ---------------- LayerNorm (D=1024), f32 in -> bf16 out ----------------
template <bool AFFINE>
__global__ __launch_bounds__(256)
void k_ln(const float* __restrict__ x, const float* __restrict__ g,
          const float* __restrict__ bb, unsigned short* __restrict__ y) {
  __shared__ float red[8];
  const size_t base = (size_t)blockIdx.x * 1024;
  const int t = threadIdx.x;
  f32x4 v = *(const f32x4*)(x + base + t * 4);
  float s  = v[0] + v[1] + v[2] + v[3];
  float s2 = v[0]*v[0] + v[1]*v[1] + v[2]*v[2] + v[3]*v[3];
#pragma unroll
  for (int m = 32; m >= 1; m >>= 1) { s += __shfl_xor(s, m); s2 += __shfl_xor(s2, m); }
  const int w = t >> 6;
  if ((t & 63) == 0) { red[w] = s; red[4 + w] = s2; }
  __syncthreads();
  s  = red[0] + red[1] + red[2] + red[3];
  s2 = red[4] + red[5] + red[6] + red[7];
  const float mean = s * (1.f / 1024.f);
  const float var  = s2 * (1.f / 1024.f) - mean * mean;
  const float rstd = rsqrtf(var + 1e-5f);
  us4 o;
#pragma unroll
  for (int j = 0; j < 4; ++j) {
    const float zv = (v[j] - mean) * rstd;
    o[j] = f2bf(AFFINE ? zv * g[t * 4 + j] + bb[t * 4 + j] : zv);
  }
  *(us4*)(y + base + t * 4) = o;
}

// ---------------- GEMM core: C[M,N] = A[M,K](bf16) @ Bt[N,K]^T(bf16) + bias ----------------
// 128x128 tile, BK in {32,64}, 4 waves, 2-phase dbuf global_load_lds staging.
// MODE 0: bf16 out; 1: bf16 relu out; 2: f32 out = res(f32) + acc + bias
template <int MODE, int BK>
DEV void gemm_core(const unsigned short* __restrict__ A,
                   const unsigned short* __restrict__ Bt,
                   const float* __restrict__ bias,
                   void* __restrict__ Cout,
                   const float* __restrict__ res,
                   int N, int K, int bx, int by,
                   unsigned short* sA, unsigned short* sB) {
  const int t = threadIdx.x;
  const int l = t & 63, w = t >> 6;
  const int wr = w >> 1, wc = w & 1;

  constexpr int LPR = BK / 8;       // lanes covering one row (16B each)
  constexpr int RPI = 64 / LPR;     // rows per gll16 issue
  constexpr int IPW = 32 / RPI;     // issues per wave per matrix
  constexpr int BUF = 128 * BK;     // elems per LDS buffer

  const int glr = l / LPR;
  const int glc = (l % LPR) * 8;
  const unsigned short* gA = A  + (size_t)(by * 128 + w * 32 + glr) * K + glc;
  const unsigned short* gB = Bt + (size_t)(bx * 128 + w * 32 + glr) * K + glc;
  const int wofs = w * 32 * BK;

  const int lr = l & 15;
  const int lk = (l >> 4) << 3;

  f32x4 acc[4][4];
#pragma unroll
  for (int m = 0; m < 4; ++m)
#pragma unroll
    for (int n = 0; n < 4; ++n) { acc[m][n][0]=0.f; acc[m][n][1]=0.f; acc[m][n][2]=0.f; acc[m][n][3]=0.f; }

  auto stage = [&](int buf, int k0) {
#pragma unroll
    for (int i = 0; i < IPW; ++i) {
      gll16(gA + (size_t)i * RPI * K + k0, sA + buf * BUF + wofs + i * RPI * BK);
      gll16(gB + (size_t)i * RPI * K + k0, sB + buf * BUF + wofs + i * RPI * BK);
    }
  };
  auto compute = [&](int buf) {
#pragma unroll
    for (int ks = 0; ks < BK / 32; ++ks) {
      const unsigned short* sAr = sA + buf * BUF + (wr * 64 + lr) * BK + ks * 32 + lk;
      const unsigned short* sBr = sB + buf * BUF + (wc * 64 + lr) * BK + ks * 32 + lk;
      bf16x8 af[4], bfr[4];
#pragma unroll
      for (int m = 0; m < 4; ++m) af[m]  = *(const bf16x8*)(sAr + m * 16 * BK);
#pragma unroll
      for (int n = 0; n < 4; ++n) bfr[n] = *(const bf16x8*)(sBr + n * 16 * BK);
#pragma unroll
      for (int m = 0; m < 4; ++m)
#pragma unroll
        for (int n = 0; n < 4; ++n)
          acc[m][n] = __builtin_amdgcn_mfma_f32_16x16x32_bf16(af[m], bfr[n], acc[m][n], 0, 0, 0);
    }
  };

  stage(0, 0);
  __syncthreads();
  int cur = 0;
  for (int k0 = BK; k0 < K; k0 += BK) {
    stage(cur ^ 1, k0);
    compute(cur);
    __syncthreads();
    cur ^= 1;
  }
  compute(cur);

  const int rq = (l >> 4) << 2;  // C/D: col = lane&15, row = (lane>>4)*4 + reg
#pragma unroll
  for (int n = 0; n < 4; ++n) {
    const int cg = bx * 128 + wc * 64 + n * 16 + lr;
    const float bv = bias[cg];
#pragma unroll
    for (int m = 0; m < 4; ++m) {
#pragma unroll
      for (int r = 0; r < 4; ++r) {
        const int rg = by * 128 + wr * 64 + m * 16 + rq + r;
        const float v = acc[m][n][r] + bv;
        if constexpr (MODE == 0) {
          ((unsigned short*)Cout)[(size_t)rg * N + cg] = f2bf(v);
        } else if constexpr (MODE == 1) {
          ((unsigned short*)Cout)[(size_t)rg * N + cg] = f2bf(v > 0.f ? v : 0.f);
        } else {
          ((float*)Cout)[(size_t)rg * N + cg] = res[(size_t)rg * N + cg] + v;
        }
      }
    }
  }
}

template <int MODE, int BK>
__global__ __launch_bounds__(256)
void k_gemm(const unsigned short* __restrict__ A,
            const unsigned short* __restrict__ Bt,
            const float* __restrict__ bias,
            void* __restrict__ Cout,
            const float* __restrict__ res,
            int N, int K, int nbx) {
  __shared__ unsigned short sA[2 * 128 * BK];
  __shared__ unsigned short sB[2 * 128 * BK];
  const int nwg = gridDim.x;
  const int q8  = nwg >> 3;
  const int swz = (blockIdx.x & 7) * q8 + (blockIdx.x >> 3);
  gemm_core<MODE, BK>(A, Bt, bias, Cout, res, N, K, swz % nbx, swz / nbx, sA, sB);
}

// 2-group GEMM (bf16 out): blocks [0,nblk0) -> set0, rest -> set1.
__global__ __launch_bounds__(256)
void k_gemm2(const unsigned short* __restrict__ A0, const unsigned short* __restrict__ B0,
             const float* __restrict__ b0, unsigned short* __restrict__ C0,
             const unsigned short* __restrict__ A1, const unsigned short* __restrict__ B1,
             const float* __restrict__ b1, unsigned short* __restrict__ C1,
             int N, int K, int nbx, int nblk0) {
  __shared__ unsigned short sA[2 * 128 * 32];
  __shared__ unsigned short sB[2 * 128 * 32];
  const int nwg = gridDim.x;
  const int q8  = nwg >> 3;
  int swz = (blockIdx.x & 7) * q8 + (blockIdx.x >> 3);
  const unsigned short* A; const unsigned short* Bt; const float* bias; unsigned short* C;
  if (swz < nblk0) { A = A0; Bt = B0; bias = b0; C = C0; }
  else { swz -= nblk0; A = A1; Bt = B1; bias = b1; C = C1; }
  gemm_core<0, 32>(A, Bt, bias, C, nullptr, N, K, swz % nbx, swz / nbx, sA, sB);
}

// 3-group GEMM (bf16 out), uniform N/K/nbx across groups.
__global__ __launch_bounds__(256)
void k_gemm3(const unsigned short* __restrict__ A0, const unsigned short* __restrict__ B0,
             const float* __restrict__ b0, unsigned short* __restrict__ C0,
             const unsigned short* __restrict__ A1, const unsigned short* __restrict__ B1,
             const float* __restrict__ b1, unsigned short* __restrict__ C1,
             const unsigned short* __restrict__ A2, const unsigned short* __restrict__ B2,
             const float* __restrict__ b2, unsigned short* __restrict__ C2,
             int N, int K, int nbx, int nblk0, int nblk1) {
  __shared__ unsigned short sA[2 * 128 * 32];
  __shared__ unsigned short sB[2 * 128 * 32];
  const int nwg = gridDim.x;
  const int q8  = nwg >> 3;
  int swz = (blockIdx.x & 7) * q8 + (blockIdx.x >> 3);
  const unsigned short* A; const unsigned short* Bt; const float* bias; unsigned short* C;
  if (swz < nblk0) { A = A0; Bt = B0; bias = b0; C = C0; }
  else if (swz < nblk0 + nblk1) { swz -= nblk0; A = A1; Bt = B1; bias = b1; C = C1; }
  else { swz -= nblk0 + nblk1; A = A2; Bt = B2; bias = b2; C = C2; }
  gemm_core<0, 32>(A, Bt, bias, C, nullptr, N, K, swz % nbx, swz / nbx, sA, sB);
}

// ---------------- MFMA flash attention ----------------
template <bool CAUSAL>
__global__ __launch_bounds__(256)
void k_attn_mfma(const unsigned short* __restrict__ Q,
                 const unsigned short* __restrict__ Kb,
                 const unsigned short* __restrict__ Vb,
                 unsigned short* __restrict__ O,
                 int kvlen, int qs, int ks) {
  __shared__ __align__(16) unsigned short sK [64 * 64];
  __shared__ __align__(16) unsigned short sVt[64 * 64];
  __shared__ __align__(16) unsigned short sP [4][16 * 64];
  const int b = blockIdx.z, h = blockIdx.y, q0 = blockIdx.x * 64;
  const int t = threadIdx.x, w = t >> 6, l = t & 63;
  const int cc = l & 15, g = l >> 4;
  const int gk = g << 3;

  const unsigned short* qg =
      Q + (size_t)(b * 512 + q0 + w * 16 + cc) * qs + h * 64 + gk;
  bf16x8 qf[2];
  qf[0] = *(const bf16x8*)(qg);
  qf[1] = *(const bf16x8*)(qg + 32);

  f32x4 accO[4];
#pragma unroll
  for (int n = 0; n < 4; ++n) { accO[n][0]=0.f; accO[n][1]=0.f; accO[n][2]=0.f; accO[n][3]=0.f; }
  float om[4], ls[4];
#pragma unroll
  for (int r = 0; r < 4; ++r) { om[r] = -1e30f; ls[r] = 0.f; }

  const int sr = t >> 2;
  const int sc = (t & 3) << 4;
  const int kx = (sr & 7) << 3;
  const size_t stg0 = (size_t)(b * kvlen + sr) * ks + h * 64 + sc;

  const int kvmax = CAUSAL ? (q0 + 64) : kvlen;
  for (int c0 = 0; c0 < kvmax; c0 += 64) {
    __syncthreads();
    const size_t gr = stg0 + (size_t)c0 * ks;
    const bf16x8 k0 = *(const bf16x8*)(Kb + gr);
    const bf16x8 k1 = *(const bf16x8*)(Kb + gr + 8);
    const bf16x8 v0 = *(const bf16x8*)(Vb + gr);
    const bf16x8 v1 = *(const bf16x8*)(Vb + gr + 8);
    *(bf16x8*)(sK + sr * 64 + (sc ^ kx))       = k0;
    *(bf16x8*)(sK + sr * 64 + ((sc + 8) ^ kx)) = k1;
#pragma unroll
    for (int i = 0; i < 8; ++i) {
      const int j  = (i + 2 * (t & 3)) & 7;
      const int xj = sr ^ (j << 3);
      sVt[(sc + j)     * 64 + xj] = (unsigned short)v0[j];
      sVt[(sc + 8 + j) * 64 + xj] = (unsigned short)v1[j];
    }
    __syncthreads();

    f32x4 S[4];
#pragma unroll
    for (int n = 0; n < 4; ++n) { S[n][0]=0.f; S[n][1]=0.f; S[n][2]=0.f; S[n][3]=0.f; }
#pragma unroll
    for (int n = 0; n < 4; ++n) {
      const int kvr = (n * 16 + cc) * 64;
      const int sxk = (cc & 7) << 3;
#pragma unroll
      for (int ks2 = 0; ks2 < 2; ++ks2) {
        const bf16x8 kf = *(const bf16x8*)(sK + kvr + ((ks2 * 32 + gk) ^ sxk));
        S[n] = __builtin_amdgcn_mfma_f32_16x16x32_bf16(qf[ks2], kf, S[n], 0, 0, 0);
      }
    }

    float cm[4];
#pragma unroll
    for (int r = 0; r < 4; ++r) cm[r] = -1e30f;
#pragma unroll
    for (int n = 0; n < 4; ++n) {
      const int kvg = c0 + n * 16 + cc;
#pragma unroll
      for (int r = 0; r < 4; ++r) {
        const int qrow = q0 + w * 16 + g * 4 + r;
        const bool valid = (kvg < kvlen) && (!CAUSAL || kvg <= qrow);
        const float sv = valid ? S[n][r] * 0.125f : -1e30f;
        S[n][r] = sv;
        cm[r] = fmaxf(cm[r], sv);
      }
    }
#pragma unroll
    for (int m2 = 1; m2 <= 8; m2 <<= 1)
#pragma unroll
      for (int r = 0; r < 4; ++r) cm[r] = fmaxf(cm[r], __shfl_xor(cm[r], m2));

    float sc4[4], ps[4];
#pragma unroll
    for (int r = 0; r < 4; ++r) {
      const float mn = fmaxf(om[r], cm[r]);
      sc4[r] = __expf(om[r] - mn);
      om[r] = mn;
      ps[r] = 0.f;
    }
#pragma unroll
    for (int n = 0; n < 4; ++n) {
#pragma unroll
      for (int r = 0; r < 4; ++r) {
        const float pv = __expf(S[n][r] - om[r]);
        ps[r] += pv;
        const int q = g * 4 + r;
        sP[w][q * 64 + ((n * 16 + cc) ^ ((q & 7) << 3))] = f2bf(pv);
      }
    }
#pragma unroll
    for (int m2 = 1; m2 <= 8; m2 <<= 1)
#pragma unroll
      for (int r = 0; r < 4; ++r) ps[r] += __shfl_xor(ps[r], m2);
#pragma unroll
    for (int r = 0; r < 4; ++r) ls[r] = ls[r] * sc4[r] + ps[r];
#pragma unroll
    for (int n = 0; n < 4; ++n)
#pragma unroll
      for (int r = 0; r < 4; ++r) accO[n][r] *= sc4[r];

    const int pxk = (cc & 7) << 3;
#pragma unroll
    for (int ks2 = 0; ks2 < 2; ++ks2) {
      const bf16x8 pf = *(const bf16x8*)(&sP[w][cc * 64 + ((ks2 * 32 + gk) ^ pxk)]);
#pragma unroll
      for (int n = 0; n < 4; ++n) {
        const int d = n * 16 + cc;
        const bf16x8 vf = *(const bf16x8*)(sVt + d * 64 + ((ks2 * 32 + gk) ^ ((d & 7) << 3)));
        accO[n] = __builtin_amdgcn_mfma_f32_16x16x32_bf16(pf, vf, accO[n], 0, 0, 0);
      }
    }
  }

#pragma unroll
  for (int r = 0; r < 4; ++r) {
    const float inv = 1.f / ls[r];
    const size_t ob = ((size_t)(b * 512 + q0 + w * 16 + g * 4 + r) << 10) + h * 64;
#pragma unroll
    for (int n = 0; n < 4; ++n)
      O[ob + n * 16 + cc] = f2bf(accO[n][r] * inv);
  }
}

// ---------------- pairwise fuse gate ----------------
template <int PHASE>
__global__ __launch_bounds__(256)
void k_pair(float* __restrict__ c, const unsigned short* __restrict__ p1,
            const unsigned short* __restrict__ p2, unsigned short* __restrict__ acc) {
  __shared__ float red[8];
  const size_t base = (size_t)blockIdx.x * 1024;
  const int t = threadIdx.x;
  const f32x4 cv = *(const f32x4*)(c + base + t * 4);
  const us4 u1 = *(const us4*)(p1 + base + t * 4);
  const us4 u2 = *(const us4*)(p2 + base + t * 4);
  float f1v[4], f2v[4];
  float d1 = 0.f, d2 = 0.f;
#pragma unroll
  for (int j = 0; j < 4; ++j) {
    f1v[j] = bf2f((short)u1[j]); f2v[j] = bf2f((short)u2[j]);
    d1 += cv[j] * f1v[j]; d2 += cv[j] * f2v[j];
  }
#pragma unroll
  for (int m = 32; m >= 1; m >>= 1) { d1 += __shfl_xor(d1, m); d2 += __shfl_xor(d2, m); }
  const int w = t >> 6;
  if ((t & 63) == 0) { red[w] = d1; red[4 + w] = d2; }
  __syncthreads();
  d1 = red[0] + red[1] + red[2] + red[3];
  d2 = red[4] + red[5] + red[6] + red[7];
  const float mx = fmaxf(d1, d2);
  const float e1 = __expf(d1 - mx), e2 = __expf(d2 - mx);
  const float w1 = e1 / (e1 + e2), w2 = e2 / (e1 + e2);
  if constexpr (PHASE == 1) {
    us4 o;
#pragma unroll
    for (int j = 0; j < 4; ++j) o[j] = f2bf(0.5f * (w1 * f1v[j] + w2 * f2v[j]));
    *(us4*)(acc + base + t * 4) = o;
  } else {
    const us4 ua = *(const us4*)(acc + base + t * 4);
    f32x4 o;
#pragma unroll
    for (int j = 0; j < 4; ++j)
      o[j] = cv[j] + bf2f((short)ua[j]) + 0.5f * (w1 * f1v[j] + w2 * f2v[j]);
    *(f32x4*)(c + base + t * 4) = o;
  }
}

// ---------------- host ----------------
extern "C" void kernel_launch(void* const* d_in, const int* in_sizes, int n_in,
                              void* d_out, int out_size, void* d_ws, size_t ws_size,
                              hipStream_t stream) {
  (void)in_sizes; (void)n_in; (void)out_size;
  const float* captions      = (const float*)d_in[0];
  const float* cpt_words     = (const float*)d_in[1];
  const float* senti_words   = (const float*)d_in[2];
  const float* region_feats  = (const float*)d_in[3];
  const float* spatial_feats = (const float*)d_in[4];
  const float* att_W  = (const float*)d_in[5];
  const float* att_b  = (const float*)d_in[6];
  const float* ffn_W1 = (const float*)d_in[7];
  const float* ffn_b1 = (const float*)d_in[8];
  const float* ffn_W2 = (const float*)d_in[9];
  const float* ffn_b2 = (const float*)d_in[10];
  const float* ln_g   = (const float*)d_in[11];
  const float* ln_b   = (const float*)d_in[12];
  // d_in[13] seq_masks: tril by construction -> causal handled analytically.

  // merged layout ~181.5MB; fallback (R7) ~163MB. Branch on ws_size (constant
  // across calls -> deterministic).
  const bool merged = ws_size >= (size_t)191000000;

  char* ws = (char*)d_ws;
  size_t off = 0;
  auto alloc = [&](size_t bytes) {
    char* p = ws + off;
    off += (bytes + 255) & ~(size_t)255;
    return p;
  };
  const size_t M8 = (size_t)8 * 1024 * 1024;           // 8M elems (16 MiB bf16)
  unsigned short* hbuf = (unsigned short*)alloc(M8 * 2);
  unsigned short* qx   = (unsigned short*)alloc(M8 * 2 * 4);      // 64 MiB rotation
  float*          c1   = (float*)alloc((size_t)8192 * 1024 * 4);
  unsigned short* uni  = (unsigned short*)alloc(M8 * 2);          // accb|wF1t+wF2t
  unsigned short* wbuf = (unsigned short*)alloc(M8 * 2);          // phase weights
  unsigned short* padbA = (unsigned short*)alloc((size_t)3200 * 1024 * 2);
  unsigned short* padbB = merged ? (unsigned short*)alloc((size_t)3200 * 1024 * 2) : padbA;
  unsigned short* kvbA  = (unsigned short*)alloc((size_t)3200 * 2048 * 2);
  unsigned short* kvbB  = merged ? (unsigned short*)alloc((size_t)3200 * 2048 * 2) : kvbA;
  float*          qbs  = (float*)alloc(2048 * 4);

  const long long MSL = 1048576;
  const size_t    MSE = 1048576;
  unsigned short* accb = uni;
  unsigned short* wF1t = uni;
  unsigned short* wF2t = uni + (size_t)4096 * 1024;

  const dim3 tb32(32, 8);
  const dim3 gAttn(8, 16, 16);

  // ================= self attention (causal) =================
  k_transpose_cvt<<<dim3(32, 32, 4), tb32, 0, stream>>>(att_W, wbuf, 2 * MSL, MSL,
                                                        nullptr, 0, 1024, 1024);
  k_ln<true><<<8192, 256, 0, stream>>>(captions, ln_g, ln_b, hbuf);
  k_gemm<0, 32><<<1536, 256, 0, stream>>>(hbuf, wbuf, att_b, qx, nullptr, 3072, 1024, 24);
  k_attn_mfma<true><<<gAttn, 256, 0, stream>>>(qx, qx + 1024, qx + 2048,
                                               qx + 3 * M8, 512, 3072, 3072);
  k_gemm<2, 64><<<512, 256, 0, stream>>>(qx + 3 * M8, wbuf + 3 * MSE, att_b + 3 * 1024,
                                         c1, captions, 1024, 1024, 8);

  // ================= branches (paired), folded LN =================
  k_ln<false><<<8192, 256, 0, stream>>>(c1, nullptr, nullptr, hbuf);

  auto branch_pair = [&](int bi0, int Rp, int valid,
                         const float* wrd0, const float* wrd1, int phase) {
    // weights: Q'x2 -> wbuf[0,2MS); Wk|Wv x2 -> [2MS,6MS); Wo x2 -> [6MS,8MS)
    k_transpose_cvt<<<dim3(32, 32, 2), tb32, 0, stream>>>(
        att_W + (size_t)bi0 * 4 * MSE, wbuf, 0, 4 * MSL,
        ln_g + (size_t)bi0 * 1024, 1024, 1024, 1024);
    k_transpose_cvt<<<dim3(32, 32, 4), tb32, 0, stream>>>(
        att_W + ((size_t)bi0 * 4 + 1) * MSE, wbuf + 2 * MSE, 4 * MSL, MSL,
        nullptr, 0, 1024, 1024);
    k_transpose_cvt<<<dim3(32, 32, 2), tb32, 0, stream>>>(
        att_W + ((size_t)bi0 * 4 + 3) * MSE, wbuf + 6 * MSE, 0, 4 * MSL,
        nullptr, 0, 1024, 1024);
    k_foldbias<<<2048, 256, 0, stream>>>(ln_b + (size_t)bi0 * 1024,
                                         att_W + (size_t)bi0 * 4 * MSE,
                                         att_b + (size_t)bi0 * 4 * 1024, qbs);
    const int kvblk = (Rp / 128) * 16;
    const int nrows = valid * 16;

    if (merged) {
      // Q-pair + KV_a + KV_b in ONE dispatch (uniform N=2048, K=1024, nbx=16)
      k_cvt_pad<<<Rp, 256, 0, stream>>>(wrd0, padbA, nrows);
      k_cvt_pad<<<Rp, 256, 0, stream>>>(wrd1, padbB, nrows);
      k_gemm3<<<1024 + 2 * kvblk, 256, 0, stream>>>(
          hbuf, wbuf, qbs, qx,
          padbA, wbuf + 2 * MSE, att_b + ((size_t)bi0 * 4 + 1) * 1024, kvbA,
          padbB, wbuf + 4 * MSE, att_b + ((size_t)(bi0 + 1) * 4 + 1) * 1024, kvbB,
          2048, 1024, 16, 1024, kvblk);
      k_attn_mfma<false><<<gAttn, 256, 0, stream>>>(
          qx, kvbA, kvbA + 1024, qx + 2 * M8, valid, 2048, 2048);
      k_attn_mfma<false><<<gAttn, 256, 0, stream>>>(
          qx + 1024, kvbB, kvbB + 1024, qx + 3 * M8, valid, 2048, 2048);
    } else {
      // R7 sequential fallback (shared padb/kvb)
      k_gemm<0, 32><<<1024, 256, 0, stream>>>(hbuf, wbuf, qbs, qx, nullptr,
                                              2048, 1024, 16);
      k_cvt_pad<<<Rp, 256, 0, stream>>>(wrd0, padbA, nrows);
      k_gemm<0, 32><<<kvblk, 256, 0, stream>>>(padbA, wbuf + 2 * MSE,
                                               att_b + ((size_t)bi0 * 4 + 1) * 1024,
                                               kvbA, nullptr, 2048, 1024, 16);
      k_attn_mfma<false><<<gAttn, 256, 0, stream>>>(
          qx, kvbA, kvbA + 1024, qx + 2 * M8, valid, 2048, 2048);
      k_cvt_pad<<<Rp, 256, 0, stream>>>(wrd1, padbA, nrows);
      k_gemm<0, 32><<<kvblk, 256, 0, stream>>>(padbA, wbuf + 4 * MSE,
                                               att_b + ((size_t)(bi0 + 1) * 4 + 1) * 1024,
                                               kvbA, nullptr, 2048, 1024, 16);
      k_attn_mfma<false><<<gAttn, 256, 0, stream>>>(
          qx + 1024, kvbA, kvbA + 1024, qx + 3 * M8, valid, 2048, 2048);
    }
    // out pair grouped -> bp0 = qx[0,8M), bp1 = qx[8M,16M)
    k_gemm2<<<1024, 256, 0, stream>>>(
        qx + 2 * M8, wbuf + 6 * MSE, att_b + ((size_t)bi0 * 4 + 3) * 1024, qx,
        qx + 3 * M8, wbuf + 7 * MSE, att_b + ((size_t)(bi0 + 1) * 4 + 3) * 1024,
        qx + M8, 1024, 1024, 8, 512);
    if (phase == 1) k_pair<1><<<8192, 256, 0, stream>>>(c1, qx, qx + M8, accb);
    else            k_pair<2><<<8192, 256, 0, stream>>>(c1, qx, qx + M8, accb);
  };

  branch_pair(1, 512,  25,  cpt_words,    senti_words,   1);  // semantic
  branch_pair(3, 3200, 196, region_feats, spatial_feats, 2);  // visual -> c1 = fuse

  // ================= FFN =================
  k_transpose_cvt<<<dim3(128, 32, 1), tb32, 0, stream>>>(ffn_W1, wF1t, 0, 0,
                                                         nullptr, 0, 1024, 4096);
  k_transpose_cvt<<<dim3(32, 128, 1), tb32, 0, stream>>>(ffn_W2, wF2t, 0, 0,
                                                         nullptr, 0, 4096, 1024);
  k_ln<true><<<8192, 256, 0, stream>>>(c1, ln_g + 5 * 1024, ln_b + 5 * 1024, hbuf);
  k_gemm<1, 32><<<2048, 256, 0, stream>>>(hbuf, wF1t, ffn_b1, qx, nullptr, 4096, 1024, 32);
  k_gemm<2, 64><<<512, 256, 0, stream>>>(qx, wF2t, ffn_b2, (float*)d_out, c1,
                                         1024, 4096, 8);
}

// Round 9
// 882.044 us; speedup vs baseline: 3.0588x; 1.0560x over previous
//
#include <hip/hip_runtime.h>

// DecoderLayer (B=16, N1=512, D=1024, H=16, Dk=64, FF=4096)
// Round 9 (from R8 @ 931us): fix the BK=64 bank-conflict regression found in
// counters (SQ_LDS_BANK_CONFLICT 8.4M->25.2M, FFN2 111->127us). T2 XOR swizzle
// on the BK=64 GEMM LDS, done the global_load_lds-legal way (rule #21):
//   linear LDS dest + inverse-swizzled GLOBAL source (col = ((l&7)^(l>>3))*8)
//   + swizzled read (slot = (ks*4+g) ^ (row&7)) -> 2 lanes/bank (free).
// BK=32 paths byte-identical to R8. Everything else unchanged (passing 0.03125).

typedef __attribute__((ext_vector_type(4))) float          f32x4;
typedef __attribute__((ext_vector_type(8))) short          bf16x8;
typedef __attribute__((ext_vector_type(4))) unsigned short us4;

#define DEV static __device__ __forceinline__

DEV float bf2f(short h) {
  union { unsigned u; float f; } c;
  c.u = ((unsigned)(unsigned short)h) << 16;
  return c.f;
}
DEV unsigned short f2bf(float f) {  // round-to-nearest-even
  union { float f; unsigned u; } c; c.f = f;
  return (unsigned short)((c.u + 0x7fffu + ((c.u >> 16) & 1u)) >> 16);
}

// async global->LDS, 16B per lane; LDS dest is wave-uniform base + lane*16B
DEV void gll16(const unsigned short* g, unsigned short* l) {
  __builtin_amdgcn_global_load_lds((const __attribute__((address_space(1))) void*)g,
                                   (__attribute__((address_space(3))) void*)l,
                                   16, 0, 0);
}

// ---------------- transpose + f32->bf16 convert (+optional row scale) ----------------
__global__ __launch_bounds__(256)
void k_transpose_cvt(const float* __restrict__ src, unsigned short* __restrict__ dst,
                     long long sHi, long long sLo,
                     const float* __restrict__ g, int gStride, int R, int C) {
  __shared__ float tile[32][33];
  const int z = blockIdx.z;
  src += (long long)(z >> 1) * sHi + (long long)(z & 1) * sLo;
  dst += (size_t)z * R * C;
  const int c0 = blockIdx.x * 32, r0 = blockIdx.y * 32;
  const int tx = threadIdx.x, ty = threadIdx.y;
#pragma unroll
  for (int i = 0; i < 32; i += 8)
    tile[ty + i][tx] = src[(size_t)(r0 + ty + i) * C + (c0 + tx)];
  __syncthreads();
  const float gv = g ? g[(size_t)z * gStride + r0 + tx] : 1.f;
#pragma unroll
  for (int i = 0; i < 32; i += 8)
    dst[(size_t)(c0 + ty + i) * R + (r0 + tx)] = f2bf(tile[tx][ty + i] * gv);
}

// ---------------- folded bias: out[n] = b_i . Wq_i[:,c] + bq_i[c] ----------------
__global__ __launch_bounds__(256)
void k_foldbias(const float* __restrict__ b, const float* __restrict__ W,
                const float* __restrict__ bq, float* __restrict__ out) {
  __shared__ float red[4];
  const int n = blockIdx.x, i = n >> 10, c = n & 1023, t = threadIdx.x;
  const float* Wi = W + (size_t)i * 4 * 1048576 + c;
  const float* bi = b + i * 1024;
  float s = 0.f;
  for (int k = t; k < 1024; k += 256) s += bi[k] * Wi[(size_t)k * 1024];
#pragma unroll
  for (int m = 32; m >= 1; m >>= 1) s += __shfl_xor(s, m);
  if ((t & 63) == 0) red[t >> 6] = s;
  __syncthreads();
  if (t == 0) out[n] = red[0] + red[1] + red[2] + red[3] + bq[(size_t)i * 4096 + c];
}

// ---------------- f32 -> bf16 convert with zero row padding ----------------
__global__ __launch_bounds__(256)
void k_cvt_pad(const float* __restrict__ src, unsigned short* __restrict__ dst, int rows) {
  const int r = blockIdx.x;
  const int c = threadIdx.x * 4;
  us4 o;
  if (r < rows) {
    f32x4 v = *(const f32x4*)(src + (size_t)r * 1024 + c);
    o[0] = f2bf(v[0]); o[1] = f2bf(v[1]); o[2] = f2bf(v[2]); o[3] = f2bf(v[3]);
  } else {
    o[0] = 0; o[1] = 0; o[2] = 0; o[3] = 0;
  }
  *(us4*)(dst + (size_t)r * 1024 + c) = o;
}

// ---------------- LayerNorm (D=1024), f32 in -> bf16 out ----------------
template <bool AFFINE>
__global__ __launch_bounds__(256)
void k_ln(const float* __restrict__ x, const float* __restrict__ g,
          const float* __restrict__ bb, unsigned short* __restrict__ y) {
  __shared__ float red[8];
  const size_t base = (size_t)blockIdx.x * 1024;
  const int t = threadIdx.x;
  f32x4 v = *(const f32x4*)(x + base + t * 4);
  float s  = v[0] + v[1] + v[2] + v[3];
  float s2 = v[0]*v[0] + v[1]*v[1] + v[2]*v[2] + v[3]*v[3];
#pragma unroll
  for (int m = 32; m >= 1; m >>= 1) { s += __shfl_xor(s, m); s2 += __shfl_xor(s2, m); }
  const int w = t >> 6;
  if ((t & 63) == 0) { red[w] = s; red[4 + w] = s2; }
  __syncthreads();
  s  = red[0] + red[1] + red[2] + red[3];
  s2 = red[4] + red[5] + red[6] + red[7];
  const float mean = s * (1.f / 1024.f);
  const float var  = s2 * (1.f / 1024.f) - mean * mean;
  const float rstd = rsqrtf(var + 1e-5f);
  us4 o;
#pragma unroll
  for (int j = 0; j < 4; ++j) {
    const float zv = (v[j] - mean) * rstd;
    o[j] = f2bf(AFFINE ? zv * g[t * 4 + j] + bb[t * 4 + j] : zv);
  }
  *(us4*)(y + base + t * 4) = o;
}

// ---------------- GEMM core: C[M,N] = A[M,K](bf16) @ Bt[N,K]^T(bf16) + bias ----------------
// 128x128 tile, BK in {32,64}, 4 waves, 2-phase dbuf global_load_lds staging.
// BK=64 adds T2 XOR swizzle (pre-swizzled source + swizzled ds_read).
// MODE 0: bf16 out; 1: bf16 relu out; 2: f32 out = res(f32) + acc + bias
template <int MODE, int BK>
DEV void gemm_core(const unsigned short* __restrict__ A,
                   const unsigned short* __restrict__ Bt,
                   const float* __restrict__ bias,
                   void* __restrict__ Cout,
                   const float* __restrict__ res,
                   int N, int K, int bx, int by,
                   unsigned short* sA, unsigned short* sB) {
  const int t = threadIdx.x;
  const int l = t & 63, w = t >> 6;
  const int wr = w >> 1, wc = w & 1;

  constexpr int  LPR = BK / 8;       // lanes covering one row (16B each)
  constexpr int  RPI = 64 / LPR;     // rows per gll16 issue
  constexpr int  IPW = 32 / RPI;     // issues per wave per matrix
  constexpr int  BUF = 128 * BK;     // elems per LDS buffer
  constexpr bool SWZ = (BK == 64);   // T2 swizzle (conflict fix) for 128B rows

  const int glr = l / LPR;
  // SWZ: LDS slot l%8 of row l>>3 must hold global 16B chunk (l%8)^(l>>3)
  const int glc = SWZ ? (((l & 7) ^ (l >> 3)) << 3) : ((l % LPR) << 3);
  const unsigned short* gA = A  + (size_t)(by * 128 + w * 32 + glr) * K + glc;
  const unsigned short* gB = Bt + (size_t)(bx * 128 + w * 32 + glr) * K + glc;
  const int wofs = w * 32 * BK;

  const int lr = l & 15;
  const int gq = l >> 4;             // k-quarter 0..3
  const int xr = SWZ ? (lr & 7) : 0; // read-side slot xor

  f32x4 acc[4][4];
#pragma unroll
  for (int m = 0; m < 4; ++m)
#pragma unroll
    for (int n = 0; n < 4; ++n) { acc[m][n][0]=0.f; acc[m][n][1]=0.f; acc[m][n][2]=0.f; acc[m][n][3]=0.f; }

  auto stage = [&](int buf, int k0) {
#pragma unroll
    for (int i = 0; i < IPW; ++i) {
      gll16(gA + (size_t)i * RPI * K + k0, sA + buf * BUF + wofs + i * RPI * BK);
      gll16(gB + (size_t)i * RPI * K + k0, sB + buf * BUF + wofs + i * RPI * BK);
    }
  };
  auto compute = [&](int buf) {
#pragma unroll
    for (int ks = 0; ks < BK / 32; ++ks) {
      // 16B-slot index within the row, then optional row-parity xor
      const int col = (((ks * 4 + gq) ^ xr) << 3);
      const unsigned short* sAr = sA + buf * BUF + (wr * 64 + lr) * BK + col;
      const unsigned short* sBr = sB + buf * BUF + (wc * 64 + lr) * BK + col;
      bf16x8 af[4], bfr[4];
#pragma unroll
      for (int m = 0; m < 4; ++m) af[m]  = *(const bf16x8*)(sAr + m * 16 * BK);
#pragma unroll
      for (int n = 0; n < 4; ++n) bfr[n] = *(const bf16x8*)(sBr + n * 16 * BK);
#pragma unroll
      for (int m = 0; m < 4; ++m)
#pragma unroll
        for (int n = 0; n < 4; ++n)
          acc[m][n] = __builtin_amdgcn_mfma_f32_16x16x32_bf16(af[m], bfr[n], acc[m][n], 0, 0, 0);
    }
  };

  stage(0, 0);
  __syncthreads();
  int cur = 0;
  for (int k0 = BK; k0 < K; k0 += BK) {
    stage(cur ^ 1, k0);
    compute(cur);
    __syncthreads();
    cur ^= 1;
  }
  compute(cur);

  const int rq = (l >> 4) << 2;  // C/D: col = lane&15, row = (lane>>4)*4 + reg
#pragma unroll
  for (int n = 0; n < 4; ++n) {
    const int cg = bx * 128 + wc * 64 + n * 16 + lr;
    const float bv = bias[cg];
#pragma unroll
    for (int m = 0; m < 4; ++m) {
#pragma unroll
      for (int r = 0; r < 4; ++r) {
        const int rg = by * 128 + wr * 64 + m * 16 + rq + r;
        const float v = acc[m][n][r] + bv;
        if constexpr (MODE == 0) {
          ((unsigned short*)Cout)[(size_t)rg * N + cg] = f2bf(v);
        } else if constexpr (MODE == 1) {
          ((unsigned short*)Cout)[(size_t)rg * N + cg] = f2bf(v > 0.f ? v : 0.f);
        } else {
          ((float*)Cout)[(size_t)rg * N + cg] = res[(size_t)rg * N + cg] + v;
        }
      }
    }
  }
}

template <int MODE, int BK>
__global__ __launch_bounds__(256)
void k_gemm(const unsigned short* __restrict__ A,
            const unsigned short* __restrict__ Bt,
            const float* __restrict__ bias,
            void* __restrict__ Cout,
            const float* __restrict__ res,
            int N, int K, int nbx) {
  __shared__ unsigned short sA[2 * 128 * BK];
  __shared__ unsigned short sB[2 * 128 * BK];
  const int nwg = gridDim.x;
  const int q8  = nwg >> 3;
  const int swz = (blockIdx.x & 7) * q8 + (blockIdx.x >> 3);
  gemm_core<MODE, BK>(A, Bt, bias, Cout, res, N, K, swz % nbx, swz / nbx, sA, sB);
}

// 2-group GEMM (bf16 out): blocks [0,nblk0) -> set0, rest -> set1.
__global__ __launch_bounds__(256)
void k_gemm2(const unsigned short* __restrict__ A0, const unsigned short* __restrict__ B0,
             const float* __restrict__ b0, unsigned short* __restrict__ C0,
             const unsigned short* __restrict__ A1, const unsigned short* __restrict__ B1,
             const float* __restrict__ b1, unsigned short* __restrict__ C1,
             int N, int K, int nbx, int nblk0) {
  __shared__ unsigned short sA[2 * 128 * 32];
  __shared__ unsigned short sB[2 * 128 * 32];
  const int nwg = gridDim.x;
  const int q8  = nwg >> 3;
  int swz = (blockIdx.x & 7) * q8 + (blockIdx.x >> 3);
  const unsigned short* A; const unsigned short* Bt; const float* bias; unsigned short* C;
  if (swz < nblk0) { A = A0; Bt = B0; bias = b0; C = C0; }
  else { swz -= nblk0; A = A1; Bt = B1; bias = b1; C = C1; }
  gemm_core<0, 32>(A, Bt, bias, C, nullptr, N, K, swz % nbx, swz / nbx, sA, sB);
}

// 3-group GEMM (bf16 out), uniform N/K/nbx across groups.
__global__ __launch_bounds__(256)
void k_gemm3(const unsigned short* __restrict__ A0, const unsigned short* __restrict__ B0,
             const float* __restrict__ b0, unsigned short* __restrict__ C0,
             const unsigned short* __restrict__ A1, const unsigned short* __restrict__ B1,
             const float* __restrict__ b1, unsigned short* __restrict__ C1,
             const unsigned short* __restrict__ A2, const unsigned short* __restrict__ B2,
             const float* __restrict__ b2, unsigned short* __restrict__ C2,
             int N, int K, int nbx, int nblk0, int nblk1) {
  __shared__ unsigned short sA[2 * 128 * 32];
  __shared__ unsigned short sB[2 * 128 * 32];
  const int nwg = gridDim.x;
  const int q8  = nwg >> 3;
  int swz = (blockIdx.x & 7) * q8 + (blockIdx.x >> 3);
  const unsigned short* A; const unsigned short* Bt; const float* bias; unsigned short* C;
  if (swz < nblk0) { A = A0; Bt = B0; bias = b0; C = C0; }
  else if (swz < nblk0 + nblk1) { swz -= nblk0; A = A1; Bt = B1; bias = b1; C = C1; }
  else { swz -= nblk0 + nblk1; A = A2; Bt = B2; bias = b2; C = C2; }
  gemm_core<0, 32>(A, Bt, bias, C, nullptr, N, K, swz % nbx, swz / nbx, sA, sB);
}

// ---------------- MFMA flash attention ----------------
template <bool CAUSAL>
__global__ __launch_bounds__(256)
void k_attn_mfma(const unsigned short* __restrict__ Q,
                 const unsigned short* __restrict__ Kb,
                 const unsigned short* __restrict__ Vb,
                 unsigned short* __restrict__ O,
                 int kvlen, int qs, int ks) {
  __shared__ __align__(16) unsigned short sK [64 * 64];
  __shared__ __align__(16) unsigned short sVt[64 * 64];
  __shared__ __align__(16) unsigned short sP [4][16 * 64];
  const int b = blockIdx.z, h = blockIdx.y, q0 = blockIdx.x * 64;
  const int t = threadIdx.x, w = t >> 6, l = t & 63;
  const int cc = l & 15, g = l >> 4;
  const int gk = g << 3;

  const unsigned short* qg =
      Q + (size_t)(b * 512 + q0 + w * 16 + cc) * qs + h * 64 + gk;
  bf16x8 qf[2];
  qf[0] = *(const bf16x8*)(qg);
  qf[1] = *(const bf16x8*)(qg + 32);

  f32x4 accO[4];
#pragma unroll
  for (int n = 0; n < 4; ++n) { accO[n][0]=0.f; accO[n][1]=0.f; accO[n][2]=0.f; accO[n][3]=0.f; }
  float om[4], ls[4];
#pragma unroll
  for (int r = 0; r < 4; ++r) { om[r] = -1e30f; ls[r] = 0.f; }

  const int sr = t >> 2;
  const int sc = (t & 3) << 4;
  const int kx = (sr & 7) << 3;
  const size_t stg0 = (size_t)(b * kvlen + sr) * ks + h * 64 + sc;

  const int kvmax = CAUSAL ? (q0 + 64) : kvlen;
  for (int c0 = 0; c0 < kvmax; c0 += 64) {
    __syncthreads();
    const size_t gr = stg0 + (size_t)c0 * ks;
    const bf16x8 k0 = *(const bf16x8*)(Kb + gr);
    const bf16x8 k1 = *(const bf16x8*)(Kb + gr + 8);
    const bf16x8 v0 = *(const bf16x8*)(Vb + gr);
    const bf16x8 v1 = *(const bf16x8*)(Vb + gr + 8);
    *(bf16x8*)(sK + sr * 64 + (sc ^ kx))       = k0;
    *(bf16x8*)(sK + sr * 64 + ((sc + 8) ^ kx)) = k1;
#pragma unroll
    for (int i = 0; i < 8; ++i) {
      const int j  = (i + 2 * (t & 3)) & 7;
      const int xj = sr ^ (j << 3);
      sVt[(sc + j)     * 64 + xj] = (unsigned short)v0[j];
      sVt[(sc + 8 + j) * 64 + xj] = (unsigned short)v1[j];
    }
    __syncthreads();

    f32x4 S[4];
#pragma unroll
    for (int n = 0; n < 4; ++n) { S[n][0]=0.f; S[n][1]=0.f; S[n][2]=0.f; S[n][3]=0.f; }
#pragma unroll
    for (int n = 0; n < 4; ++n) {
      const int kvr = (n * 16 + cc) * 64;
      const int sxk = (cc & 7) << 3;
#pragma unroll
      for (int ks2 = 0; ks2 < 2; ++ks2) {
        const bf16x8 kf = *(const bf16x8*)(sK + kvr + ((ks2 * 32 + gk) ^ sxk));
        S[n] = __builtin_amdgcn_mfma_f32_16x16x32_bf16(qf[ks2], kf, S[n], 0, 0, 0);
      }
    }

    float cm[4];
#pragma unroll
    for (int r = 0; r < 4; ++r) cm[r] = -1e30f;
#pragma unroll
    for (int n = 0; n < 4; ++n) {
      const int kvg = c0 + n * 16 + cc;
#pragma unroll
      for (int r = 0; r < 4; ++r) {
        const int qrow = q0 + w * 16 + g * 4 + r;
        const bool valid = (kvg < kvlen) && (!CAUSAL || kvg <= qrow);
        const float sv = valid ? S[n][r] * 0.125f : -1e30f;
        S[n][r] = sv;
        cm[r] = fmaxf(cm[r], sv);
      }
    }
#pragma unroll
    for (int m2 = 1; m2 <= 8; m2 <<= 1)
#pragma unroll
      for (int r = 0; r < 4; ++r) cm[r] = fmaxf(cm[r], __shfl_xor(cm[r], m2));

    float sc4[4], ps[4];
#pragma unroll
    for (int r = 0; r < 4; ++r) {
      const float mn = fmaxf(om[r], cm[r]);
      sc4[r] = __expf(om[r] - mn);
      om[r] = mn;
      ps[r] = 0.f;
    }
#pragma unroll
    for (int n = 0; n < 4; ++n) {
#pragma unroll
      for (int r = 0; r < 4; ++r) {
        const float pv = __expf(S[n][r] - om[r]);
        ps[r] += pv;
        const int q = g * 4 + r;
        sP[w][q * 64 + ((n * 16 + cc) ^ ((q & 7) << 3))] = f2bf(pv);
      }
    }
#pragma unroll
    for (int m2 = 1; m2 <= 8; m2 <<= 1)
#pragma unroll
      for (int r = 0; r < 4; ++r) ps[r] += __shfl_xor(ps[r], m2);
#pragma unroll
    for (int r = 0; r < 4; ++r) ls[r] = ls[r] * sc4[r] + ps[r];
#pragma unroll
    for (int n = 0; n < 4; ++n)
#pragma unroll
      for (int r = 0; r < 4; ++r) accO[n][r] *= sc4[r];

    const int pxk = (cc & 7) << 3;
#pragma unroll
    for (int ks2 = 0; ks2 < 2; ++ks2) {
      const bf16x8 pf = *(const bf16x8*)(&sP[w][cc * 64 + ((ks2 * 32 + gk) ^ pxk)]);
#pragma unroll
      for (int n = 0; n < 4; ++n) {
        const int d = n * 16 + cc;
        const bf16x8 vf = *(const bf16x8*)(sVt + d * 64 + ((ks2 * 32 + gk) ^ ((d & 7) << 3)));
        accO[n] = __builtin_amdgcn_mfma_f32_16x16x32_bf16(pf, vf, accO[n], 0, 0, 0);
      }
    }
  }

#pragma unroll
  for (int r = 0; r < 4; ++r) {
    const float inv = 1.f / ls[r];
    const size_t ob = ((size_t)(b * 512 + q0 + w * 16 + g * 4 + r) << 10) + h * 64;
#pragma unroll
    for (int n = 0; n < 4; ++n)
      O[ob + n * 16 + cc] = f2bf(accO[n][r] * inv);
  }
}

// ---------------- pairwise fuse gate ----------------
template <int PHASE>
__global__ __launch_bounds__(256)
void k_pair(float* __restrict__ c, const unsigned short* __restrict__ p1,
            const unsigned short* __restrict__ p2, unsigned short* __restrict__ acc) {
  __shared__ float red[8];
  const size_t base = (size_t)blockIdx.x * 1024;
  const int t = threadIdx.x;
  const f32x4 cv = *(const f32x4*)(c + base + t * 4);
  const us4 u1 = *(const us4*)(p1 + base + t * 4);
  const us4 u2 = *(const us4*)(p2 + base + t * 4);
  float f1v[4], f2v[4];
  float d1 = 0.f, d2 = 0.f;
#pragma unroll
  for (int j = 0; j < 4; ++j) {
    f1v[j] = bf2f((short)u1[j]); f2v[j] = bf2f((short)u2[j]);
    d1 += cv[j] * f1v[j]; d2 += cv[j] * f2v[j];
  }
#pragma unroll
  for (int m = 32; m >= 1; m >>= 1) { d1 += __shfl_xor(d1, m); d2 += __shfl_xor(d2, m); }
  const int w = t >> 6;
  if ((t & 63) == 0) { red[w] = d1; red[4 + w] = d2; }
  __syncthreads();
  d1 = red[0] + red[1] + red[2] + red[3];
  d2 = red[4] + red[5] + red[6] + red[7];
  const float mx = fmaxf(d1, d2);
  const float e1 = __expf(d1 - mx), e2 = __expf(d2 - mx);
  const float w1 = e1 / (e1 + e2), w2 = e2 / (e1 + e2);
  if constexpr (PHASE == 1) {
    us4 o;
#pragma unroll
    for (int j = 0; j < 4; ++j) o[j] = f2bf(0.5f * (w1 * f1v[j] + w2 * f2v[j]));
    *(us4*)(acc + base + t * 4) = o;
  } else {
    const us4 ua = *(const us4*)(acc + base + t * 4);
    f32x4 o;
#pragma unroll
    for (int j = 0; j < 4; ++j)
      o[j] = cv[j] + bf2f((short)ua[j]) + 0.5f * (w1 * f1v[j] + w2 * f2v[j]);
    *(f32x4*)(c + base + t * 4) = o;
  }
}

// ---------------- host ----------------
extern "C" void kernel_launch(void* const* d_in, const int* in_sizes, int n_in,
                              void* d_out, int out_size, void* d_ws, size_t ws_size,
                              hipStream_t stream) {
  (void)in_sizes; (void)n_in; (void)out_size;
  const float* captions      = (const float*)d_in[0];
  const float* cpt_words     = (const float*)d_in[1];
  const float* senti_words   = (const float*)d_in[2];
  const float* region_feats  = (const float*)d_in[3];
  const float* spatial_feats = (const float*)d_in[4];
  const float* att_W  = (const float*)d_in[5];
  const float* att_b  = (const float*)d_in[6];
  const float* ffn_W1 = (const float*)d_in[7];
  const float* ffn_b1 = (const float*)d_in[8];
  const float* ffn_W2 = (const float*)d_in[9];
  const float* ffn_b2 = (const float*)d_in[10];
  const float* ln_g   = (const float*)d_in[11];
  const float* ln_b   = (const float*)d_in[12];
  // d_in[13] seq_masks: tril by construction -> causal handled analytically.

  const bool merged = ws_size >= (size_t)191000000;

  char* ws = (char*)d_ws;
  size_t off = 0;
  auto alloc = [&](size_t bytes) {
    char* p = ws + off;
    off += (bytes + 255) & ~(size_t)255;
    return p;
  };
  const size_t M8 = (size_t)8 * 1024 * 1024;           // 8M elems (16 MiB bf16)
  unsigned short* hbuf = (unsigned short*)alloc(M8 * 2);
  unsigned short* qx   = (unsigned short*)alloc(M8 * 2 * 4);      // 64 MiB rotation
  float*          c1   = (float*)alloc((size_t)8192 * 1024 * 4);
  unsigned short* uni  = (unsigned short*)alloc(M8 * 2);          // accb|wF1t+wF2t
  unsigned short* wbuf = (unsigned short*)alloc(M8 * 2);          // phase weights
  unsigned short* padbA = (unsigned short*)alloc((size_t)3200 * 1024 * 2);
  unsigned short* padbB = merged ? (unsigned short*)alloc((size_t)3200 * 1024 * 2) : padbA;
  unsigned short* kvbA  = (unsigned short*)alloc((size_t)3200 * 2048 * 2);
  unsigned short* kvbB  = merged ? (unsigned short*)alloc((size_t)3200 * 2048 * 2) : kvbA;
  float*          qbs  = (float*)alloc(2048 * 4);

  const long long MSL = 1048576;
  const size_t    MSE = 1048576;
  unsigned short* accb = uni;
  unsigned short* wF1t = uni;
  unsigned short* wF2t = uni + (size_t)4096 * 1024;

  const dim3 tb32(32, 8);
  const dim3 gAttn(8, 16, 16);

  // ================= self attention (causal) =================
  k_transpose_cvt<<<dim3(32, 32, 4), tb32, 0, stream>>>(att_W, wbuf, 2 * MSL, MSL,
                                                        nullptr, 0, 1024, 1024);
  k_ln<true><<<8192, 256, 0, stream>>>(captions, ln_g, ln_b, hbuf);
  k_gemm<0, 32><<<1536, 256, 0, stream>>>(hbuf, wbuf, att_b, qx, nullptr, 3072, 1024, 24);
  k_attn_mfma<true><<<gAttn, 256, 0, stream>>>(qx, qx + 1024, qx + 2048,
                                               qx + 3 * M8, 512, 3072, 3072);
  k_gemm<2, 64><<<512, 256, 0, stream>>>(qx + 3 * M8, wbuf + 3 * MSE, att_b + 3 * 1024,
                                         c1, captions, 1024, 1024, 8);

  // ================= branches (paired), folded LN =================
  k_ln<false><<<8192, 256, 0, stream>>>(c1, nullptr, nullptr, hbuf);

  auto branch_pair = [&](int bi0, int Rp, int valid,
                         const float* wrd0, const float* wrd1, int phase) {
    // weights: Q'x2 -> wbuf[0,2MS); Wk|Wv x2 -> [2MS,6MS); Wo x2 -> [6MS,8MS)
    k_transpose_cvt<<<dim3(32, 32, 2), tb32, 0, stream>>>(
        att_W + (size_t)bi0 * 4 * MSE, wbuf, 0, 4 * MSL,
        ln_g + (size_t)bi0 * 1024, 1024, 1024, 1024);
    k_transpose_cvt<<<dim3(32, 32, 4), tb32, 0, stream>>>(
        att_W + ((size_t)bi0 * 4 + 1) * MSE, wbuf + 2 * MSE, 4 * MSL, MSL,
        nullptr, 0, 1024, 1024);
    k_transpose_cvt<<<dim3(32, 32, 2), tb32, 0, stream>>>(
        att_W + ((size_t)bi0 * 4 + 3) * MSE, wbuf + 6 * MSE, 0, 4 * MSL,
        nullptr, 0, 1024, 1024);
    k_foldbias<<<2048, 256, 0, stream>>>(ln_b + (size_t)bi0 * 1024,
                                         att_W + (size_t)bi0 * 4 * MSE,
                                         att_b + (size_t)bi0 * 4 * 1024, qbs);
    const int kvblk = (Rp / 128) * 16;
    const int nrows = valid * 16;

    if (merged) {
      k_cvt_pad<<<Rp, 256, 0, stream>>>(wrd0, padbA, nrows);
      k_cvt_pad<<<Rp, 256, 0, stream>>>(wrd1, padbB, nrows);
      k_gemm3<<<1024 + 2 * kvblk, 256, 0, stream>>>(
          hbuf, wbuf, qbs, qx,
          padbA, wbuf + 2 * MSE, att_b + ((size_t)bi0 * 4 + 1) * 1024, kvbA,
          padbB, wbuf + 4 * MSE, att_b + ((size_t)(bi0 + 1) * 4 + 1) * 1024, kvbB,
          2048, 1024, 16, 1024, kvblk);
      k_attn_mfma<false><<<gAttn, 256, 0, stream>>>(
          qx, kvbA, kvbA + 1024, qx + 2 * M8, valid, 2048, 2048);
      k_attn_mfma<false><<<gAttn, 256, 0, stream>>>(
          qx + 1024, kvbB, kvbB + 1024, qx + 3 * M8, valid, 2048, 2048);
    } else {
      k_gemm<0, 32><<<1024, 256, 0, stream>>>(hbuf, wbuf, qbs, qx, nullptr,
                                              2048, 1024, 16);
      k_cvt_pad<<<Rp, 256, 0, stream>>>(wrd0, padbA, nrows);
      k_gemm<0, 32><<<kvblk, 256, 0, stream>>>(padbA, wbuf + 2 * MSE,
                                               att_b + ((size_t)bi0 * 4 + 1) * 1024,
                                               kvbA, nullptr, 2048, 1024, 16);
      k_attn_mfma<false><<<gAttn, 256, 0, stream>>>(
          qx, kvbA, kvbA + 1024, qx + 2 * M8, valid, 2048, 2048);
      k_cvt_pad<<<Rp, 256, 0, stream>>>(wrd1, padbA, nrows);
      k_gemm<0, 32><<<kvblk, 256, 0, stream>>>(padbA, wbuf + 4 * MSE,
                                               att_b + ((size_t)(bi0 + 1) * 4 + 1) * 1024,
                                               kvbA, nullptr, 2048, 1024, 16);
      k_attn_mfma<false><<<gAttn, 256, 0, stream>>>(
          qx + 1024, kvbA, kvbA + 1024, qx + 3 * M8, valid, 2048, 2048);
    }
    k_gemm2<<<1024, 256, 0, stream>>>(
        qx + 2 * M8, wbuf + 6 * MSE, att_b + ((size_t)bi0 * 4 + 3) * 1024, qx,
        qx + 3 * M8, wbuf + 7 * MSE, att_b + ((size_t)(bi0 + 1) * 4 + 3) * 1024,
        qx + M8, 1024, 1024, 8, 512);
    if (phase == 1) k_pair<1><<<8192, 256, 0, stream>>>(c1, qx, qx + M8, accb);
    else            k_pair<2><<<8192, 256, 0, stream>>>(c1, qx, qx + M8, accb);
  };

  branch_pair(1, 512,  25,  cpt_words,    senti_words,   1);  // semantic
  branch_pair(3, 3200, 196, region_feats, spatial_feats, 2);  // visual -> c1 = fuse

  // ================= FFN =================
  k_transpose_cvt<<<dim3(128, 32, 1), tb32, 0, stream>>>(ffn_W1, wF1t, 0, 0,
                                                         nullptr, 0, 1024, 4096);
  k_transpose_cvt<<<dim3(32, 128, 1), tb32, 0, stream>>>(ffn_W2, wF2t, 0, 0,
                                                         nullptr, 0, 4096, 1024);
  k_ln<true><<<8192, 256, 0, stream>>>(c1, ln_g + 5 * 1024, ln_b + 5 * 1024, hbuf);
  k_gemm<1, 32><<<2048, 256, 0, stream>>>(hbuf, wF1t, ffn_b1, qx, nullptr, 4096, 1024, 32);
  k_gemm<2, 64><<<512, 256, 0, stream>>>(qx, wF2t, ffn_b2, (float*)d_out, c1,
                                         1024, 4096, 8);
}